// Round 1
// baseline (681.926 us; speedup 1.0000x reference)
//
#include <hip/hip_runtime.h>
#include <math.h>

typedef unsigned short u16;
typedef unsigned int   u32;

#define PP   2
#define LQ   1024     // H*W
#define DM   512      // d_model
#define DI   1024     // d_inner
#define NS   16       // d_state
#define CIN  256
#define EPSF 1e-5f

__device__ __forceinline__ float bf2f(u16 u){ return __uint_as_float(((u32)u)<<16); }
__device__ __forceinline__ u16 f2bf(float f){
  u32 x = __float_as_uint(f);
  x += 0x7fffu + ((x>>16)&1u);           // RNE
  return (u16)(x>>16);
}
__device__ __forceinline__ float sigm(float x){ return 1.f/(1.f+expf(-x)); }

// ---- shared 64x64x16 fp32 MAC tile (4x4 per thread, 256 threads) ----
__device__ __forceinline__ void mac_tile(const float (*As)[68], const float (*Bs)[68],
                                         float acc[4][4], int tx, int ty)
{
  #pragma unroll
  for (int kk=0;kk<16;++kk){
    float av[4], bv[4];
    #pragma unroll
    for (int i=0;i<4;++i) av[i]=As[kk][ty*4+i];
    #pragma unroll
    for (int j=0;j<4;++j) bv[j]=Bs[kk][tx*4+j];
    #pragma unroll
    for (int i=0;i<4;++i)
      #pragma unroll
      for (int j=0;j<4;++j) acc[i][j] = fmaf(av[i], bv[j], acc[i][j]);
  }
}

// K1: xr[p][b][hw][o] = relu(bn(sum_c X[c][hw]*crw[o][c]))
__global__ __launch_bounds__(256) void k1_convraise(
    const float* __restrict__ xV, const float* __restrict__ xI,
    const float* __restrict__ crw, const float* __restrict__ crg,
    const float* __restrict__ crb, const float* __restrict__ crm,
    const float* __restrict__ crv, float* __restrict__ xr)
{
  const int img = blockIdx.z, p = img>>1, b = img&1;
  const float* __restrict__ X = (p ? xI : xV) + (size_t)b*CIN*LQ;
  const int m0 = blockIdx.x*64, n0 = blockIdx.y*64;
  __shared__ float As[16][68];
  __shared__ float Bs[16][68];
  const int tid = threadIdx.x, tx = tid&15, ty = tid>>4;
  float acc[4][4] = {};
  for (int k0=0; k0<CIN; k0+=16){
    {
      const int kk = tid>>4, mm = (tid&15)*4;
      const float4 v = *(const float4*)(X + (size_t)(k0+kk)*LQ + m0 + mm);
      *(float4*)&As[kk][mm] = v;
      const int nn = tid>>2, k4 = (tid&3)*4;
      const float4 w = *(const float4*)(crw + (size_t)(n0+nn)*CIN + k0 + k4);
      Bs[k4+0][nn]=w.x; Bs[k4+1][nn]=w.y; Bs[k4+2][nn]=w.z; Bs[k4+3][nn]=w.w;
    }
    __syncthreads();
    mac_tile(As, Bs, acc, tx, ty);
    __syncthreads();
  }
  #pragma unroll
  for (int i=0;i<4;++i){
    const int m = m0 + ty*4 + i;
    float4 o; float* po = (float*)&o;
    #pragma unroll
    for (int j=0;j<4;++j){
      const int n = n0 + tx*4 + j;
      const float s = crg[n]*rsqrtf(crv[n]+EPSF);
      const float t = crb[n] - crm[n]*s;
      po[j] = fmaxf(fmaf(acc[i][j], s, t), 0.f);
    }
    *(float4*)(xr + ((size_t)img*LQ + m)*DM + n0 + tx*4) = o;
  }
}

// K2b: per-row (p,b,hw) layernorm stats over DM
__global__ __launch_bounds__(64) void k2_stats(const float* __restrict__ xr,
                                               float* __restrict__ stats)
{
  const int row = blockIdx.x;        // p*2048 + m
  const int lane = threadIdx.x;
  const float* __restrict__ base = xr + (size_t)row*DM;
  float s=0.f, q=0.f;
  #pragma unroll
  for (int j=0;j<8;j+=4){
    const float4 v = *(const float4*)(base + lane*8 + j);
    s += v.x+v.y+v.z+v.w;
    q += v.x*v.x+v.y*v.y+v.z*v.z+v.w*v.w;
  }
  #pragma unroll
  for (int off=32; off; off>>=1){ s += __shfl_down(s,off); q += __shfl_down(q,off); }
  if (lane==0){
    const float mean = s*(1.f/DM);
    const float var  = fmaxf(q*(1.f/DM) - mean*mean, 0.f);
    stats[row*2+0] = mean;
    stats[row*2+1] = rsqrtf(var+EPSF);
  }
}

// K2: lam[p*2+b] = sigmoid(relu(pool@w1^T+b1)@w2^T+b2)
__global__ __launch_bounds__(512) void k2_lambda(
    const float* __restrict__ xr,
    const float* __restrict__ w1V, const float* __restrict__ b1V,
    const float* __restrict__ w2V, const float* __restrict__ b2V,
    const float* __restrict__ w1I, const float* __restrict__ b1I,
    const float* __restrict__ w2I, const float* __restrict__ b2I,
    float* __restrict__ lam)
{
  const int img = blockIdx.x, p = img>>1;
  const float* __restrict__ w1 = p? w1I : w1V;
  const float* __restrict__ b1 = p? b1I : b1V;
  const float* __restrict__ w2 = p? w2I : w2V;
  const float* __restrict__ b2 = p? b2I : b2V;
  __shared__ float pool[DM];
  __shared__ float hb[128];
  const int tid = threadIdx.x;
  const float* __restrict__ base = xr + (size_t)img*LQ*DM + tid;
  float s0=0.f,s1=0.f,s2=0.f,s3=0.f;
  for (int t=0;t<LQ;t+=4){
    s0 += base[(size_t)(t+0)*DM];
    s1 += base[(size_t)(t+1)*DM];
    s2 += base[(size_t)(t+2)*DM];
    s3 += base[(size_t)(t+3)*DM];
  }
  pool[tid] = (s0+s1+s2+s3)*(1.f/LQ);
  __syncthreads();
  if (tid<128){
    float h = b1[tid];
    const float* __restrict__ wr = w1 + (size_t)tid*DM;
    for (int o=0;o<DM;o+=4){
      const float4 w = *(const float4*)(wr+o);
      h += pool[o]*w.x + pool[o+1]*w.y + pool[o+2]*w.z + pool[o+3]*w.w;
    }
    hb[tid] = fmaxf(h,0.f);
  }
  __syncthreads();
  if (tid==0){
    float v = b2[0];
    for (int j=0;j<128;++j) v += hb[j]*w2[j];
    lam[img] = sigm(v);
  }
}

// K3: xp[p][m][n] = bf16( LN(xr[p][m][:]) . in_w[n][:] )   (n in [0,2048))
__global__ __launch_bounds__(256) void k3_inproj(
    const float* __restrict__ xr, const float* __restrict__ stats,
    const float* __restrict__ lgV, const float* __restrict__ lbV,
    const float* __restrict__ lgI, const float* __restrict__ lbI,
    const float* __restrict__ iwV, const float* __restrict__ iwI,
    u16* __restrict__ xp)
{
  const int p = blockIdx.z;
  const float* __restrict__ A  = xr + (size_t)p*2048*DM;
  const float* __restrict__ st = stats + (size_t)p*2048*2;
  const float* __restrict__ lg = p? lgI : lgV;
  const float* __restrict__ lb = p? lbI : lbV;
  const float* __restrict__ Bw = p? iwI : iwV;
  const int m0 = blockIdx.x*64, n0 = blockIdx.y*64;
  __shared__ float As[16][68];
  __shared__ float Bs[16][68];
  const int tid = threadIdx.x, tx = tid&15, ty = tid>>4;
  float acc[4][4] = {};
  for (int k0=0;k0<DM;k0+=16){
    {
      const int rr = tid>>2, k4 = (tid&3)*4;
      const float4 v  = *(const float4*)(A + (size_t)(m0+rr)*DM + k0 + k4);
      const float mean = st[(m0+rr)*2+0], rstd = st[(m0+rr)*2+1];
      const float4 g  = *(const float4*)(lg + k0 + k4);
      const float4 be = *(const float4*)(lb + k0 + k4);
      As[k4+0][rr] = (v.x-mean)*rstd*g.x + be.x;
      As[k4+1][rr] = (v.y-mean)*rstd*g.y + be.y;
      As[k4+2][rr] = (v.z-mean)*rstd*g.z + be.z;
      As[k4+3][rr] = (v.w-mean)*rstd*g.w + be.w;
      const float4 w = *(const float4*)(Bw + (size_t)(n0+rr)*DM + k0 + k4);
      Bs[k4+0][rr]=w.x; Bs[k4+1][rr]=w.y; Bs[k4+2][rr]=w.z; Bs[k4+3][rr]=w.w;
    }
    __syncthreads();
    mac_tile(As, Bs, acc, tx, ty);
    __syncthreads();
  }
  #pragma unroll
  for (int i=0;i<4;++i){
    const int m = m0+ty*4+i;
    ushort4 o;
    o.x=f2bf(acc[i][0]); o.y=f2bf(acc[i][1]); o.z=f2bf(acc[i][2]); o.w=f2bf(acc[i][3]);
    *(ushort4*)(xp + ((size_t)p*2048 + m)*2048 + n0 + tx*4) = o;
  }
}

// K4: 8 scan instances (p,sel,dir). 4 lanes per (b,i) row, 4 states each.
__global__ __launch_bounds__(256) void k4_scan(
    const u16* __restrict__ xp,
    const float* __restrict__ AlV, const float* __restrict__ AlI,
    const float* __restrict__ BV,  const float* __restrict__ BI,
    const float* __restrict__ CV,  const float* __restrict__ CI,
    u16* __restrict__ ysf, u16* __restrict__ ysb)
{
  const int inst = blockIdx.y;          // p*2+sel
  const int dir  = blockIdx.z;          // 0 fwd, 1 bwd
  const int p = inst>>1, sel = inst&1;
  const int tid = threadIdx.x;
  const int row = blockIdx.x*64 + (tid>>2);   // b*1024 + i
  const int q = tid&3;
  const int b = row>>10, i = row&1023;
  const float* __restrict__ Al = p? AlI : AlV;
  const float* __restrict__ Cm = p? CI  : CV;
  const float* __restrict__ Bm = (p^sel) ? BI : BV;   // sel=0: own B; sel=1: other's B
  const int s0 = q*4;
  const float4 al = *(const float4*)(Al + (size_t)i*NS + s0);
  const float4 bv = *(const float4*)(Bm + (size_t)i*NS + s0);
  const float4 cv = *(const float4*)(Cm + (size_t)i*NS + s0);
  const float a0=-expf(al.x), a1=-expf(al.y), a2=-expf(al.z), a3=-expf(al.w);
  const u16* __restrict__ xs = xp + ((size_t)p*2048 + b*1024)*2048 + i;
  u16* __restrict__ yr = (dir ? ysb : ysf) + ((size_t)inst*2048 + (size_t)b*1024)*DI + i;
  float h0=0.f,h1=0.f,h2=0.f,h3=0.f;
  for (int tt=0; tt<LQ; ++tt){
    const int t = dir ? (LQ-1-tt) : tt;
    const float x = bf2f(xs[(size_t)t*2048]);
    h0 = fmaf(h0, a0, x*bv.x);
    h1 = fmaf(h1, a1, x*bv.y);
    h2 = fmaf(h2, a2, x*bv.z);
    h3 = fmaf(h3, a3, x*bv.w);
    float y = (h0*cv.x + h1*cv.y) + (h2*cv.z + h3*cv.w);
    y += __shfl_xor(y, 1);
    y += __shfl_xor(y, 2);
    if (q==0) yr[(size_t)t*DI] = f2bf(y);
  }
}

// K5: outp[p][m][n] = comb[p][m][:] . out_w[n][:]
// comb = 0.5*silu(gate)*(lam*(ysf_std+ysb_std) + (1-lam)*(ysf_x+ysb_x))
__global__ __launch_bounds__(256) void k5_outproj(
    const u16* __restrict__ ysf, const u16* __restrict__ ysb,
    const u16* __restrict__ xp, const float* __restrict__ lam,
    const float* __restrict__ owV, const float* __restrict__ owI,
    float* __restrict__ outp)
{
  const int p = blockIdx.z;
  const float* __restrict__ Bw = p? owI : owV;
  const int m0 = blockIdx.x*64, n0 = blockIdx.y*64;
  __shared__ float As[16][68];
  __shared__ float Bs[16][68];
  const int tid = threadIdx.x, tx = tid&15, ty = tid>>4;
  float acc[4][4] = {};
  for (int k0=0;k0<DI;k0+=16){
    {
      const int rr = tid>>2, k4 = (tid&3)*4;
      const int m = m0+rr;
      const float lm = lam[p*2 + (m>>10)];
      const size_t r0 = ((size_t)(p*2+0)*2048 + m)*DI + k0 + k4;
      const size_t r1 = ((size_t)(p*2+1)*2048 + m)*DI + k0 + k4;
      const ushort4 f0 = *(const ushort4*)(ysf + r0);
      const ushort4 bb0= *(const ushort4*)(ysb + r0);
      const ushort4 f1 = *(const ushort4*)(ysf + r1);
      const ushort4 bb1= *(const ushort4*)(ysb + r1);
      const ushort4 gu = *(const ushort4*)(xp + ((size_t)p*2048 + m)*2048 + DI + k0 + k4);
      const u16 fa[4]={f0.x,f0.y,f0.z,f0.w}, ba[4]={bb0.x,bb0.y,bb0.z,bb0.w};
      const u16 fx[4]={f1.x,f1.y,f1.z,f1.w}, bx[4]={bb1.x,bb1.y,bb1.z,bb1.w};
      const u16 ga[4]={gu.x,gu.y,gu.z,gu.w};
      #pragma unroll
      for (int d=0; d<4; ++d){
        const float ys = bf2f(fa[d]) + bf2f(ba[d]);
        const float yx = bf2f(fx[d]) + bf2f(bx[d]);
        const float g  = bf2f(ga[d]);
        As[k4+d][rr] = 0.5f * g * sigm(g) * (lm*ys + (1.f-lm)*yx);
      }
      const float4 w = *(const float4*)(Bw + (size_t)(n0+rr)*DI + k0 + k4);
      Bs[k4+0][rr]=w.x; Bs[k4+1][rr]=w.y; Bs[k4+2][rr]=w.z; Bs[k4+3][rr]=w.w;
    }
    __syncthreads();
    mac_tile(As, Bs, acc, tx, ty);
    __syncthreads();
  }
  #pragma unroll
  for (int i=0;i<4;++i){
    const int m = m0+ty*4+i;
    float4 o; o.x=acc[i][0]; o.y=acc[i][1]; o.z=acc[i][2]; o.w=acc[i][3];
    *(float4*)(outp + ((size_t)p*2048 + m)*DM + n0 + tx*4) = o;
  }
}

// K6: fpre[p][m][q] = outp[p][m][:] . rs_w[q][:]
__global__ __launch_bounds__(256) void k6_rs(
    const float* __restrict__ outp, const float* __restrict__ rsw,
    float* __restrict__ fpre)
{
  const int p = blockIdx.z;
  const int m0 = blockIdx.x*64, n0 = blockIdx.y*64;
  __shared__ float As[16][68];
  __shared__ float Bs[16][68];
  const int tid = threadIdx.x, tx = tid&15, ty = tid>>4;
  float acc[4][4] = {};
  for (int k0=0;k0<DM;k0+=16){
    {
      const int rr = tid>>2, k4 = (tid&3)*4;
      const float4 v = *(const float4*)(outp + (size_t)(p*2048 + m0+rr)*DM + k0 + k4);
      As[k4+0][rr]=v.x; As[k4+1][rr]=v.y; As[k4+2][rr]=v.z; As[k4+3][rr]=v.w;
      const float4 w = *(const float4*)(rsw + (size_t)(n0+rr)*DM + k0 + k4);
      Bs[k4+0][rr]=w.x; Bs[k4+1][rr]=w.y; Bs[k4+2][rr]=w.z; Bs[k4+3][rr]=w.w;
    }
    __syncthreads();
    mac_tile(As, Bs, acc, tx, ty);
    __syncthreads();
  }
  #pragma unroll
  for (int i=0;i<4;++i){
    const int m = m0+ty*4+i;
    float4 o; o.x=acc[i][0]; o.y=acc[i][1]; o.z=acc[i][2]; o.w=acc[i][3];
    *(float4*)(fpre + ((size_t)p*2048 + m)*CIN + n0 + tx*4) = o;
  }
}

// K7: out[p][b][q][hw] = x[p][b][q][hw] + bn(fpre[p][b*1024+hw][q])   (32x32 LDS transpose)
__global__ __launch_bounds__(256) void k7_final(
    const float* __restrict__ fpre, const float* __restrict__ xV, const float* __restrict__ xI,
    const float* __restrict__ rsg, const float* __restrict__ rsb,
    const float* __restrict__ rsm, const float* __restrict__ rsv,
    float* __restrict__ out)
{
  const int img = blockIdx.z, p = img>>1, b = img&1;
  const int hw0 = blockIdx.x*32, q0 = blockIdx.y*32;
  const float* __restrict__ xres = (p? xI : xV) + (size_t)b*CIN*LQ;
  __shared__ float tile[32][33];
  const int tid = threadIdx.x;
  {
    const int r = tid>>3, c = (tid&7)*4;
    const float4 v = *(const float4*)(fpre + ((size_t)p*2048 + b*1024 + hw0 + r)*CIN + q0 + c);
    tile[r][c]=v.x; tile[r][c+1]=v.y; tile[r][c+2]=v.z; tile[r][c+3]=v.w;
  }
  __syncthreads();
  #pragma unroll
  for (int k=0;k<4;++k){
    const int lin = k*256 + tid;
    const int ql = lin>>5, hl = lin&31;
    const int qch = q0+ql, hw = hw0+hl;
    const float s = rsg[qch]*rsqrtf(rsv[qch]+EPSF);
    const float t = rsb[qch] - rsm[qch]*s;
    const float v = fmaf(tile[hl][ql], s, t) + xres[(size_t)qch*LQ + hw];
    out[(size_t)img*CIN*LQ + (size_t)qch*LQ + hw] = v;
  }
}

extern "C" void kernel_launch(void* const* d_in, const int* in_sizes, int n_in,
                              void* d_out, int out_size, void* d_ws, size_t ws_size,
                              hipStream_t stream)
{
  const float* cr_w = (const float*)d_in[0];
  const float* cr_g = (const float*)d_in[1];
  const float* cr_b = (const float*)d_in[2];
  const float* cr_m = (const float*)d_in[3];
  const float* cr_v = (const float*)d_in[4];
  const float* rs_w = (const float*)d_in[5];
  const float* rs_g = (const float*)d_in[6];
  const float* rs_b = (const float*)d_in[7];
  const float* rs_m = (const float*)d_in[8];
  const float* rs_v = (const float*)d_in[9];
  const float* mV_ln_g = (const float*)d_in[10];
  const float* mV_ln_b = (const float*)d_in[11];
  const float* mV_in_w = (const float*)d_in[12];
  const float* mV_A    = (const float*)d_in[13];
  const float* mV_B    = (const float*)d_in[14];
  const float* mV_C    = (const float*)d_in[15];
  const float* mV_ow   = (const float*)d_in[16];
  const float* lpV_w1  = (const float*)d_in[17];
  const float* lpV_b1  = (const float*)d_in[18];
  const float* lpV_w2  = (const float*)d_in[19];
  const float* lpV_b2  = (const float*)d_in[20];
  const float* mI_ln_g = (const float*)d_in[21];
  const float* mI_ln_b = (const float*)d_in[22];
  const float* mI_in_w = (const float*)d_in[23];
  const float* mI_A    = (const float*)d_in[24];
  const float* mI_B    = (const float*)d_in[25];
  const float* mI_C    = (const float*)d_in[26];
  const float* mI_ow   = (const float*)d_in[27];
  const float* lpI_w1  = (const float*)d_in[28];
  const float* lpI_b1  = (const float*)d_in[29];
  const float* lpI_w2  = (const float*)d_in[30];
  const float* lpI_b2  = (const float*)d_in[31];
  const float* x_V = (const float*)d_in[32];
  const float* x_I = (const float*)d_in[33];
  float* out = (float*)d_out;

  char* ws = (char*)d_ws;
  float* xr    = (float*)(ws + 0);            // [2][2048][512] f32   8,388,608 B
  float* stats = (float*)(ws + 8388608);      // [4096][2] f32          32,768 B
  float* lam   = (float*)(ws + 8421376);      // [4] f32
  u16*   xp    = (u16*)  (ws + 8421632);      // [2][2048][2048] bf16  16,777,216 B
  u16*   ysf   = (u16*)  (ws + 25198848);     // [4][2048][1024] bf16  16,777,216 B
  u16*   ysb   = (u16*)  (ws + 41976064);     // [4][2048][1024] bf16  16,777,216 B
  float* outp  = xr;                          // reuse (xr dead after k3)
  float* fpre  = (float*)(ws + 25198848);     // reuse ysf region (dead after k5)

  k1_convraise<<<dim3(16,8,4),  dim3(256), 0, stream>>>(x_V,x_I,cr_w,cr_g,cr_b,cr_m,cr_v,xr);
  k2_stats    <<<dim3(4096),    dim3(64),  0, stream>>>(xr, stats);
  k2_lambda   <<<dim3(4),       dim3(512), 0, stream>>>(xr, lpV_w1,lpV_b1,lpV_w2,lpV_b2,
                                                            lpI_w1,lpI_b1,lpI_w2,lpI_b2, lam);
  k3_inproj   <<<dim3(32,32,2), dim3(256), 0, stream>>>(xr, stats, mV_ln_g,mV_ln_b,
                                                        mI_ln_g,mI_ln_b, mV_in_w, mI_in_w, xp);
  k4_scan     <<<dim3(32,4,2),  dim3(256), 0, stream>>>(xp, mV_A, mI_A, mV_B, mI_B,
                                                        mV_C, mI_C, ysf, ysb);
  k5_outproj  <<<dim3(32,8,2),  dim3(256), 0, stream>>>(ysf, ysb, xp, lam, mV_ow, mI_ow, outp);
  k6_rs       <<<dim3(32,4,2),  dim3(256), 0, stream>>>(outp, rs_w, fpre);
  k7_final    <<<dim3(32,8,4),  dim3(256), 0, stream>>>(fpre, x_V, x_I, rs_g, rs_b, rs_m, rs_v, out);
}

// Round 2
// 389.901 us; speedup vs baseline: 1.7490x; 1.7490x over previous
//
#include <hip/hip_runtime.h>
#include <math.h>

typedef unsigned short u16;
typedef unsigned int   u32;

#define PP   2
#define LQ   1024     // H*W
#define DM   512      // d_model
#define DI   1024     // d_inner
#define NS   16       // d_state
#define CIN  256
#define EPSF 1e-5f
#define CH   16       // scan chunks
#define TL   64       // chunk length (CH*TL == LQ)

__device__ __forceinline__ float bf2f(u16 u){ return __uint_as_float(((u32)u)<<16); }
__device__ __forceinline__ u16 f2bf(float f){
  u32 x = __float_as_uint(f);
  x += 0x7fffu + ((x>>16)&1u);           // RNE
  return (u16)(x>>16);
}
__device__ __forceinline__ float sigm(float x){ return 1.f/(1.f+expf(-x)); }

// 8 bf16 <-> 8 f32 (16B vector)
__device__ __forceinline__ void ld8(const u16* p, float* f){
  const uint4 v = *(const uint4*)p;
  f[0]=bf2f((u16)v.x); f[1]=bf2f((u16)(v.x>>16));
  f[2]=bf2f((u16)v.y); f[3]=bf2f((u16)(v.y>>16));
  f[4]=bf2f((u16)v.z); f[5]=bf2f((u16)(v.z>>16));
  f[6]=bf2f((u16)v.w); f[7]=bf2f((u16)(v.w>>16));
}
__device__ __forceinline__ void st8(u16* p, const float* f){
  uint4 v;
  v.x = (u32)f2bf(f[0]) | ((u32)f2bf(f[1])<<16);
  v.y = (u32)f2bf(f[2]) | ((u32)f2bf(f[3])<<16);
  v.z = (u32)f2bf(f[4]) | ((u32)f2bf(f[5])<<16);
  v.w = (u32)f2bf(f[6]) | ((u32)f2bf(f[7])<<16);
  *(uint4*)p = v;
}

// ---- shared 64x64x16 fp32 MAC tile (4x4 per thread, 256 threads) ----
__device__ __forceinline__ void mac_tile(const float (*As)[68], const float (*Bs)[68],
                                         float acc[4][4], int tx, int ty)
{
  #pragma unroll
  for (int kk=0;kk<16;++kk){
    float av[4], bv[4];
    #pragma unroll
    for (int i=0;i<4;++i) av[i]=As[kk][ty*4+i];
    #pragma unroll
    for (int j=0;j<4;++j) bv[j]=Bs[kk][tx*4+j];
    #pragma unroll
    for (int i=0;i<4;++i)
      #pragma unroll
      for (int j=0;j<4;++j) acc[i][j] = fmaf(av[i], bv[j], acc[i][j]);
  }
}

// K1: xr[p][b][hw][o] = relu(bn(sum_c X[c][hw]*crw[o][c]))
__global__ __launch_bounds__(256) void k1_convraise(
    const float* __restrict__ xV, const float* __restrict__ xI,
    const float* __restrict__ crw, const float* __restrict__ crg,
    const float* __restrict__ crb, const float* __restrict__ crm,
    const float* __restrict__ crv, float* __restrict__ xr)
{
  const int img = blockIdx.z, p = img>>1, b = img&1;
  const float* __restrict__ X = (p ? xI : xV) + (size_t)b*CIN*LQ;
  const int m0 = blockIdx.x*64, n0 = blockIdx.y*64;
  __shared__ float As[16][68];
  __shared__ float Bs[16][68];
  const int tid = threadIdx.x, tx = tid&15, ty = tid>>4;
  float acc[4][4] = {};
  for (int k0=0; k0<CIN; k0+=16){
    {
      const int kk = tid>>4, mm = (tid&15)*4;
      const float4 v = *(const float4*)(X + (size_t)(k0+kk)*LQ + m0 + mm);
      *(float4*)&As[kk][mm] = v;
      const int nn = tid>>2, k4 = (tid&3)*4;
      const float4 w = *(const float4*)(crw + (size_t)(n0+nn)*CIN + k0 + k4);
      Bs[k4+0][nn]=w.x; Bs[k4+1][nn]=w.y; Bs[k4+2][nn]=w.z; Bs[k4+3][nn]=w.w;
    }
    __syncthreads();
    mac_tile(As, Bs, acc, tx, ty);
    __syncthreads();
  }
  #pragma unroll
  for (int i=0;i<4;++i){
    const int m = m0 + ty*4 + i;
    float4 o; float* po = (float*)&o;
    #pragma unroll
    for (int j=0;j<4;++j){
      const int n = n0 + tx*4 + j;
      const float s = crg[n]*rsqrtf(crv[n]+EPSF);
      const float t = crb[n] - crm[n]*s;
      po[j] = fmaxf(fmaf(acc[i][j], s, t), 0.f);
    }
    *(float4*)(xr + ((size_t)img*LQ + m)*DM + n0 + tx*4) = o;
  }
}

// K2b: per-row (p,b,hw) layernorm stats over DM
__global__ __launch_bounds__(64) void k2_stats(const float* __restrict__ xr,
                                               float* __restrict__ stats)
{
  const int row = blockIdx.x;        // p*2048 + m
  const int lane = threadIdx.x;
  const float* __restrict__ base = xr + (size_t)row*DM;
  float s=0.f, q=0.f;
  #pragma unroll
  for (int j=0;j<8;j+=4){
    const float4 v = *(const float4*)(base + lane*8 + j);
    s += v.x+v.y+v.z+v.w;
    q += v.x*v.x+v.y*v.y+v.z*v.z+v.w*v.w;
  }
  #pragma unroll
  for (int off=32; off; off>>=1){ s += __shfl_down(s,off); q += __shfl_down(q,off); }
  if (lane==0){
    const float mean = s*(1.f/DM);
    const float var  = fmaxf(q*(1.f/DM) - mean*mean, 0.f);
    stats[row*2+0] = mean;
    stats[row*2+1] = rsqrtf(var+EPSF);
  }
}

// K2p: part[img][sl][ch] = sum over 64 t of xr[img][sl*64+t][ch]
__global__ __launch_bounds__(256) void k2_pool(const float* __restrict__ xr,
                                               float* __restrict__ part)
{
  const int img = blockIdx.y, sl = blockIdx.x;
  const int tid = threadIdx.x;
  const float* __restrict__ base = xr + ((size_t)img*LQ + sl*64)*DM;
  float s0=0.f, s1=0.f;
  for (int t=0;t<64;++t){
    s0 += base[(size_t)t*DM + tid];
    s1 += base[(size_t)t*DM + 256 + tid];
  }
  part[((size_t)img*16 + sl)*DM + tid]       = s0;
  part[((size_t)img*16 + sl)*DM + 256 + tid] = s1;
}

// K2: lam[img] = sigmoid(relu(pool@w1^T+b1)@w2^T+b2)
__global__ __launch_bounds__(256) void k2_lambda(
    const float* __restrict__ part,
    const float* __restrict__ w1V, const float* __restrict__ b1V,
    const float* __restrict__ w2V, const float* __restrict__ b2V,
    const float* __restrict__ w1I, const float* __restrict__ b1I,
    const float* __restrict__ w2I, const float* __restrict__ b2I,
    float* __restrict__ lam)
{
  const int img = blockIdx.x, p = img>>1;
  const float* __restrict__ w1 = p? w1I : w1V;
  const float* __restrict__ b1 = p? b1I : b1V;
  const float* __restrict__ w2 = p? w2I : w2V;
  const float* __restrict__ b2 = p? b2I : b2V;
  __shared__ float pool[DM];
  __shared__ float hb[128];
  const int tid = threadIdx.x;
  for (int ch=tid; ch<DM; ch+=256){
    float s=0.f;
    #pragma unroll
    for (int sl=0; sl<16; ++sl) s += part[((size_t)img*16 + sl)*DM + ch];
    pool[ch] = s * (1.f/LQ);
  }
  __syncthreads();
  if (tid<128){
    float h = b1[tid];
    const float* __restrict__ wr = w1 + (size_t)tid*DM;
    for (int o=0;o<DM;o+=4){
      const float4 w = *(const float4*)(wr+o);
      h += pool[o]*w.x + pool[o+1]*w.y + pool[o+2]*w.z + pool[o+3]*w.w;
    }
    hb[tid] = fmaxf(h,0.f);
  }
  __syncthreads();
  if (tid==0){
    float v = b2[0];
    for (int j=0;j<128;++j) v += hb[j]*w2[j];
    lam[img] = sigm(v);
  }
}

// K3: xp[p][m][n] = bf16( LN(xr[p][m][:]) . in_w[n][:] )   (n in [0,2048))
__global__ __launch_bounds__(256) void k3_inproj(
    const float* __restrict__ xr, const float* __restrict__ stats,
    const float* __restrict__ lgV, const float* __restrict__ lbV,
    const float* __restrict__ lgI, const float* __restrict__ lbI,
    const float* __restrict__ iwV, const float* __restrict__ iwI,
    u16* __restrict__ xp)
{
  const int p = blockIdx.z;
  const float* __restrict__ A  = xr + (size_t)p*2048*DM;
  const float* __restrict__ st = stats + (size_t)p*2048*2;
  const float* __restrict__ lg = p? lgI : lgV;
  const float* __restrict__ lb = p? lbI : lbV;
  const float* __restrict__ Bw = p? iwI : iwV;
  const int m0 = blockIdx.x*64, n0 = blockIdx.y*64;
  __shared__ float As[16][68];
  __shared__ float Bs[16][68];
  const int tid = threadIdx.x, tx = tid&15, ty = tid>>4;
  float acc[4][4] = {};
  for (int k0=0;k0<DM;k0+=16){
    {
      const int rr = tid>>2, k4 = (tid&3)*4;
      const float4 v  = *(const float4*)(A + (size_t)(m0+rr)*DM + k0 + k4);
      const float mean = st[(m0+rr)*2+0], rstd = st[(m0+rr)*2+1];
      const float4 g  = *(const float4*)(lg + k0 + k4);
      const float4 be = *(const float4*)(lb + k0 + k4);
      As[k4+0][rr] = (v.x-mean)*rstd*g.x + be.x;
      As[k4+1][rr] = (v.y-mean)*rstd*g.y + be.y;
      As[k4+2][rr] = (v.z-mean)*rstd*g.z + be.z;
      As[k4+3][rr] = (v.w-mean)*rstd*g.w + be.w;
      const float4 w = *(const float4*)(Bw + (size_t)(n0+rr)*DM + k0 + k4);
      Bs[k4+0][rr]=w.x; Bs[k4+1][rr]=w.y; Bs[k4+2][rr]=w.z; Bs[k4+3][rr]=w.w;
    }
    __syncthreads();
    mac_tile(As, Bs, acc, tx, ty);
    __syncthreads();
  }
  #pragma unroll
  for (int i=0;i<4;++i){
    const int m = m0+ty*4+i;
    ushort4 o;
    o.x=f2bf(acc[i][0]); o.y=f2bf(acc[i][1]); o.z=f2bf(acc[i][2]); o.w=f2bf(acc[i][3]);
    *(ushort4*)(xp + ((size_t)p*2048 + m)*2048 + n0 + tx*4) = o;
  }
}

// ---- chunked scan: k4a local sweep -> k4b chunk prefix -> k4c final sweep ----
// hfin layout: [z=inst*2+dir][c][row(b*1024+i)][16 states] bf16

// K4a: per-chunk local scan (zero init), store chunk-final states
__global__ __launch_bounds__(256) void k4a_sweep1(
    const u16* __restrict__ xp,
    const float* __restrict__ AlV, const float* __restrict__ AlI,
    const float* __restrict__ BV,  const float* __restrict__ BI,
    u16* __restrict__ hfin)
{
  const int z = blockIdx.z, inst = z>>1, dir = z&1;
  const int p = inst>>1, sel = inst&1;
  const int c = blockIdx.y;
  const int row = blockIdx.x*256 + threadIdx.x;
  const int b = row>>10, i = row&1023;
  const float* __restrict__ Al = p? AlI : AlV;
  const float* __restrict__ Bm = (p^sel)? BI : BV;
  float a[16], bc[16], h[16];
  #pragma unroll
  for (int s=0;s<16;s+=4){
    const float4 al = *(const float4*)(Al + (size_t)i*NS + s);
    const float4 bv = *(const float4*)(Bm + (size_t)i*NS + s);
    a[s]=-expf(al.x); a[s+1]=-expf(al.y); a[s+2]=-expf(al.z); a[s+3]=-expf(al.w);
    bc[s]=bv.x; bc[s+1]=bv.y; bc[s+2]=bv.z; bc[s+3]=bv.w;
    h[s]=0.f; h[s+1]=0.f; h[s+2]=0.f; h[s+3]=0.f;
  }
  const u16* xptr = xp + ((size_t)(p*2048 + b*1024 + c*TL + (dir?TL-1:0)))*2048 + i;
  const ptrdiff_t xstep = dir ? -2048 : 2048;
  #pragma unroll 4
  for (int tt=0; tt<TL; ++tt){
    const float x = bf2f(*xptr);
    #pragma unroll
    for (int s=0;s<16;++s) h[s] = fmaf(h[s], a[s], x*bc[s]);
    xptr += xstep;
  }
  u16* hp = hfin + (((size_t)z*CH + c)*2048 + row)*NS;
  st8(hp, h); st8(hp+8, h+8);
}

// K4b: sequential prefix over chunks (in place: fin -> H_init)
__global__ __launch_bounds__(256) void k4b_prefix(
    const float* __restrict__ AlV, const float* __restrict__ AlI,
    u16* __restrict__ hfin)
{
  const int z = blockIdx.y, inst = z>>1, dir = z&1, p = inst>>1;
  const int row = blockIdx.x*256 + threadIdx.x;
  const int i = row & 1023;
  const float* __restrict__ Al = p? AlI : AlV;
  float a64[16], H[16];
  #pragma unroll
  for (int s=0;s<16;s+=4){
    const float4 al = *(const float4*)(Al + (size_t)i*NS + s);
    a64[s]  =expf(64.f*al.x); a64[s+1]=expf(64.f*al.y);
    a64[s+2]=expf(64.f*al.z); a64[s+3]=expf(64.f*al.w);
    H[s]=0.f; H[s+1]=0.f; H[s+2]=0.f; H[s+3]=0.f;
  }
  for (int k=0;k<CH;++k){
    const int c = dir ? (CH-1-k) : k;
    u16* hp = hfin + (((size_t)z*CH + c)*2048 + row)*NS;
    float fin[16];
    ld8(hp, fin); ld8(hp+8, fin+8);
    st8(hp, H);  st8(hp+8, H+8);
    #pragma unroll
    for (int s=0;s<16;++s) H[s] = fmaf(a64[s], H[s], fin[s]);
  }
}

// K4c: final sweep seeded with exact chunk-init states, emit y
__global__ __launch_bounds__(256) void k4c_sweep2(
    const u16* __restrict__ xp, const u16* __restrict__ hfin,
    const float* __restrict__ AlV, const float* __restrict__ AlI,
    const float* __restrict__ BV,  const float* __restrict__ BI,
    const float* __restrict__ CV,  const float* __restrict__ CI,
    u16* __restrict__ ysf, u16* __restrict__ ysb)
{
  const int z = blockIdx.z, inst = z>>1, dir = z&1;
  const int p = inst>>1, sel = inst&1;
  const int c = blockIdx.y;
  const int row = blockIdx.x*256 + threadIdx.x;
  const int b = row>>10, i = row&1023;
  const float* __restrict__ Al = p? AlI : AlV;
  const float* __restrict__ Bm = (p^sel)? BI : BV;
  const float* __restrict__ Cm = p? CI : CV;
  float a[16], bc[16], cc[16], h[16];
  #pragma unroll
  for (int s=0;s<16;s+=4){
    const float4 al = *(const float4*)(Al + (size_t)i*NS + s);
    const float4 bv = *(const float4*)(Bm + (size_t)i*NS + s);
    const float4 cv = *(const float4*)(Cm + (size_t)i*NS + s);
    a[s]=-expf(al.x); a[s+1]=-expf(al.y); a[s+2]=-expf(al.z); a[s+3]=-expf(al.w);
    bc[s]=bv.x; bc[s+1]=bv.y; bc[s+2]=bv.z; bc[s+3]=bv.w;
    cc[s]=cv.x; cc[s+1]=cv.y; cc[s+2]=cv.z; cc[s+3]=cv.w;
  }
  const u16* hp = hfin + (((size_t)z*CH + c)*2048 + row)*NS;
  ld8(hp, h); ld8(hp+8, h+8);
  const u16* xptr = xp + ((size_t)(p*2048 + b*1024 + c*TL + (dir?TL-1:0)))*2048 + i;
  const ptrdiff_t xstep = dir ? -2048 : 2048;
  u16* yptr = (dir ? ysb : ysf)
            + ((size_t)inst*2048 + b*1024 + c*TL + (dir?TL-1:0))*(size_t)DI + i;
  const ptrdiff_t ystep = dir ? -DI : DI;
  #pragma unroll 2
  for (int tt=0; tt<TL; ++tt){
    const float x = bf2f(*xptr);
    float p0=0.f,p1=0.f,p2=0.f,p3=0.f;
    #pragma unroll
    for (int s=0;s<16;s+=4){
      h[s]   = fmaf(h[s],   a[s],   x*bc[s]);
      h[s+1] = fmaf(h[s+1], a[s+1], x*bc[s+1]);
      h[s+2] = fmaf(h[s+2], a[s+2], x*bc[s+2]);
      h[s+3] = fmaf(h[s+3], a[s+3], x*bc[s+3]);
      p0 = fmaf(h[s],   cc[s],   p0);
      p1 = fmaf(h[s+1], cc[s+1], p1);
      p2 = fmaf(h[s+2], cc[s+2], p2);
      p3 = fmaf(h[s+3], cc[s+3], p3);
    }
    *yptr = f2bf((p0+p1)+(p2+p3));
    xptr += xstep; yptr += ystep;
  }
}

// K5: outp[p][m][n] = comb[p][m][:] . out_w[n][:]
__global__ __launch_bounds__(256) void k5_outproj(
    const u16* __restrict__ ysf, const u16* __restrict__ ysb,
    const u16* __restrict__ xp, const float* __restrict__ lam,
    const float* __restrict__ owV, const float* __restrict__ owI,
    float* __restrict__ outp)
{
  const int p = blockIdx.z;
  const float* __restrict__ Bw = p? owI : owV;
  const int m0 = blockIdx.x*64, n0 = blockIdx.y*64;
  __shared__ float As[16][68];
  __shared__ float Bs[16][68];
  const int tid = threadIdx.x, tx = tid&15, ty = tid>>4;
  float acc[4][4] = {};
  for (int k0=0;k0<DI;k0+=16){
    {
      const int rr = tid>>2, k4 = (tid&3)*4;
      const int m = m0+rr;
      const float lm = lam[p*2 + (m>>10)];
      const size_t r0 = ((size_t)(p*2+0)*2048 + m)*DI + k0 + k4;
      const size_t r1 = ((size_t)(p*2+1)*2048 + m)*DI + k0 + k4;
      const ushort4 f0 = *(const ushort4*)(ysf + r0);
      const ushort4 bb0= *(const ushort4*)(ysb + r0);
      const ushort4 f1 = *(const ushort4*)(ysf + r1);
      const ushort4 bb1= *(const ushort4*)(ysb + r1);
      const ushort4 gu = *(const ushort4*)(xp + ((size_t)p*2048 + m)*2048 + DI + k0 + k4);
      const u16 fa[4]={f0.x,f0.y,f0.z,f0.w}, ba[4]={bb0.x,bb0.y,bb0.z,bb0.w};
      const u16 fx[4]={f1.x,f1.y,f1.z,f1.w}, bx[4]={bb1.x,bb1.y,bb1.z,bb1.w};
      const u16 ga[4]={gu.x,gu.y,gu.z,gu.w};
      #pragma unroll
      for (int d=0; d<4; ++d){
        const float ys = bf2f(fa[d]) + bf2f(ba[d]);
        const float yx = bf2f(fx[d]) + bf2f(bx[d]);
        const float g  = bf2f(ga[d]);
        As[k4+d][rr] = 0.5f * g * sigm(g) * (lm*ys + (1.f-lm)*yx);
      }
      const float4 w = *(const float4*)(Bw + (size_t)(n0+rr)*DI + k0 + k4);
      Bs[k4+0][rr]=w.x; Bs[k4+1][rr]=w.y; Bs[k4+2][rr]=w.z; Bs[k4+3][rr]=w.w;
    }
    __syncthreads();
    mac_tile(As, Bs, acc, tx, ty);
    __syncthreads();
  }
  #pragma unroll
  for (int i=0;i<4;++i){
    const int m = m0+ty*4+i;
    float4 o; o.x=acc[i][0]; o.y=acc[i][1]; o.z=acc[i][2]; o.w=acc[i][3];
    *(float4*)(outp + ((size_t)p*2048 + m)*DM + n0 + tx*4) = o;
  }
}

// K6: fpre[p][m][q] = outp[p][m][:] . rs_w[q][:]
__global__ __launch_bounds__(256) void k6_rs(
    const float* __restrict__ outp, const float* __restrict__ rsw,
    float* __restrict__ fpre)
{
  const int p = blockIdx.z;
  const int m0 = blockIdx.x*64, n0 = blockIdx.y*64;
  __shared__ float As[16][68];
  __shared__ float Bs[16][68];
  const int tid = threadIdx.x, tx = tid&15, ty = tid>>4;
  float acc[4][4] = {};
  for (int k0=0;k0<DM;k0+=16){
    {
      const int rr = tid>>2, k4 = (tid&3)*4;
      const float4 v = *(const float4*)(outp + (size_t)(p*2048 + m0+rr)*DM + k0 + k4);
      As[k4+0][rr]=v.x; As[k4+1][rr]=v.y; As[k4+2][rr]=v.z; As[k4+3][rr]=v.w;
      const float4 w = *(const float4*)(rsw + (size_t)(n0+rr)*DM + k0 + k4);
      Bs[k4+0][rr]=w.x; Bs[k4+1][rr]=w.y; Bs[k4+2][rr]=w.z; Bs[k4+3][rr]=w.w;
    }
    __syncthreads();
    mac_tile(As, Bs, acc, tx, ty);
    __syncthreads();
  }
  #pragma unroll
  for (int i=0;i<4;++i){
    const int m = m0+ty*4+i;
    float4 o; o.x=acc[i][0]; o.y=acc[i][1]; o.z=acc[i][2]; o.w=acc[i][3];
    *(float4*)(fpre + ((size_t)p*2048 + m)*CIN + n0 + tx*4) = o;
  }
}

// K7: out[p][b][q][hw] = x[p][b][q][hw] + bn(fpre[p][b*1024+hw][q])
__global__ __launch_bounds__(256) void k7_final(
    const float* __restrict__ fpre, const float* __restrict__ xV, const float* __restrict__ xI,
    const float* __restrict__ rsg, const float* __restrict__ rsb,
    const float* __restrict__ rsm, const float* __restrict__ rsv,
    float* __restrict__ out)
{
  const int img = blockIdx.z, p = img>>1, b = img&1;
  const int hw0 = blockIdx.x*32, q0 = blockIdx.y*32;
  const float* __restrict__ xres = (p? xI : xV) + (size_t)b*CIN*LQ;
  __shared__ float tile[32][33];
  const int tid = threadIdx.x;
  {
    const int r = tid>>3, c = (tid&7)*4;
    const float4 v = *(const float4*)(fpre + ((size_t)p*2048 + b*1024 + hw0 + r)*CIN + q0 + c);
    tile[r][c]=v.x; tile[r][c+1]=v.y; tile[r][c+2]=v.z; tile[r][c+3]=v.w;
  }
  __syncthreads();
  #pragma unroll
  for (int k=0;k<4;++k){
    const int lin = k*256 + tid;
    const int ql = lin>>5, hl = lin&31;
    const int qch = q0+ql, hw = hw0+hl;
    const float s = rsg[qch]*rsqrtf(rsv[qch]+EPSF);
    const float t = rsb[qch] - rsm[qch]*s;
    const float v = fmaf(tile[hl][ql], s, t) + xres[(size_t)qch*LQ + hw];
    out[(size_t)img*CIN*LQ + (size_t)qch*LQ + hw] = v;
  }
}

extern "C" void kernel_launch(void* const* d_in, const int* in_sizes, int n_in,
                              void* d_out, int out_size, void* d_ws, size_t ws_size,
                              hipStream_t stream)
{
  const float* cr_w = (const float*)d_in[0];
  const float* cr_g = (const float*)d_in[1];
  const float* cr_b = (const float*)d_in[2];
  const float* cr_m = (const float*)d_in[3];
  const float* cr_v = (const float*)d_in[4];
  const float* rs_w = (const float*)d_in[5];
  const float* rs_g = (const float*)d_in[6];
  const float* rs_b = (const float*)d_in[7];
  const float* rs_m = (const float*)d_in[8];
  const float* rs_v = (const float*)d_in[9];
  const float* mV_ln_g = (const float*)d_in[10];
  const float* mV_ln_b = (const float*)d_in[11];
  const float* mV_in_w = (const float*)d_in[12];
  const float* mV_A    = (const float*)d_in[13];
  const float* mV_B    = (const float*)d_in[14];
  const float* mV_C    = (const float*)d_in[15];
  const float* mV_ow   = (const float*)d_in[16];
  const float* lpV_w1  = (const float*)d_in[17];
  const float* lpV_b1  = (const float*)d_in[18];
  const float* lpV_w2  = (const float*)d_in[19];
  const float* lpV_b2  = (const float*)d_in[20];
  const float* mI_ln_g = (const float*)d_in[21];
  const float* mI_ln_b = (const float*)d_in[22];
  const float* mI_in_w = (const float*)d_in[23];
  const float* mI_A    = (const float*)d_in[24];
  const float* mI_B    = (const float*)d_in[25];
  const float* mI_C    = (const float*)d_in[26];
  const float* mI_ow   = (const float*)d_in[27];
  const float* lpI_w1  = (const float*)d_in[28];
  const float* lpI_b1  = (const float*)d_in[29];
  const float* lpI_w2  = (const float*)d_in[30];
  const float* lpI_b2  = (const float*)d_in[31];
  const float* x_V = (const float*)d_in[32];
  const float* x_I = (const float*)d_in[33];
  float* out = (float*)d_out;

  char* ws = (char*)d_ws;
  float* xr    = (float*)(ws + 0);            // [2][2048][512] f32   8,388,608 B
  float* stats = (float*)(ws + 8388608);      // [4096][2] f32          32,768 B
  float* lam   = (float*)(ws + 8421376);      // [4] f32
  u16*   xp    = (u16*)  (ws + 8421632);      // [2][2048][2048] bf16  16,777,216 B
  u16*   ysf   = (u16*)  (ws + 25198848);     // [4][2048][1024] bf16  16,777,216 B
  u16*   ysb   = (u16*)  (ws + 41976064);     // [4][2048][1024] bf16  16,777,216 B
  float* outp  = xr;                          // reuse (xr dead after k4a overwrite? no: outp used by k5/k6 only)
  float* fpre  = (float*)(ws + 25198848);     // reuse ysf region (dead after k5)
  u16*   hfin  = (u16*)  (ws + 0);            // [8][16][2048][16] bf16 = 8,388,608 B (aliases xr; xr dead after k3)
  float* part  = (float*)(ws + 8421632);      // [4][16][512] f32 (aliases xp; consumed before k3 writes xp)

  k1_convraise<<<dim3(16,8,4),  dim3(256), 0, stream>>>(x_V,x_I,cr_w,cr_g,cr_b,cr_m,cr_v,xr);
  k2_stats    <<<dim3(4096),    dim3(64),  0, stream>>>(xr, stats);
  k2_pool     <<<dim3(16,4),    dim3(256), 0, stream>>>(xr, part);
  k2_lambda   <<<dim3(4),       dim3(256), 0, stream>>>(part, lpV_w1,lpV_b1,lpV_w2,lpV_b2,
                                                              lpI_w1,lpI_b1,lpI_w2,lpI_b2, lam);
  k3_inproj   <<<dim3(32,32,2), dim3(256), 0, stream>>>(xr, stats, mV_ln_g,mV_ln_b,
                                                        mI_ln_g,mI_ln_b, mV_in_w, mI_in_w, xp);
  k4a_sweep1  <<<dim3(8,16,8),  dim3(256), 0, stream>>>(xp, mV_A, mI_A, mV_B, mI_B, hfin);
  k4b_prefix  <<<dim3(8,8),     dim3(256), 0, stream>>>(mV_A, mI_A, hfin);
  k4c_sweep2  <<<dim3(8,16,8),  dim3(256), 0, stream>>>(xp, hfin, mV_A, mI_A, mV_B, mI_B,
                                                        mV_C, mI_C, ysf, ysb);
  k5_outproj  <<<dim3(32,8,2),  dim3(256), 0, stream>>>(ysf, ysb, xp, lam, mV_ow, mI_ow, outp);
  k6_rs       <<<dim3(32,4,2),  dim3(256), 0, stream>>>(outp, rs_w, fpre);
  k7_final    <<<dim3(32,8,4),  dim3(256), 0, stream>>>(fpre, x_V, x_I, rs_g, rs_b, rs_m, rs_v, out);
}

// Round 3
// 235.073 us; speedup vs baseline: 2.9009x; 1.6586x over previous
//
#include <hip/hip_runtime.h>
#include <math.h>

typedef unsigned short u16;
typedef unsigned int   u32;
typedef __bf16 bf16x8 __attribute__((ext_vector_type(8)));
typedef float  f32x4  __attribute__((ext_vector_type(4)));

#define PP   2
#define LQ   1024     // H*W
#define DM   512      // d_model
#define DI   1024     // d_inner
#define NS   16       // d_state
#define CIN  256
#define EPSF 1e-5f
#define CH   16       // scan chunks
#define TL   64       // chunk length (CH*TL == LQ)
#define LDK  40       // padded LDS row length (bf16 elems): 80 B = 5*16B, breaks pow2 bank stride

__device__ __forceinline__ float bf2f(u16 u){ return __uint_as_float(((u32)u)<<16); }
__device__ __forceinline__ u16 f2bf(float f){
  u32 x = __float_as_uint(f);
  x += 0x7fffu + ((x>>16)&1u);           // RNE
  return (u16)(x>>16);
}
__device__ __forceinline__ float sigm(float x){ return 1.f/(1.f+expf(-x)); }

// 8 bf16 <-> 8 f32 (16B vector)
__device__ __forceinline__ void ld8(const u16* p, float* f){
  const uint4 v = *(const uint4*)p;
  f[0]=bf2f((u16)v.x); f[1]=bf2f((u16)(v.x>>16));
  f[2]=bf2f((u16)v.y); f[3]=bf2f((u16)(v.y>>16));
  f[4]=bf2f((u16)v.z); f[5]=bf2f((u16)(v.z>>16));
  f[6]=bf2f((u16)v.w); f[7]=bf2f((u16)(v.w>>16));
}
__device__ __forceinline__ void st8(u16* p, const float* f){
  uint4 v;
  v.x = (u32)f2bf(f[0]) | ((u32)f2bf(f[1])<<16);
  v.y = (u32)f2bf(f[2]) | ((u32)f2bf(f[3])<<16);
  v.z = (u32)f2bf(f[4]) | ((u32)f2bf(f[5])<<16);
  v.w = (u32)f2bf(f[6]) | ((u32)f2bf(f[7])<<16);
  *(uint4*)p = v;
}

// MFMA fragment read: lane l takes 8 contiguous bf16 at row (base), k-chunk (l>>4)*8.
__device__ __forceinline__ bf16x8 lds_frag(const u16* tile, int row, int lane){
  return *(const bf16x8*)(tile + row*LDK + ((lane>>4)<<3));
}

// One BK=32 step: 4 m-frags x NI n-frags per wave (wave tile 64 x NI*16)
template<int NI>
__device__ __forceinline__ void mfma_step(const u16* As, const u16* Bs,
                                          f32x4 acc[4][NI], int m_off, int n_off, int lane){
  bf16x8 a[4], b[NI];
  #pragma unroll
  for (int mi=0;mi<4;++mi) a[mi] = lds_frag(As, m_off + mi*16 + (lane&15), lane);
  #pragma unroll
  for (int ni=0;ni<NI;++ni) b[ni] = lds_frag(Bs, n_off + ni*16 + (lane&15), lane);
  #pragma unroll
  for (int mi=0;mi<4;++mi)
    #pragma unroll
    for (int ni=0;ni<NI;++ni)
      acc[mi][ni] = __builtin_amdgcn_mfma_f32_16x16x32_bf16(a[mi], b[ni], acc[mi][ni], 0, 0, 0);
}

// ---- shared 64x64x16 fp32 MAC tile (k1 only) ----
__device__ __forceinline__ void mac_tile(const float (*As)[68], const float (*Bs)[68],
                                         float acc[4][4], int tx, int ty)
{
  #pragma unroll
  for (int kk=0;kk<16;++kk){
    float av[4], bv[4];
    #pragma unroll
    for (int i=0;i<4;++i) av[i]=As[kk][ty*4+i];
    #pragma unroll
    for (int j=0;j<4;++j) bv[j]=Bs[kk][tx*4+j];
    #pragma unroll
    for (int i=0;i<4;++i)
      #pragma unroll
      for (int j=0;j<4;++j) acc[i][j] = fmaf(av[i], bv[j], acc[i][j]);
  }
}

// K1: xr[p][b][hw][o] = relu(bn(sum_c X[c][hw]*crw[o][c]))
__global__ __launch_bounds__(256) void k1_convraise(
    const float* __restrict__ xV, const float* __restrict__ xI,
    const float* __restrict__ crw, const float* __restrict__ crg,
    const float* __restrict__ crb, const float* __restrict__ crm,
    const float* __restrict__ crv, float* __restrict__ xr)
{
  const int img = blockIdx.z, p = img>>1, b = img&1;
  const float* __restrict__ X = (p ? xI : xV) + (size_t)b*CIN*LQ;
  const int m0 = blockIdx.x*64, n0 = blockIdx.y*64;
  __shared__ float As[16][68];
  __shared__ float Bs[16][68];
  const int tid = threadIdx.x, tx = tid&15, ty = tid>>4;
  float acc[4][4] = {};
  for (int k0=0; k0<CIN; k0+=16){
    {
      const int kk = tid>>4, mm = (tid&15)*4;
      const float4 v = *(const float4*)(X + (size_t)(k0+kk)*LQ + m0 + mm);
      *(float4*)&As[kk][mm] = v;
      const int nn = tid>>2, k4 = (tid&3)*4;
      const float4 w = *(const float4*)(crw + (size_t)(n0+nn)*CIN + k0 + k4);
      Bs[k4+0][nn]=w.x; Bs[k4+1][nn]=w.y; Bs[k4+2][nn]=w.z; Bs[k4+3][nn]=w.w;
    }
    __syncthreads();
    mac_tile(As, Bs, acc, tx, ty);
    __syncthreads();
  }
  #pragma unroll
  for (int i=0;i<4;++i){
    const int m = m0 + ty*4 + i;
    float4 o; float* po = (float*)&o;
    #pragma unroll
    for (int j=0;j<4;++j){
      const int n = n0 + tx*4 + j;
      const float s = crg[n]*rsqrtf(crv[n]+EPSF);
      const float t = crb[n] - crm[n]*s;
      po[j] = fmaxf(fmaf(acc[i][j], s, t), 0.f);
    }
    *(float4*)(xr + ((size_t)img*LQ + m)*DM + n0 + tx*4) = o;
  }
}

// K2b: per-row (p,b,hw) layernorm stats over DM
__global__ __launch_bounds__(64) void k2_stats(const float* __restrict__ xr,
                                               float* __restrict__ stats)
{
  const int row = blockIdx.x;        // p*2048 + m
  const int lane = threadIdx.x;
  const float* __restrict__ base = xr + (size_t)row*DM;
  float s=0.f, q=0.f;
  #pragma unroll
  for (int j=0;j<8;j+=4){
    const float4 v = *(const float4*)(base + lane*8 + j);
    s += v.x+v.y+v.z+v.w;
    q += v.x*v.x+v.y*v.y+v.z*v.z+v.w*v.w;
  }
  #pragma unroll
  for (int off=32; off; off>>=1){ s += __shfl_down(s,off); q += __shfl_down(q,off); }
  if (lane==0){
    const float mean = s*(1.f/DM);
    const float var  = fmaxf(q*(1.f/DM) - mean*mean, 0.f);
    stats[row*2+0] = mean;
    stats[row*2+1] = rsqrtf(var+EPSF);
  }
}

// K2p: part[img][sl][ch] = sum over 64 t of xr[img][sl*64+t][ch]
__global__ __launch_bounds__(256) void k2_pool(const float* __restrict__ xr,
                                               float* __restrict__ part)
{
  const int img = blockIdx.y, sl = blockIdx.x;
  const int tid = threadIdx.x;
  const float* __restrict__ base = xr + ((size_t)img*LQ + sl*64)*DM;
  float s0=0.f, s1=0.f;
  for (int t=0;t<64;++t){
    s0 += base[(size_t)t*DM + tid];
    s1 += base[(size_t)t*DM + 256 + tid];
  }
  part[((size_t)img*16 + sl)*DM + tid]       = s0;
  part[((size_t)img*16 + sl)*DM + 256 + tid] = s1;
}

// K2: lam[img] = sigmoid(relu(pool@w1^T+b1)@w2^T+b2)
__global__ __launch_bounds__(256) void k2_lambda(
    const float* __restrict__ part,
    const float* __restrict__ w1V, const float* __restrict__ b1V,
    const float* __restrict__ w2V, const float* __restrict__ b2V,
    const float* __restrict__ w1I, const float* __restrict__ b1I,
    const float* __restrict__ w2I, const float* __restrict__ b2I,
    float* __restrict__ lam)
{
  const int img = blockIdx.x, p = img>>1;
  const float* __restrict__ w1 = p? w1I : w1V;
  const float* __restrict__ b1 = p? b1I : b1V;
  const float* __restrict__ w2 = p? w2I : w2V;
  const float* __restrict__ b2 = p? b2I : b2V;
  __shared__ float pool[DM];
  __shared__ float hb[128];
  const int tid = threadIdx.x;
  for (int ch=tid; ch<DM; ch+=256){
    float s=0.f;
    #pragma unroll
    for (int sl=0; sl<16; ++sl) s += part[((size_t)img*16 + sl)*DM + ch];
    pool[ch] = s * (1.f/LQ);
  }
  __syncthreads();
  if (tid<128){
    float h = b1[tid];
    const float* __restrict__ wr = w1 + (size_t)tid*DM;
    for (int o=0;o<DM;o+=4){
      const float4 w = *(const float4*)(wr+o);
      h += pool[o]*w.x + pool[o+1]*w.y + pool[o+2]*w.z + pool[o+3]*w.w;
    }
    hb[tid] = fmaxf(h,0.f);
  }
  __syncthreads();
  if (tid==0){
    float v = b2[0];
    for (int j=0;j<128;++j) v += hb[j]*w2[j];
    lam[img] = sigm(v);
  }
}

// K3 (MFMA): xp[p][m][n] = bf16( LN(xr[p][m][:]) . in_w[n][:] ),  M=2048 N=2048 K=512
__global__ __launch_bounds__(256) void k3_mfma(
    const float* __restrict__ xr, const float* __restrict__ stats,
    const float* __restrict__ lgV, const float* __restrict__ lbV,
    const float* __restrict__ lgI, const float* __restrict__ lbI,
    const float* __restrict__ iwV, const float* __restrict__ iwI,
    u16* __restrict__ xp)
{
  const int p = blockIdx.z;
  const float* __restrict__ A  = xr + (size_t)p*2048*DM;
  const float* __restrict__ st = stats + (size_t)p*2048*2;
  const float* __restrict__ lg = p? lgI : lgV;
  const float* __restrict__ lb = p? lbI : lbV;
  const float* __restrict__ Bw = p? iwI : iwV;
  const int m0 = blockIdx.x*128, n0 = blockIdx.y*128;
  __shared__ __align__(16) u16 As[128*LDK];
  __shared__ __align__(16) u16 Bs[128*LDK];
  const int tid = threadIdx.x, lane = tid&63, wid = tid>>6;
  const int m_off = (wid>>1)*64, n_off = (wid&1)*64;
  const int r = tid>>1, chs = (tid&1)*16;
  const float mean = st[(m0+r)*2+0], rstd = st[(m0+r)*2+1];
  const float* __restrict__ arow = A  + (size_t)(m0+r)*DM;
  const float* __restrict__ brow = Bw + (size_t)(n0+r)*DM;
  f32x4 acc[4][4];
  const f32x4 z = {0.f,0.f,0.f,0.f};
  #pragma unroll
  for (int mi=0;mi<4;++mi) for (int ni=0;ni<4;++ni) acc[mi][ni]=z;
  for (int k0=0;k0<DM;k0+=32){
    float va[16], vb[16];
    #pragma unroll
    for (int j=0;j<16;j+=4){
      const float4 v  = *(const float4*)(arow + k0 + chs + j);
      const float4 g  = *(const float4*)(lg   + k0 + chs + j);
      const float4 be = *(const float4*)(lb   + k0 + chs + j);
      va[j+0]=(v.x-mean)*rstd*g.x+be.x;
      va[j+1]=(v.y-mean)*rstd*g.y+be.y;
      va[j+2]=(v.z-mean)*rstd*g.z+be.z;
      va[j+3]=(v.w-mean)*rstd*g.w+be.w;
      const float4 w  = *(const float4*)(brow + k0 + chs + j);
      vb[j+0]=w.x; vb[j+1]=w.y; vb[j+2]=w.z; vb[j+3]=w.w;
    }
    st8(&As[r*LDK+chs], va); st8(&As[r*LDK+chs+8], va+8);
    st8(&Bs[r*LDK+chs], vb); st8(&Bs[r*LDK+chs+8], vb+8);
    __syncthreads();
    mfma_step<4>(As, Bs, acc, m_off, n_off, lane);
    __syncthreads();
  }
  u16* __restrict__ orow = xp + (size_t)p*2048*2048;
  #pragma unroll
  for (int mi=0;mi<4;++mi){
    #pragma unroll
    for (int rr=0;rr<4;++rr){
      const int m = m0 + m_off + mi*16 + ((lane>>4)<<2) + rr;
      #pragma unroll
      for (int ni=0;ni<4;++ni){
        const int n = n0 + n_off + ni*16 + (lane&15);
        orow[(size_t)m*2048 + n] = f2bf(acc[mi][ni][rr]);
      }
    }
  }
}

// ---- chunked scan: k4a local sweep -> k4b chunk prefix -> k4c final sweep ----
__global__ __launch_bounds__(256) void k4a_sweep1(
    const u16* __restrict__ xp,
    const float* __restrict__ AlV, const float* __restrict__ AlI,
    const float* __restrict__ BV,  const float* __restrict__ BI,
    u16* __restrict__ hfin)
{
  const int z = blockIdx.z, inst = z>>1, dir = z&1;
  const int p = inst>>1, sel = inst&1;
  const int c = blockIdx.y;
  const int row = blockIdx.x*256 + threadIdx.x;
  const int b = row>>10, i = row&1023;
  const float* __restrict__ Al = p? AlI : AlV;
  const float* __restrict__ Bm = (p^sel)? BI : BV;
  float a[16], bc[16], h[16];
  #pragma unroll
  for (int s=0;s<16;s+=4){
    const float4 al = *(const float4*)(Al + (size_t)i*NS + s);
    const float4 bv = *(const float4*)(Bm + (size_t)i*NS + s);
    a[s]=-expf(al.x); a[s+1]=-expf(al.y); a[s+2]=-expf(al.z); a[s+3]=-expf(al.w);
    bc[s]=bv.x; bc[s+1]=bv.y; bc[s+2]=bv.z; bc[s+3]=bv.w;
    h[s]=0.f; h[s+1]=0.f; h[s+2]=0.f; h[s+3]=0.f;
  }
  const u16* xptr = xp + ((size_t)(p*2048 + b*1024 + c*TL + (dir?TL-1:0)))*2048 + i;
  const ptrdiff_t xstep = dir ? -2048 : 2048;
  #pragma unroll 4
  for (int tt=0; tt<TL; ++tt){
    const float x = bf2f(*xptr);
    #pragma unroll
    for (int s=0;s<16;++s) h[s] = fmaf(h[s], a[s], x*bc[s]);
    xptr += xstep;
  }
  u16* hp = hfin + (((size_t)z*CH + c)*2048 + row)*NS;
  st8(hp, h); st8(hp+8, h+8);
}

__global__ __launch_bounds__(256) void k4b_prefix(
    const float* __restrict__ AlV, const float* __restrict__ AlI,
    u16* __restrict__ hfin)
{
  const int z = blockIdx.y, inst = z>>1, dir = z&1, p = inst>>1;
  const int row = blockIdx.x*256 + threadIdx.x;
  const int i = row & 1023;
  const float* __restrict__ Al = p? AlI : AlV;
  float a64[16], H[16];
  #pragma unroll
  for (int s=0;s<16;s+=4){
    const float4 al = *(const float4*)(Al + (size_t)i*NS + s);
    a64[s]  =expf(64.f*al.x); a64[s+1]=expf(64.f*al.y);
    a64[s+2]=expf(64.f*al.z); a64[s+3]=expf(64.f*al.w);
    H[s]=0.f; H[s+1]=0.f; H[s+2]=0.f; H[s+3]=0.f;
  }
  for (int k=0;k<CH;++k){
    const int c = dir ? (CH-1-k) : k;
    u16* hp = hfin + (((size_t)z*CH + c)*2048 + row)*NS;
    float fin[16];
    ld8(hp, fin); ld8(hp+8, fin+8);
    st8(hp, H);  st8(hp+8, H+8);
    #pragma unroll
    for (int s=0;s<16;++s) H[s] = fmaf(a64[s], H[s], fin[s]);
  }
}

__global__ __launch_bounds__(256) void k4c_sweep2(
    const u16* __restrict__ xp, const u16* __restrict__ hfin,
    const float* __restrict__ AlV, const float* __restrict__ AlI,
    const float* __restrict__ BV,  const float* __restrict__ BI,
    const float* __restrict__ CV,  const float* __restrict__ CI,
    u16* __restrict__ ysf, u16* __restrict__ ysb)
{
  const int z = blockIdx.z, inst = z>>1, dir = z&1;
  const int p = inst>>1, sel = inst&1;
  const int c = blockIdx.y;
  const int row = blockIdx.x*256 + threadIdx.x;
  const int b = row>>10, i = row&1023;
  const float* __restrict__ Al = p? AlI : AlV;
  const float* __restrict__ Bm = (p^sel)? BI : BV;
  const float* __restrict__ Cm = p? CI : CV;
  float a[16], bc[16], cc[16], h[16];
  #pragma unroll
  for (int s=0;s<16;s+=4){
    const float4 al = *(const float4*)(Al + (size_t)i*NS + s);
    const float4 bv = *(const float4*)(Bm + (size_t)i*NS + s);
    const float4 cv = *(const float4*)(Cm + (size_t)i*NS + s);
    a[s]=-expf(al.x); a[s+1]=-expf(al.y); a[s+2]=-expf(al.z); a[s+3]=-expf(al.w);
    bc[s]=bv.x; bc[s+1]=bv.y; bc[s+2]=bv.z; bc[s+3]=bv.w;
    cc[s]=cv.x; cc[s+1]=cv.y; cc[s+2]=cv.z; cc[s+3]=cv.w;
  }
  const u16* hp = hfin + (((size_t)z*CH + c)*2048 + row)*NS;
  ld8(hp, h); ld8(hp+8, h+8);
  const u16* xptr = xp + ((size_t)(p*2048 + b*1024 + c*TL + (dir?TL-1:0)))*2048 + i;
  const ptrdiff_t xstep = dir ? -2048 : 2048;
  u16* yptr = (dir ? ysb : ysf)
            + ((size_t)inst*2048 + b*1024 + c*TL + (dir?TL-1:0))*(size_t)DI + i;
  const ptrdiff_t ystep = dir ? -DI : DI;
  #pragma unroll 2
  for (int tt=0; tt<TL; ++tt){
    const float x = bf2f(*xptr);
    float p0=0.f,p1=0.f,p2=0.f,p3=0.f;
    #pragma unroll
    for (int s=0;s<16;s+=4){
      h[s]   = fmaf(h[s],   a[s],   x*bc[s]);
      h[s+1] = fmaf(h[s+1], a[s+1], x*bc[s+1]);
      h[s+2] = fmaf(h[s+2], a[s+2], x*bc[s+2]);
      h[s+3] = fmaf(h[s+3], a[s+3], x*bc[s+3]);
      p0 = fmaf(h[s],   cc[s],   p0);
      p1 = fmaf(h[s+1], cc[s+1], p1);
      p2 = fmaf(h[s+2], cc[s+2], p2);
      p3 = fmaf(h[s+3], cc[s+3], p3);
    }
    *yptr = f2bf((p0+p1)+(p2+p3));
    xptr += xstep; yptr += ystep;
  }
}

// K5 (MFMA): outp[p][m][n] = comb[p][m][:] . out_w[n][:],  M=2048 N=512 K=1024
__global__ __launch_bounds__(256) void k5_mfma(
    const u16* __restrict__ ysf, const u16* __restrict__ ysb,
    const u16* __restrict__ xp, const float* __restrict__ lam,
    const float* __restrict__ owV, const float* __restrict__ owI,
    float* __restrict__ outp)
{
  const int p = blockIdx.z;
  const float* __restrict__ Bw = p? owI : owV;
  const int m0 = blockIdx.x*128, n0 = blockIdx.y*64;
  __shared__ __align__(16) u16 As[128*LDK];
  __shared__ __align__(16) u16 Bs[64*LDK];
  const int tid = threadIdx.x, lane = tid&63, wid = tid>>6;
  const int m_off = (wid>>1)*64, n_off = (wid&1)*32;
  const int r = tid>>1, chs = (tid&1)*16;
  const int m = m0 + r;
  const float lm = lam[p*2 + (m>>10)];
  const size_t b_std = ((size_t)(p*2+0)*2048 + m)*(size_t)DI;
  const size_t b_x   = ((size_t)(p*2+1)*2048 + m)*(size_t)DI;
  const size_t b_g   = ((size_t)p*2048 + m)*2048 + DI;
  const int rb = tid>>2, ch2 = (tid&3)*8;
  const float* __restrict__ browb = Bw + (size_t)(n0+rb)*DI;
  f32x4 acc[4][2];
  const f32x4 z = {0.f,0.f,0.f,0.f};
  #pragma unroll
  for (int mi=0;mi<4;++mi) for (int ni=0;ni<2;++ni) acc[mi][ni]=z;
  for (int k0=0;k0<DI;k0+=32){
    float va[16];
    #pragma unroll
    for (int h=0;h<16;h+=8){
      float f0[8], f1[8], x0[8], x1[8], gg[8];
      ld8(ysf + b_std + k0+chs+h, f0);
      ld8(ysb + b_std + k0+chs+h, f1);
      ld8(ysf + b_x   + k0+chs+h, x0);
      ld8(ysb + b_x   + k0+chs+h, x1);
      ld8(xp  + b_g   + k0+chs+h, gg);
      #pragma unroll
      for (int j=0;j<8;++j){
        const float ys = f0[j]+f1[j];
        const float yx = x0[j]+x1[j];
        const float g  = gg[j];
        va[h+j] = 0.5f*g*sigm(g)*(lm*ys + (1.f-lm)*yx);
      }
    }
    st8(&As[r*LDK+chs], va); st8(&As[r*LDK+chs+8], va+8);
    {
      float vb[8];
      const float4 w0 = *(const float4*)(browb + k0 + ch2);
      const float4 w1 = *(const float4*)(browb + k0 + ch2 + 4);
      vb[0]=w0.x; vb[1]=w0.y; vb[2]=w0.z; vb[3]=w0.w;
      vb[4]=w1.x; vb[5]=w1.y; vb[6]=w1.z; vb[7]=w1.w;
      st8(&Bs[rb*LDK+ch2], vb);
    }
    __syncthreads();
    mfma_step<2>(As, Bs, acc, m_off, n_off, lane);
    __syncthreads();
  }
  #pragma unroll
  for (int mi=0;mi<4;++mi){
    #pragma unroll
    for (int rr=0;rr<4;++rr){
      const int mm = m0 + m_off + mi*16 + ((lane>>4)<<2) + rr;
      #pragma unroll
      for (int ni=0;ni<2;++ni){
        const int n = n0 + n_off + ni*16 + (lane&15);
        outp[((size_t)p*2048+mm)*DM + n] = acc[mi][ni][rr];
      }
    }
  }
}

// K6 (MFMA): fpre[p][m][q] = outp[p][m][:] . rs_w[q][:],  M=2048 N=256 K=512
__global__ __launch_bounds__(256) void k6_mfma(
    const float* __restrict__ outp, const float* __restrict__ rsw,
    float* __restrict__ fpre)
{
  const int p = blockIdx.z;
  const int m0 = blockIdx.x*128, n0 = blockIdx.y*64;
  __shared__ __align__(16) u16 As[128*LDK];
  __shared__ __align__(16) u16 Bs[64*LDK];
  const int tid = threadIdx.x, lane = tid&63, wid = tid>>6;
  const int m_off = (wid>>1)*64, n_off = (wid&1)*32;
  const int r = tid>>1, chs = (tid&1)*16;
  const float* __restrict__ arow = outp + ((size_t)p*2048 + m0 + r)*DM;
  const int rb = tid>>2, ch2 = (tid&3)*8;
  const float* __restrict__ browb = rsw + (size_t)(n0+rb)*DM;
  f32x4 acc[4][2];
  const f32x4 z = {0.f,0.f,0.f,0.f};
  #pragma unroll
  for (int mi=0;mi<4;++mi) for (int ni=0;ni<2;++ni) acc[mi][ni]=z;
  for (int k0=0;k0<DM;k0+=32){
    float va[16];
    #pragma unroll
    for (int j=0;j<16;j+=4){
      const float4 v = *(const float4*)(arow + k0 + chs + j);
      va[j+0]=v.x; va[j+1]=v.y; va[j+2]=v.z; va[j+3]=v.w;
    }
    st8(&As[r*LDK+chs], va); st8(&As[r*LDK+chs+8], va+8);
    {
      float vb[8];
      const float4 w0 = *(const float4*)(browb + k0 + ch2);
      const float4 w1 = *(const float4*)(browb + k0 + ch2 + 4);
      vb[0]=w0.x; vb[1]=w0.y; vb[2]=w0.z; vb[3]=w0.w;
      vb[4]=w1.x; vb[5]=w1.y; vb[6]=w1.z; vb[7]=w1.w;
      st8(&Bs[rb*LDK+ch2], vb);
    }
    __syncthreads();
    mfma_step<2>(As, Bs, acc, m_off, n_off, lane);
    __syncthreads();
  }
  #pragma unroll
  for (int mi=0;mi<4;++mi){
    #pragma unroll
    for (int rr=0;rr<4;++rr){
      const int mm = m0 + m_off + mi*16 + ((lane>>4)<<2) + rr;
      #pragma unroll
      for (int ni=0;ni<2;++ni){
        const int n = n0 + n_off + ni*16 + (lane&15);
        fpre[((size_t)p*2048+mm)*CIN + n] = acc[mi][ni][rr];
      }
    }
  }
}

// K7: out[p][b][q][hw] = x[p][b][q][hw] + bn(fpre[p][b*1024+hw][q])
__global__ __launch_bounds__(256) void k7_final(
    const float* __restrict__ fpre, const float* __restrict__ xV, const float* __restrict__ xI,
    const float* __restrict__ rsg, const float* __restrict__ rsb,
    const float* __restrict__ rsm, const float* __restrict__ rsv,
    float* __restrict__ out)
{
  const int img = blockIdx.z, p = img>>1, b = img&1;
  const int hw0 = blockIdx.x*32, q0 = blockIdx.y*32;
  const float* __restrict__ xres = (p? xI : xV) + (size_t)b*CIN*LQ;
  __shared__ float tile[32][33];
  const int tid = threadIdx.x;
  {
    const int r = tid>>3, c = (tid&7)*4;
    const float4 v = *(const float4*)(fpre + ((size_t)p*2048 + b*1024 + hw0 + r)*CIN + q0 + c);
    tile[r][c]=v.x; tile[r][c+1]=v.y; tile[r][c+2]=v.z; tile[r][c+3]=v.w;
  }
  __syncthreads();
  #pragma unroll
  for (int k=0;k<4;++k){
    const int lin = k*256 + tid;
    const int ql = lin>>5, hl = lin&31;
    const int qch = q0+ql, hw = hw0+hl;
    const float s = rsg[qch]*rsqrtf(rsv[qch]+EPSF);
    const float t = rsb[qch] - rsm[qch]*s;
    const float v = fmaf(tile[hl][ql], s, t) + xres[(size_t)qch*LQ + hw];
    out[(size_t)img*CIN*LQ + (size_t)qch*LQ + hw] = v;
  }
}

extern "C" void kernel_launch(void* const* d_in, const int* in_sizes, int n_in,
                              void* d_out, int out_size, void* d_ws, size_t ws_size,
                              hipStream_t stream)
{
  const float* cr_w = (const float*)d_in[0];
  const float* cr_g = (const float*)d_in[1];
  const float* cr_b = (const float*)d_in[2];
  const float* cr_m = (const float*)d_in[3];
  const float* cr_v = (const float*)d_in[4];
  const float* rs_w = (const float*)d_in[5];
  const float* rs_g = (const float*)d_in[6];
  const float* rs_b = (const float*)d_in[7];
  const float* rs_m = (const float*)d_in[8];
  const float* rs_v = (const float*)d_in[9];
  const float* mV_ln_g = (const float*)d_in[10];
  const float* mV_ln_b = (const float*)d_in[11];
  const float* mV_in_w = (const float*)d_in[12];
  const float* mV_A    = (const float*)d_in[13];
  const float* mV_B    = (const float*)d_in[14];
  const float* mV_C    = (const float*)d_in[15];
  const float* mV_ow   = (const float*)d_in[16];
  const float* lpV_w1  = (const float*)d_in[17];
  const float* lpV_b1  = (const float*)d_in[18];
  const float* lpV_w2  = (const float*)d_in[19];
  const float* lpV_b2  = (const float*)d_in[20];
  const float* mI_ln_g = (const float*)d_in[21];
  const float* mI_ln_b = (const float*)d_in[22];
  const float* mI_in_w = (const float*)d_in[23];
  const float* mI_A    = (const float*)d_in[24];
  const float* mI_B    = (const float*)d_in[25];
  const float* mI_C    = (const float*)d_in[26];
  const float* mI_ow   = (const float*)d_in[27];
  const float* lpI_w1  = (const float*)d_in[28];
  const float* lpI_b1  = (const float*)d_in[29];
  const float* lpI_w2  = (const float*)d_in[30];
  const float* lpI_b2  = (const float*)d_in[31];
  const float* x_V = (const float*)d_in[32];
  const float* x_I = (const float*)d_in[33];
  float* out = (float*)d_out;

  char* ws = (char*)d_ws;
  float* xr    = (float*)(ws + 0);            // [2][2048][512] f32   8,388,608 B
  float* stats = (float*)(ws + 8388608);      // [4096][2] f32          32,768 B
  float* lam   = (float*)(ws + 8421376);      // [4] f32
  u16*   xp    = (u16*)  (ws + 8421632);      // [2][2048][2048] bf16  16,777,216 B
  u16*   ysf   = (u16*)  (ws + 25198848);     // [4][2048][1024] bf16  16,777,216 B
  u16*   ysb   = (u16*)  (ws + 41976064);     // [4][2048][1024] bf16  16,777,216 B
  float* outp  = xr;                          // reuse (xr dead after k3; hfin dead after k4c)
  float* fpre  = (float*)(ws + 25198848);     // reuse ysf region (dead after k5)
  u16*   hfin  = (u16*)  (ws + 0);            // [8][16][2048][16] bf16 = 8,388,608 B (aliases xr)
  float* part  = (float*)(ws + 8421632);      // [4][16][512] f32 (aliases xp; consumed before k3)

  k1_convraise<<<dim3(16,8,4),  dim3(256), 0, stream>>>(x_V,x_I,cr_w,cr_g,cr_b,cr_m,cr_v,xr);
  k2_stats    <<<dim3(4096),    dim3(64),  0, stream>>>(xr, stats);
  k2_pool     <<<dim3(16,4),    dim3(256), 0, stream>>>(xr, part);
  k2_lambda   <<<dim3(4),       dim3(256), 0, stream>>>(part, lpV_w1,lpV_b1,lpV_w2,lpV_b2,
                                                              lpI_w1,lpI_b1,lpI_w2,lpI_b2, lam);
  k3_mfma     <<<dim3(16,16,2), dim3(256), 0, stream>>>(xr, stats, mV_ln_g,mV_ln_b,
                                                        mI_ln_g,mI_ln_b, mV_in_w, mI_in_w, xp);
  k4a_sweep1  <<<dim3(8,16,8),  dim3(256), 0, stream>>>(xp, mV_A, mI_A, mV_B, mI_B, hfin);
  k4b_prefix  <<<dim3(8,8),     dim3(256), 0, stream>>>(mV_A, mI_A, hfin);
  k4c_sweep2  <<<dim3(8,16,8),  dim3(256), 0, stream>>>(xp, hfin, mV_A, mI_A, mV_B, mI_B,
                                                        mV_C, mI_C, ysf, ysb);
  k5_mfma     <<<dim3(16,8,2),  dim3(256), 0, stream>>>(ysf, ysb, xp, lam, mV_ow, mI_ow, outp);
  k6_mfma     <<<dim3(16,4,2),  dim3(256), 0, stream>>>(outp, rs_w, fpre);
  k7_final    <<<dim3(32,8,4),  dim3(256), 0, stream>>>(fpre, x_V, x_I, rs_g, rs_b, rs_m, rs_v, out);
}

// Round 4
// 186.487 us; speedup vs baseline: 3.6567x; 1.2605x over previous
//
#include <hip/hip_runtime.h>
#include <math.h>

typedef unsigned short u16;
typedef unsigned int   u32;
typedef __bf16 bf16x8 __attribute__((ext_vector_type(8)));
typedef float  f32x4  __attribute__((ext_vector_type(4)));

#define PP   2
#define LQ   1024     // H*W
#define DM   512      // d_model
#define DI   1024     // d_inner
#define NS   16       // d_state
#define CIN  256
#define EPSF 1e-5f
#define CH   16       // scan chunks
#define TL   64       // chunk length (CH*TL == LQ)
#define LDK  72       // padded LDS row (bf16): 144 B stride -> 2-way max on frag reads (free, m136)

__device__ __forceinline__ float bf2f(u16 u){ return __uint_as_float(((u32)u)<<16); }
__device__ __forceinline__ u16 f2bf(float f){
  u32 x = __float_as_uint(f);
  x += 0x7fffu + ((x>>16)&1u);           // RNE
  return (u16)(x>>16);
}
__device__ __forceinline__ float sigm(float x){ return 1.f/(1.f+expf(-x)); }

__device__ __forceinline__ void ld8(const u16* p, float* f){
  const uint4 v = *(const uint4*)p;
  f[0]=bf2f((u16)v.x); f[1]=bf2f((u16)(v.x>>16));
  f[2]=bf2f((u16)v.y); f[3]=bf2f((u16)(v.y>>16));
  f[4]=bf2f((u16)v.z); f[5]=bf2f((u16)(v.z>>16));
  f[6]=bf2f((u16)v.w); f[7]=bf2f((u16)(v.w>>16));
}
__device__ __forceinline__ void st8(u16* p, const float* f){
  uint4 v;
  v.x = (u32)f2bf(f[0]) | ((u32)f2bf(f[1])<<16);
  v.y = (u32)f2bf(f[2]) | ((u32)f2bf(f[3])<<16);
  v.z = (u32)f2bf(f[4]) | ((u32)f2bf(f[5])<<16);
  v.w = (u32)f2bf(f[6]) | ((u32)f2bf(f[7])<<16);
  *(uint4*)p = v;
}

// Stage a ROWS x 64 bf16 tile (row-major, source row stride srcK) into padded LDS.
template<int ROWS>
__device__ __forceinline__ void stage_bf16(const u16* __restrict__ src, size_t srcK,
                                           u16* __restrict__ dst, int k0, int tid)
{
  #pragma unroll
  for (int c = 0; c < ROWS*8; c += 256){
    const int cc = c + tid;
    const int row = cc>>3, pos = cc&7;
    *(uint4*)(dst + row*LDK + pos*8) = *(const uint4*)(src + (size_t)row*srcK + k0 + pos*8);
  }
}

// MFMA fragment: lane l -> row, k-chunk (l>>4)*8 within the 32-k step (+ks*32).
__device__ __forceinline__ bf16x8 frag(const u16* t, int row, int ks, int lane){
  return *(const bf16x8*)(t + row*LDK + ks*32 + ((lane>>4)<<3));
}

// ---- fp32 MAC tile (k1 only) ----
__device__ __forceinline__ void mac_tile(const float (*As)[68], const float (*Bs)[68],
                                         float acc[4][4], int tx, int ty)
{
  #pragma unroll
  for (int kk=0;kk<16;++kk){
    float av[4], bv[4];
    #pragma unroll
    for (int i=0;i<4;++i) av[i]=As[kk][ty*4+i];
    #pragma unroll
    for (int j=0;j<4;++j) bv[j]=Bs[kk][tx*4+j];
    #pragma unroll
    for (int i=0;i<4;++i)
      #pragma unroll
      for (int j=0;j<4;++j) acc[i][j] = fmaf(av[i], bv[j], acc[i][j]);
  }
}

// K0: weight f32 -> bf16 conversion (iwV, iwI, owV, owI, rsw)
__global__ __launch_bounds__(256) void k0_cvt(
    const float* __restrict__ s0, const float* __restrict__ s1,
    const float* __restrict__ s2, const float* __restrict__ s3,
    const float* __restrict__ s4,
    u16* __restrict__ d0, u16* __restrict__ d1, u16* __restrict__ d2,
    u16* __restrict__ d3, u16* __restrict__ d4)
{
  const int which = blockIdx.y;
  const float* s; u16* d; int n;
  switch(which){
    case 0: s=s0; d=d0; n=1048576; break;
    case 1: s=s1; d=d1; n=1048576; break;
    case 2: s=s2; d=d2; n=524288;  break;
    case 3: s=s3; d=d3; n=524288;  break;
    default: s=s4; d=d4; n=131072; break;
  }
  for (int i = (blockIdx.x*256+threadIdx.x)*4; i < n; i += gridDim.x*256*4){
    const float4 v = *(const float4*)(s+i);
    ushort4 o; o.x=f2bf(v.x); o.y=f2bf(v.y); o.z=f2bf(v.z); o.w=f2bf(v.w);
    *(ushort4*)(d+i) = o;
  }
}

// K1: xr[p][b][hw][o] = relu(bn(sum_c X[c][hw]*crw[o][c]))   (fp32 MAC)
__global__ __launch_bounds__(256) void k1_convraise(
    const float* __restrict__ xV, const float* __restrict__ xI,
    const float* __restrict__ crw, const float* __restrict__ crg,
    const float* __restrict__ crb, const float* __restrict__ crm,
    const float* __restrict__ crv, float* __restrict__ xr)
{
  const int img = blockIdx.z, p = img>>1, b = img&1;
  const float* __restrict__ X = (p ? xI : xV) + (size_t)b*CIN*LQ;
  const int m0 = blockIdx.x*64, n0 = blockIdx.y*64;
  __shared__ float As[16][68];
  __shared__ float Bs[16][68];
  const int tid = threadIdx.x, tx = tid&15, ty = tid>>4;
  float acc[4][4] = {};
  for (int k0=0; k0<CIN; k0+=16){
    {
      const int kk = tid>>4, mm = (tid&15)*4;
      const float4 v = *(const float4*)(X + (size_t)(k0+kk)*LQ + m0 + mm);
      *(float4*)&As[kk][mm] = v;
      const int nn = tid>>2, k4 = (tid&3)*4;
      const float4 w = *(const float4*)(crw + (size_t)(n0+nn)*CIN + k0 + k4);
      Bs[k4+0][nn]=w.x; Bs[k4+1][nn]=w.y; Bs[k4+2][nn]=w.z; Bs[k4+3][nn]=w.w;
    }
    __syncthreads();
    mac_tile(As, Bs, acc, tx, ty);
    __syncthreads();
  }
  #pragma unroll
  for (int i=0;i<4;++i){
    const int m = m0 + ty*4 + i;
    float4 o; float* po = (float*)&o;
    #pragma unroll
    for (int j=0;j<4;++j){
      const int n = n0 + tx*4 + j;
      const float s = crg[n]*rsqrtf(crv[n]+EPSF);
      const float t = crb[n] - crm[n]*s;
      po[j] = fmaxf(fmaf(acc[i][j], s, t), 0.f);
    }
    *(float4*)(xr + ((size_t)img*LQ + m)*DM + n0 + tx*4) = o;
  }
}

// K2ln: per-row LN over DM, write bf16 xn  (fused stats+normalize)
__global__ __launch_bounds__(64) void k2_ln(
    const float* __restrict__ xr,
    const float* __restrict__ lgV, const float* __restrict__ lbV,
    const float* __restrict__ lgI, const float* __restrict__ lbI,
    u16* __restrict__ xn)
{
  const int row = blockIdx.x;        // p*2048 + m
  const int p = row>>11;
  const int lane = threadIdx.x;
  const float* __restrict__ base = xr + (size_t)row*DM + lane*8;
  const float* __restrict__ lg = (p? lgI : lgV) + lane*8;
  const float* __restrict__ lb = (p? lbI : lbV) + lane*8;
  float v[8];
  *(float4*)&v[0] = *(const float4*)(base);
  *(float4*)&v[4] = *(const float4*)(base+4);
  float s=0.f, q=0.f;
  #pragma unroll
  for (int j=0;j<8;++j){ s += v[j]; q += v[j]*v[j]; }
  #pragma unroll
  for (int off=32; off; off>>=1){ s += __shfl_down(s,off); q += __shfl_down(q,off); }
  s = __shfl(s,0); q = __shfl(q,0);
  const float mean = s*(1.f/DM);
  const float rstd = rsqrtf(fmaxf(q*(1.f/DM) - mean*mean, 0.f)+EPSF);
  float g[8], be[8], y[8];
  *(float4*)&g[0]  = *(const float4*)(lg);
  *(float4*)&g[4]  = *(const float4*)(lg+4);
  *(float4*)&be[0] = *(const float4*)(lb);
  *(float4*)&be[4] = *(const float4*)(lb+4);
  #pragma unroll
  for (int j=0;j<8;++j) y[j] = (v[j]-mean)*rstd*g[j] + be[j];
  st8(xn + (size_t)row*DM + lane*8, y);
}

// K2p: part[img][sl][ch] = sum over 64 t of xr[img][sl*64+t][ch]
__global__ __launch_bounds__(256) void k2_pool(const float* __restrict__ xr,
                                               float* __restrict__ part)
{
  const int img = blockIdx.y, sl = blockIdx.x;
  const int tid = threadIdx.x;
  const float* __restrict__ base = xr + ((size_t)img*LQ + sl*64)*DM;
  float s0=0.f, s1=0.f;
  for (int t=0;t<64;++t){
    s0 += base[(size_t)t*DM + tid];
    s1 += base[(size_t)t*DM + 256 + tid];
  }
  part[((size_t)img*16 + sl)*DM + tid]       = s0;
  part[((size_t)img*16 + sl)*DM + 256 + tid] = s1;
}

// K2: lam[img] = sigmoid(relu(pool@w1^T+b1)@w2^T+b2)
__global__ __launch_bounds__(256) void k2_lambda(
    const float* __restrict__ part,
    const float* __restrict__ w1V, const float* __restrict__ b1V,
    const float* __restrict__ w2V, const float* __restrict__ b2V,
    const float* __restrict__ w1I, const float* __restrict__ b1I,
    const float* __restrict__ w2I, const float* __restrict__ b2I,
    float* __restrict__ lam)
{
  const int img = blockIdx.x, p = img>>1;
  const float* __restrict__ w1 = p? w1I : w1V;
  const float* __restrict__ b1 = p? b1I : b1V;
  const float* __restrict__ w2 = p? w2I : w2V;
  const float* __restrict__ b2 = p? b2I : b2V;
  __shared__ float pool[DM];
  __shared__ float hb[128];
  const int tid = threadIdx.x;
  for (int ch=tid; ch<DM; ch+=256){
    float s=0.f;
    #pragma unroll
    for (int sl=0; sl<16; ++sl) s += part[((size_t)img*16 + sl)*DM + ch];
    pool[ch] = s * (1.f/LQ);
  }
  __syncthreads();
  if (tid<128){
    float h = b1[tid];
    const float* __restrict__ wr = w1 + (size_t)tid*DM;
    for (int o=0;o<DM;o+=4){
      const float4 w = *(const float4*)(wr+o);
      h += pool[o]*w.x + pool[o+1]*w.y + pool[o+2]*w.z + pool[o+3]*w.w;
    }
    hb[tid] = fmaxf(h,0.f);
  }
  __syncthreads();
  if (tid==0){
    float v = b2[0];
    for (int j=0;j<128;++j) v += hb[j]*w2[j];
    lam[img] = sigm(v);
  }
}

// K3 (MFMA): xp[p][m][n] = bf16( xn[p][m][:] . iw[n][:] ),  M=2048 N=2048 K=512, BK=64
__global__ __launch_bounds__(256) void k3_mfma(
    const u16* __restrict__ xn, const u16* __restrict__ iwVb, const u16* __restrict__ iwIb,
    u16* __restrict__ xp)
{
  const int p = blockIdx.z;
  const u16* __restrict__ A  = xn + (size_t)p*2048*DM;
  const u16* __restrict__ Bw = p? iwIb : iwVb;
  const int m0 = blockIdx.x*128, n0 = blockIdx.y*128;
  __shared__ __align__(16) u16 As[128*LDK];
  __shared__ __align__(16) u16 Bs[128*LDK];
  const int tid = threadIdx.x, lane = tid&63, wid = tid>>6;
  const int m_off = (wid>>1)*64, n_off = (wid&1)*64;
  f32x4 acc[4][4];
  const f32x4 z = {0.f,0.f,0.f,0.f};
  #pragma unroll
  for (int mi=0;mi<4;++mi) for (int ni=0;ni<4;++ni) acc[mi][ni]=z;
  for (int k0=0;k0<DM;k0+=64){
    stage_bf16<128>(A  + (size_t)m0*DM, DM, As, k0, tid);
    stage_bf16<128>(Bw + (size_t)n0*DM, DM, Bs, k0, tid);
    __syncthreads();
    #pragma unroll
    for (int ks=0;ks<2;++ks){
      bf16x8 a[4], b[4];
      #pragma unroll
      for (int mi=0;mi<4;++mi) a[mi] = frag(As, m_off+mi*16+(lane&15), ks, lane);
      #pragma unroll
      for (int ni=0;ni<4;++ni) b[ni] = frag(Bs, n_off+ni*16+(lane&15), ks, lane);
      #pragma unroll
      for (int mi=0;mi<4;++mi)
        #pragma unroll
        for (int ni=0;ni<4;++ni)
          acc[mi][ni] = __builtin_amdgcn_mfma_f32_16x16x32_bf16(a[mi], b[ni], acc[mi][ni], 0,0,0);
    }
    __syncthreads();
  }
  u16* __restrict__ orow = xp + (size_t)p*2048*2048;
  #pragma unroll
  for (int mi=0;mi<4;++mi){
    #pragma unroll
    for (int rr=0;rr<4;++rr){
      const int m = m0 + m_off + mi*16 + ((lane>>4)<<2) + rr;
      #pragma unroll
      for (int ni=0;ni<4;++ni){
        const int n = n0 + n_off + ni*16 + (lane&15);
        orow[(size_t)m*2048 + n] = f2bf(acc[mi][ni][rr]);
      }
    }
  }
}

// ---- chunked scan ----
__global__ __launch_bounds__(256) void k4a_sweep1(
    const u16* __restrict__ xp,
    const float* __restrict__ AlV, const float* __restrict__ AlI,
    const float* __restrict__ BV,  const float* __restrict__ BI,
    u16* __restrict__ hfin)
{
  const int z = blockIdx.z, inst = z>>1, dir = z&1;
  const int p = inst>>1, sel = inst&1;
  const int c = blockIdx.y;
  const int row = blockIdx.x*256 + threadIdx.x;
  const int b = row>>10, i = row&1023;
  const float* __restrict__ Al = p? AlI : AlV;
  const float* __restrict__ Bm = (p^sel)? BI : BV;
  float a[16], bc[16], h[16];
  #pragma unroll
  for (int s=0;s<16;s+=4){
    const float4 al = *(const float4*)(Al + (size_t)i*NS + s);
    const float4 bv = *(const float4*)(Bm + (size_t)i*NS + s);
    a[s]=-expf(al.x); a[s+1]=-expf(al.y); a[s+2]=-expf(al.z); a[s+3]=-expf(al.w);
    bc[s]=bv.x; bc[s+1]=bv.y; bc[s+2]=bv.z; bc[s+3]=bv.w;
    h[s]=0.f; h[s+1]=0.f; h[s+2]=0.f; h[s+3]=0.f;
  }
  const u16* xptr = xp + ((size_t)(p*2048 + b*1024 + c*TL + (dir?TL-1:0)))*2048 + i;
  const ptrdiff_t xstep = dir ? -2048 : 2048;
  #pragma unroll 4
  for (int tt=0; tt<TL; ++tt){
    const float x = bf2f(*xptr);
    #pragma unroll
    for (int s=0;s<16;++s) h[s] = fmaf(h[s], a[s], x*bc[s]);
    xptr += xstep;
  }
  u16* hp = hfin + (((size_t)z*CH + c)*2048 + row)*NS;
  st8(hp, h); st8(hp+8, h+8);
}

__global__ __launch_bounds__(256) void k4b_prefix(
    const float* __restrict__ AlV, const float* __restrict__ AlI,
    u16* __restrict__ hfin)
{
  const int z = blockIdx.y, inst = z>>1, dir = z&1, p = inst>>1;
  const int row = blockIdx.x*256 + threadIdx.x;
  const int i = row & 1023;
  const float* __restrict__ Al = p? AlI : AlV;
  float a64[16], H[16];
  #pragma unroll
  for (int s=0;s<16;s+=4){
    const float4 al = *(const float4*)(Al + (size_t)i*NS + s);
    a64[s]  =expf(64.f*al.x); a64[s+1]=expf(64.f*al.y);
    a64[s+2]=expf(64.f*al.z); a64[s+3]=expf(64.f*al.w);
    H[s]=0.f; H[s+1]=0.f; H[s+2]=0.f; H[s+3]=0.f;
  }
  for (int k=0;k<CH;++k){
    const int c = dir ? (CH-1-k) : k;
    u16* hp = hfin + (((size_t)z*CH + c)*2048 + row)*NS;
    float fin[16];
    ld8(hp, fin); ld8(hp+8, fin+8);
    st8(hp, H);  st8(hp+8, H+8);
    #pragma unroll
    for (int s=0;s<16;++s) H[s] = fmaf(a64[s], H[s], fin[s]);
  }
}

// K4c: final sweep; dir=0 writes y_fwd, dir=1 adds y_bwd in place (ys += )
__global__ __launch_bounds__(256) void k4c_sweep2(
    const u16* __restrict__ xp, const u16* __restrict__ hfin,
    const float* __restrict__ AlV, const float* __restrict__ AlI,
    const float* __restrict__ BV,  const float* __restrict__ BI,
    const float* __restrict__ CV,  const float* __restrict__ CI,
    u16* __restrict__ ys, int dir)
{
  const int inst = blockIdx.z;
  const int z = inst*2 + dir;
  const int p = inst>>1, sel = inst&1;
  const int c = blockIdx.y;
  const int row = blockIdx.x*256 + threadIdx.x;
  const int b = row>>10, i = row&1023;
  const float* __restrict__ Al = p? AlI : AlV;
  const float* __restrict__ Bm = (p^sel)? BI : BV;
  const float* __restrict__ Cm = p? CI : CV;
  float a[16], bc[16], cc[16], h[16];
  #pragma unroll
  for (int s=0;s<16;s+=4){
    const float4 al = *(const float4*)(Al + (size_t)i*NS + s);
    const float4 bv = *(const float4*)(Bm + (size_t)i*NS + s);
    const float4 cv = *(const float4*)(Cm + (size_t)i*NS + s);
    a[s]=-expf(al.x); a[s+1]=-expf(al.y); a[s+2]=-expf(al.z); a[s+3]=-expf(al.w);
    bc[s]=bv.x; bc[s+1]=bv.y; bc[s+2]=bv.z; bc[s+3]=bv.w;
    cc[s]=cv.x; cc[s+1]=cv.y; cc[s+2]=cv.z; cc[s+3]=cv.w;
  }
  const u16* hp = hfin + (((size_t)z*CH + c)*2048 + row)*NS;
  ld8(hp, h); ld8(hp+8, h+8);
  const u16* xptr = xp + ((size_t)(p*2048 + b*1024 + c*TL + (dir?TL-1:0)))*2048 + i;
  const ptrdiff_t xstep = dir ? -2048 : 2048;
  u16* yptr = ys + ((size_t)inst*2048 + b*1024 + c*TL + (dir?TL-1:0))*(size_t)DI + i;
  const ptrdiff_t ystep = dir ? -DI : DI;
  #pragma unroll 2
  for (int tt=0; tt<TL; ++tt){
    const float x = bf2f(*xptr);
    float p0=0.f,p1=0.f,p2=0.f,p3=0.f;
    #pragma unroll
    for (int s=0;s<16;s+=4){
      h[s]   = fmaf(h[s],   a[s],   x*bc[s]);
      h[s+1] = fmaf(h[s+1], a[s+1], x*bc[s+1]);
      h[s+2] = fmaf(h[s+2], a[s+2], x*bc[s+2]);
      h[s+3] = fmaf(h[s+3], a[s+3], x*bc[s+3]);
      p0 = fmaf(h[s],   cc[s],   p0);
      p1 = fmaf(h[s+1], cc[s+1], p1);
      p2 = fmaf(h[s+2], cc[s+2], p2);
      p3 = fmaf(h[s+3], cc[s+3], p3);
    }
    float y = (p0+p1)+(p2+p3);
    if (dir) y += bf2f(*yptr);
    *yptr = f2bf(y);
    xptr += xstep; yptr += ystep;
  }
}

// K4d: comb[p][m][k] = bf16( 0.5*silu(g)*(lam*ys_std + (1-lam)*ys_x) )
__global__ __launch_bounds__(256) void k4d_comb(
    const u16* __restrict__ ys, const u16* __restrict__ xp,
    const float* __restrict__ lam, u16* __restrict__ comb)
{
  const size_t idx = (size_t)blockIdx.x*256 + threadIdx.x;   // [p][m][k/8] : 2*2048*128
  const int kk = (int)(idx & 127) * 8;
  const int m  = (int)((idx >> 7) & 2047);
  const int p  = (int)(idx >> 18);
  const float lm = lam[p*2 + (m>>10)];
  float yss[8], ysx[8], g[8], o[8];
  ld8(ys + ((size_t)(p*2+0)*2048 + m)*(size_t)DI + kk, yss);
  ld8(ys + ((size_t)(p*2+1)*2048 + m)*(size_t)DI + kk, ysx);
  ld8(xp + ((size_t)p*2048 + m)*2048 + DI + kk, g);
  #pragma unroll
  for (int j=0;j<8;++j)
    o[j] = 0.5f*g[j]*sigm(g[j])*(lm*yss[j] + (1.f-lm)*ysx[j]);
  st8(comb + ((size_t)p*2048 + m)*(size_t)DI + kk, o);
}

// K5 (MFMA): outp[p][m][n] = bf16( comb[p][m][:] . ow[n][:] ),  M=2048 N=512 K=1024, BK=64
__global__ __launch_bounds__(256) void k5_mfma(
    const u16* __restrict__ comb, const u16* __restrict__ owVb, const u16* __restrict__ owIb,
    u16* __restrict__ outp)
{
  const int p = blockIdx.z;
  const u16* __restrict__ A  = comb + (size_t)p*2048*DI;
  const u16* __restrict__ Bw = p? owIb : owVb;
  const int m0 = blockIdx.x*128, n0 = blockIdx.y*64;
  __shared__ __align__(16) u16 As[128*LDK];
  __shared__ __align__(16) u16 Bs[64*LDK];
  const int tid = threadIdx.x, lane = tid&63, wid = tid>>6;
  const int m_off = (wid>>1)*64, n_off = (wid&1)*32;
  f32x4 acc[4][2];
  const f32x4 z = {0.f,0.f,0.f,0.f};
  #pragma unroll
  for (int mi=0;mi<4;++mi) for (int ni=0;ni<2;++ni) acc[mi][ni]=z;
  for (int k0=0;k0<DI;k0+=64){
    stage_bf16<128>(A  + (size_t)m0*DI, DI, As, k0, tid);
    stage_bf16<64>( Bw + (size_t)n0*DI, DI, Bs, k0, tid);
    __syncthreads();
    #pragma unroll
    for (int ks=0;ks<2;++ks){
      bf16x8 a[4], b[2];
      #pragma unroll
      for (int mi=0;mi<4;++mi) a[mi] = frag(As, m_off+mi*16+(lane&15), ks, lane);
      #pragma unroll
      for (int ni=0;ni<2;++ni) b[ni] = frag(Bs, n_off+ni*16+(lane&15), ks, lane);
      #pragma unroll
      for (int mi=0;mi<4;++mi)
        #pragma unroll
        for (int ni=0;ni<2;++ni)
          acc[mi][ni] = __builtin_amdgcn_mfma_f32_16x16x32_bf16(a[mi], b[ni], acc[mi][ni], 0,0,0);
    }
    __syncthreads();
  }
  #pragma unroll
  for (int mi=0;mi<4;++mi){
    #pragma unroll
    for (int rr=0;rr<4;++rr){
      const int mm = m0 + m_off + mi*16 + ((lane>>4)<<2) + rr;
      #pragma unroll
      for (int ni=0;ni<2;++ni){
        const int n = n0 + n_off + ni*16 + (lane&15);
        outp[((size_t)p*2048+mm)*DM + n] = f2bf(acc[mi][ni][rr]);
      }
    }
  }
}

// K6 (MFMA): fpre[p][m][q] = outp[p][m][:] . rsw[q][:],  M=2048 N=256 K=512, BK=64
__global__ __launch_bounds__(256) void k6_mfma(
    const u16* __restrict__ outp, const u16* __restrict__ rswb,
    float* __restrict__ fpre)
{
  const int p = blockIdx.z;
  const u16* __restrict__ A = outp + (size_t)p*2048*DM;
  const int m0 = blockIdx.x*64, n0 = blockIdx.y*64;
  __shared__ __align__(16) u16 As[64*LDK];
  __shared__ __align__(16) u16 Bs[64*LDK];
  const int tid = threadIdx.x, lane = tid&63, wid = tid>>6;
  const int m_off = (wid>>1)*32, n_off = (wid&1)*32;
  f32x4 acc[2][2];
  const f32x4 z = {0.f,0.f,0.f,0.f};
  #pragma unroll
  for (int mi=0;mi<2;++mi) for (int ni=0;ni<2;++ni) acc[mi][ni]=z;
  for (int k0=0;k0<DM;k0+=64){
    stage_bf16<64>(A    + (size_t)m0*DM, DM, As, k0, tid);
    stage_bf16<64>(rswb + (size_t)n0*DM, DM, Bs, k0, tid);
    __syncthreads();
    #pragma unroll
    for (int ks=0;ks<2;++ks){
      bf16x8 a[2], b[2];
      #pragma unroll
      for (int mi=0;mi<2;++mi) a[mi] = frag(As, m_off+mi*16+(lane&15), ks, lane);
      #pragma unroll
      for (int ni=0;ni<2;++ni) b[ni] = frag(Bs, n_off+ni*16+(lane&15), ks, lane);
      #pragma unroll
      for (int mi=0;mi<2;++mi)
        #pragma unroll
        for (int ni=0;ni<2;++ni)
          acc[mi][ni] = __builtin_amdgcn_mfma_f32_16x16x32_bf16(a[mi], b[ni], acc[mi][ni], 0,0,0);
    }
    __syncthreads();
  }
  #pragma unroll
  for (int mi=0;mi<2;++mi){
    #pragma unroll
    for (int rr=0;rr<4;++rr){
      const int mm = m0 + m_off + mi*16 + ((lane>>4)<<2) + rr;
      #pragma unroll
      for (int ni=0;ni<2;++ni){
        const int n = n0 + n_off + ni*16 + (lane&15);
        fpre[((size_t)p*2048+mm)*CIN + n] = acc[mi][ni][rr];
      }
    }
  }
}

// K7: out[p][b][q][hw] = x[p][b][q][hw] + bn(fpre[p][b*1024+hw][q])
__global__ __launch_bounds__(256) void k7_final(
    const float* __restrict__ fpre, const float* __restrict__ xV, const float* __restrict__ xI,
    const float* __restrict__ rsg, const float* __restrict__ rsb,
    const float* __restrict__ rsm, const float* __restrict__ rsv,
    float* __restrict__ out)
{
  const int img = blockIdx.z, p = img>>1, b = img&1;
  const int hw0 = blockIdx.x*32, q0 = blockIdx.y*32;
  const float* __restrict__ xres = (p? xI : xV) + (size_t)b*CIN*LQ;
  __shared__ float tile[32][33];
  const int tid = threadIdx.x;
  {
    const int r = tid>>3, c = (tid&7)*4;
    const float4 v = *(const float4*)(fpre + ((size_t)p*2048 + b*1024 + hw0 + r)*CIN + q0 + c);
    tile[r][c]=v.x; tile[r][c+1]=v.y; tile[r][c+2]=v.z; tile[r][c+3]=v.w;
  }
  __syncthreads();
  #pragma unroll
  for (int k=0;k<4;++k){
    const int lin = k*256 + tid;
    const int ql = lin>>5, hl = lin&31;
    const int qch = q0+ql, hw = hw0+hl;
    const float s = rsg[qch]*rsqrtf(rsv[qch]+EPSF);
    const float t = rsb[qch] - rsm[qch]*s;
    const float v = fmaf(tile[hl][ql], s, t) + xres[(size_t)qch*LQ + hw];
    out[(size_t)img*CIN*LQ + (size_t)qch*LQ + hw] = v;
  }
}

extern "C" void kernel_launch(void* const* d_in, const int* in_sizes, int n_in,
                              void* d_out, int out_size, void* d_ws, size_t ws_size,
                              hipStream_t stream)
{
  const float* cr_w = (const float*)d_in[0];
  const float* cr_g = (const float*)d_in[1];
  const float* cr_b = (const float*)d_in[2];
  const float* cr_m = (const float*)d_in[3];
  const float* cr_v = (const float*)d_in[4];
  const float* rs_w = (const float*)d_in[5];
  const float* rs_g = (const float*)d_in[6];
  const float* rs_b = (const float*)d_in[7];
  const float* rs_m = (const float*)d_in[8];
  const float* rs_v = (const float*)d_in[9];
  const float* mV_ln_g = (const float*)d_in[10];
  const float* mV_ln_b = (const float*)d_in[11];
  const float* mV_in_w = (const float*)d_in[12];
  const float* mV_A    = (const float*)d_in[13];
  const float* mV_B    = (const float*)d_in[14];
  const float* mV_C    = (const float*)d_in[15];
  const float* mV_ow   = (const float*)d_in[16];
  const float* lpV_w1  = (const float*)d_in[17];
  const float* lpV_b1  = (const float*)d_in[18];
  const float* lpV_w2  = (const float*)d_in[19];
  const float* lpV_b2  = (const float*)d_in[20];
  const float* mI_ln_g = (const float*)d_in[21];
  const float* mI_ln_b = (const float*)d_in[22];
  const float* mI_in_w = (const float*)d_in[23];
  const float* mI_A    = (const float*)d_in[24];
  const float* mI_B    = (const float*)d_in[25];
  const float* mI_C    = (const float*)d_in[26];
  const float* mI_ow   = (const float*)d_in[27];
  const float* lpI_w1  = (const float*)d_in[28];
  const float* lpI_b1  = (const float*)d_in[29];
  const float* lpI_w2  = (const float*)d_in[30];
  const float* lpI_b2  = (const float*)d_in[31];
  const float* x_V = (const float*)d_in[32];
  const float* x_I = (const float*)d_in[33];
  float* out = (float*)d_out;

  char* ws = (char*)d_ws;
  // layout (52.7 MB total):
  float* xr    = (float*)(ws + 0);            // [2][2048][512] f32      8,388,608
  u16*   xn    = (u16*)  (ws + 8388608);      // [2][2048][512] bf16     4,194,304
  float* lam   = (float*)(ws + 12582912);     // [4] f32 (+pad)                512
  u16*   iwVb  = (u16*)  (ws + 12583424);     // [2048][512] bf16        2,097,152
  u16*   iwIb  = (u16*)  (ws + 14680576);     // [2048][512] bf16        2,097,152
  u16*   owVb  = (u16*)  (ws + 16777728);     // [512][1024] bf16        1,048,576
  u16*   owIb  = (u16*)  (ws + 17826304);     // [512][1024] bf16        1,048,576
  u16*   rswb  = (u16*)  (ws + 18874880);     // [256][512] bf16           262,144
  u16*   xp    = (u16*)  (ws + 19137024);     // [2][2048][2048] bf16   16,777,216
  u16*   ysbuf = (u16*)  (ws + 35914240);     // [4][2048][1024] bf16   16,777,216
  // aliases (lifetime-disjoint):
  u16*   hfin  = (u16*)  (ws + 0);            // [8][16][2048][16] bf16  8,388,608  (xr dead after k2)
  u16*   comb  = (u16*)  (ws + 0);            // [2][2048][1024] bf16    8,388,608  (hfin dead after k4c)
  u16*   outp  = (u16*)  (ws + 8388608);      // [2][2048][512] bf16     4,194,304  (xn dead after k3)
  float* part  = (float*)(ws + 19137024);     // [4][16][512] f32          131,072  (pre-k3 xp region)
  float* fpre  = (float*)(ws + 35914240);     // [2][2048][256] f32      4,194,304  (ys dead after k4d)

  k0_cvt      <<<dim3(256,5),   dim3(256), 0, stream>>>(mV_in_w, mI_in_w, mV_ow, mI_ow, rs_w,
                                                        iwVb, iwIb, owVb, owIb, rswb);
  k1_convraise<<<dim3(16,8,4),  dim3(256), 0, stream>>>(x_V,x_I,cr_w,cr_g,cr_b,cr_m,cr_v,xr);
  k2_ln       <<<dim3(4096),    dim3(64),  0, stream>>>(xr, mV_ln_g,mV_ln_b, mI_ln_g,mI_ln_b, xn);
  k2_pool     <<<dim3(16,4),    dim3(256), 0, stream>>>(xr, part);
  k2_lambda   <<<dim3(4),       dim3(256), 0, stream>>>(part, lpV_w1,lpV_b1,lpV_w2,lpV_b2,
                                                              lpI_w1,lpI_b1,lpI_w2,lpI_b2, lam);
  k3_mfma     <<<dim3(16,16,2), dim3(256), 0, stream>>>(xn, iwVb, iwIb, xp);
  k4a_sweep1  <<<dim3(8,16,8),  dim3(256), 0, stream>>>(xp, mV_A, mI_A, mV_B, mI_B, hfin);
  k4b_prefix  <<<dim3(8,8),     dim3(256), 0, stream>>>(mV_A, mI_A, hfin);
  k4c_sweep2  <<<dim3(8,16,4),  dim3(256), 0, stream>>>(xp, hfin, mV_A, mI_A, mV_B, mI_B,
                                                        mV_C, mI_C, ysbuf, 0);
  k4c_sweep2  <<<dim3(8,16,4),  dim3(256), 0, stream>>>(xp, hfin, mV_A, mI_A, mV_B, mI_B,
                                                        mV_C, mI_C, ysbuf, 1);
  k4d_comb    <<<dim3(2048),    dim3(256), 0, stream>>>(ysbuf, xp, lam, comb);
  k5_mfma     <<<dim3(16,8,2),  dim3(256), 0, stream>>>(comb, owVb, owIb, outp);
  k6_mfma     <<<dim3(32,4,2),  dim3(256), 0, stream>>>(outp, rswb, fpre);
  k7_final    <<<dim3(32,8,4),  dim3(256), 0, stream>>>(fpre, x_V, x_I, rs_g, rs_b, rs_m, rs_v, out);
}

// Round 5
// 134.182 us; speedup vs baseline: 5.0821x; 1.3898x over previous
//
#include <hip/hip_runtime.h>
#include <math.h>

typedef unsigned short u16;
typedef unsigned int   u32;
typedef __bf16 bf16x8 __attribute__((ext_vector_type(8)));
typedef float  f32x4  __attribute__((ext_vector_type(4)));

#define PP   2
#define LQ   1024     // H*W
#define DM   512      // d_model
#define DI   1024     // d_inner
#define NS   16       // d_state
#define CIN  256
#define EPSF 1e-5f
#define CH   32       // scan chunks
#define TL   32       // chunk length (CH*TL == LQ)
#define LDK  72       // padded LDS row (bf16): 144 B stride -> 2-way max on frag reads (free, m136)

__device__ __forceinline__ float bf2f(u16 u){ return __uint_as_float(((u32)u)<<16); }
__device__ __forceinline__ u16 f2bf(float f){
  u32 x = __float_as_uint(f);
  x += 0x7fffu + ((x>>16)&1u);           // RNE
  return (u16)(x>>16);
}
__device__ __forceinline__ float sigm(float x){ return 1.f/(1.f+expf(-x)); }

__device__ __forceinline__ void ld8(const u16* p, float* f){
  const uint4 v = *(const uint4*)p;
  f[0]=bf2f((u16)v.x); f[1]=bf2f((u16)(v.x>>16));
  f[2]=bf2f((u16)v.y); f[3]=bf2f((u16)(v.y>>16));
  f[4]=bf2f((u16)v.z); f[5]=bf2f((u16)(v.z>>16));
  f[6]=bf2f((u16)v.w); f[7]=bf2f((u16)(v.w>>16));
}
__device__ __forceinline__ void st8(u16* p, const float* f){
  uint4 v;
  v.x = (u32)f2bf(f[0]) | ((u32)f2bf(f[1])<<16);
  v.y = (u32)f2bf(f[2]) | ((u32)f2bf(f[3])<<16);
  v.z = (u32)f2bf(f[4]) | ((u32)f2bf(f[5])<<16);
  v.w = (u32)f2bf(f[6]) | ((u32)f2bf(f[7])<<16);
  *(uint4*)p = v;
}

// Stage a ROWS x 64 bf16 tile (row-major, source row stride srcK) into padded LDS.
template<int ROWS>
__device__ __forceinline__ void stage_bf16(const u16* __restrict__ src, size_t srcK,
                                           u16* __restrict__ dst, int k0, int tid)
{
  #pragma unroll
  for (int c = 0; c < ROWS*8; c += 256){
    const int cc = c + tid;
    const int row = cc>>3, pos = cc&7;
    *(uint4*)(dst + row*LDK + pos*8) = *(const uint4*)(src + (size_t)row*srcK + k0 + pos*8);
  }
}

// MFMA fragment: lane l -> row, k-chunk (l>>4)*8 within the 32-k step (+ks*32).
__device__ __forceinline__ bf16x8 frag(const u16* t, int row, int ks, int lane){
  return *(const bf16x8*)(t + row*LDK + ks*32 + ((lane>>4)<<3));
}

// ---- fp32 MAC tile (k1 only) ----
__device__ __forceinline__ void mac_tile(const float (*As)[68], const float (*Bs)[68],
                                         float acc[4][4], int tx, int ty)
{
  #pragma unroll
  for (int kk=0;kk<16;++kk){
    float av[4], bv[4];
    #pragma unroll
    for (int i=0;i<4;++i) av[i]=As[kk][ty*4+i];
    #pragma unroll
    for (int j=0;j<4;++j) bv[j]=Bs[kk][tx*4+j];
    #pragma unroll
    for (int i=0;i<4;++i)
      #pragma unroll
      for (int j=0;j<4;++j) acc[i][j] = fmaf(av[i], bv[j], acc[i][j]);
  }
}

// K0: weight f32 -> bf16 conversion (iwV, iwI, owV, owI, rsw)
__global__ __launch_bounds__(256) void k0_cvt(
    const float* __restrict__ s0, const float* __restrict__ s1,
    const float* __restrict__ s2, const float* __restrict__ s3,
    const float* __restrict__ s4,
    u16* __restrict__ d0, u16* __restrict__ d1, u16* __restrict__ d2,
    u16* __restrict__ d3, u16* __restrict__ d4)
{
  const int which = blockIdx.y;
  const float* s; u16* d; int n;
  switch(which){
    case 0: s=s0; d=d0; n=1048576; break;
    case 1: s=s1; d=d1; n=1048576; break;
    case 2: s=s2; d=d2; n=524288;  break;
    case 3: s=s3; d=d3; n=524288;  break;
    default: s=s4; d=d4; n=131072; break;
  }
  for (int i = (blockIdx.x*256+threadIdx.x)*4; i < n; i += gridDim.x*256*4){
    const float4 v = *(const float4*)(s+i);
    ushort4 o; o.x=f2bf(v.x); o.y=f2bf(v.y); o.z=f2bf(v.z); o.w=f2bf(v.w);
    *(ushort4*)(d+i) = o;
  }
}

// K1: xr[p][b][hw][o] = relu(bn(sum_c X[c][hw]*crw[o][c]))   (fp32 MAC)
__global__ __launch_bounds__(256) void k1_convraise(
    const float* __restrict__ xV, const float* __restrict__ xI,
    const float* __restrict__ crw, const float* __restrict__ crg,
    const float* __restrict__ crb, const float* __restrict__ crm,
    const float* __restrict__ crv, float* __restrict__ xr)
{
  const int img = blockIdx.z, p = img>>1, b = img&1;
  const float* __restrict__ X = (p ? xI : xV) + (size_t)b*CIN*LQ;
  const int m0 = blockIdx.x*64, n0 = blockIdx.y*64;
  __shared__ float As[16][68];
  __shared__ float Bs[16][68];
  const int tid = threadIdx.x, tx = tid&15, ty = tid>>4;
  float acc[4][4] = {};
  for (int k0=0; k0<CIN; k0+=16){
    {
      const int kk = tid>>4, mm = (tid&15)*4;
      const float4 v = *(const float4*)(X + (size_t)(k0+kk)*LQ + m0 + mm);
      *(float4*)&As[kk][mm] = v;
      const int nn = tid>>2, k4 = (tid&3)*4;
      const float4 w = *(const float4*)(crw + (size_t)(n0+nn)*CIN + k0 + k4);
      Bs[k4+0][nn]=w.x; Bs[k4+1][nn]=w.y; Bs[k4+2][nn]=w.z; Bs[k4+3][nn]=w.w;
    }
    __syncthreads();
    mac_tile(As, Bs, acc, tx, ty);
    __syncthreads();
  }
  #pragma unroll
  for (int i=0;i<4;++i){
    const int m = m0 + ty*4 + i;
    float4 o; float* po = (float*)&o;
    #pragma unroll
    for (int j=0;j<4;++j){
      const int n = n0 + tx*4 + j;
      const float s = crg[n]*rsqrtf(crv[n]+EPSF);
      const float t = crb[n] - crm[n]*s;
      po[j] = fmaxf(fmaf(acc[i][j], s, t), 0.f);
    }
    *(float4*)(xr + ((size_t)img*LQ + m)*DM + n0 + tx*4) = o;
  }
}

// K2ln: per-row LN over DM, write bf16 xn
__global__ __launch_bounds__(64) void k2_ln(
    const float* __restrict__ xr,
    const float* __restrict__ lgV, const float* __restrict__ lbV,
    const float* __restrict__ lgI, const float* __restrict__ lbI,
    u16* __restrict__ xn)
{
  const int row = blockIdx.x;        // p*2048 + m
  const int p = row>>11;
  const int lane = threadIdx.x;
  const float* __restrict__ base = xr + (size_t)row*DM + lane*8;
  const float* __restrict__ lg = (p? lgI : lgV) + lane*8;
  const float* __restrict__ lb = (p? lbI : lbV) + lane*8;
  float v[8];
  *(float4*)&v[0] = *(const float4*)(base);
  *(float4*)&v[4] = *(const float4*)(base+4);
  float s=0.f, q=0.f;
  #pragma unroll
  for (int j=0;j<8;++j){ s += v[j]; q += v[j]*v[j]; }
  #pragma unroll
  for (int off=32; off; off>>=1){ s += __shfl_down(s,off); q += __shfl_down(q,off); }
  s = __shfl(s,0); q = __shfl(q,0);
  const float mean = s*(1.f/DM);
  const float rstd = rsqrtf(fmaxf(q*(1.f/DM) - mean*mean, 0.f)+EPSF);
  float g[8], be[8], y[8];
  *(float4*)&g[0]  = *(const float4*)(lg);
  *(float4*)&g[4]  = *(const float4*)(lg+4);
  *(float4*)&be[0] = *(const float4*)(lb);
  *(float4*)&be[4] = *(const float4*)(lb+4);
  #pragma unroll
  for (int j=0;j<8;++j) y[j] = (v[j]-mean)*rstd*g[j] + be[j];
  st8(xn + (size_t)row*DM + lane*8, y);
}

// K2p: part[img][sl][ch] = sum over 64 t of xr[img][sl*64+t][ch]
__global__ __launch_bounds__(256) void k2_pool(const float* __restrict__ xr,
                                               float* __restrict__ part)
{
  const int img = blockIdx.y, sl = blockIdx.x;
  const int tid = threadIdx.x;
  const float* __restrict__ base = xr + ((size_t)img*LQ + sl*64)*DM;
  float s0=0.f, s1=0.f;
  for (int t=0;t<64;++t){
    s0 += base[(size_t)t*DM + tid];
    s1 += base[(size_t)t*DM + 256 + tid];
  }
  part[((size_t)img*16 + sl)*DM + tid]       = s0;
  part[((size_t)img*16 + sl)*DM + 256 + tid] = s1;
}

// K2: lam[img] = sigmoid(relu(pool@w1^T+b1)@w2^T+b2)
__global__ __launch_bounds__(256) void k2_lambda(
    const float* __restrict__ part,
    const float* __restrict__ w1V, const float* __restrict__ b1V,
    const float* __restrict__ w2V, const float* __restrict__ b2V,
    const float* __restrict__ w1I, const float* __restrict__ b1I,
    const float* __restrict__ w2I, const float* __restrict__ b2I,
    float* __restrict__ lam)
{
  const int img = blockIdx.x, p = img>>1;
  const float* __restrict__ w1 = p? w1I : w1V;
  const float* __restrict__ b1 = p? b1I : b1V;
  const float* __restrict__ w2 = p? w2I : w2V;
  const float* __restrict__ b2 = p? b2I : b2V;
  __shared__ float pool[DM];
  __shared__ float hb[128];
  const int tid = threadIdx.x;
  for (int ch=tid; ch<DM; ch+=256){
    float s=0.f;
    #pragma unroll
    for (int sl=0; sl<16; ++sl) s += part[((size_t)img*16 + sl)*DM + ch];
    pool[ch] = s * (1.f/LQ);
  }
  __syncthreads();
  if (tid<128){
    float h = b1[tid];
    const float* __restrict__ wr = w1 + (size_t)tid*DM;
    for (int o=0;o<DM;o+=4){
      const float4 w = *(const float4*)(wr+o);
      h += pool[o]*w.x + pool[o+1]*w.y + pool[o+2]*w.z + pool[o+3]*w.w;
    }
    hb[tid] = fmaxf(h,0.f);
  }
  __syncthreads();
  if (tid==0){
    float v = b2[0];
    for (int j=0;j<128;++j) v += hb[j]*w2[j];
    lam[img] = sigm(v);
  }
}

// K3 (MFMA): xp[p][m][n] = bf16( xn[p][m][:] . iw[n][:] ),  M=2048 N=2048 K=512, BK=64
__global__ __launch_bounds__(256) void k3_mfma(
    const u16* __restrict__ xn, const u16* __restrict__ iwVb, const u16* __restrict__ iwIb,
    u16* __restrict__ xp)
{
  const int p = blockIdx.z;
  const u16* __restrict__ A  = xn + (size_t)p*2048*DM;
  const u16* __restrict__ Bw = p? iwIb : iwVb;
  const int m0 = blockIdx.x*128, n0 = blockIdx.y*128;
  __shared__ __align__(16) u16 As[128*LDK];
  __shared__ __align__(16) u16 Bs[128*LDK];
  const int tid = threadIdx.x, lane = tid&63, wid = tid>>6;
  const int m_off = (wid>>1)*64, n_off = (wid&1)*64;
  f32x4 acc[4][4];
  const f32x4 z = {0.f,0.f,0.f,0.f};
  #pragma unroll
  for (int mi=0;mi<4;++mi) for (int ni=0;ni<4;++ni) acc[mi][ni]=z;
  for (int k0=0;k0<DM;k0+=64){
    stage_bf16<128>(A  + (size_t)m0*DM, DM, As, k0, tid);
    stage_bf16<128>(Bw + (size_t)n0*DM, DM, Bs, k0, tid);
    __syncthreads();
    #pragma unroll
    for (int ks=0;ks<2;++ks){
      bf16x8 a[4], b[4];
      #pragma unroll
      for (int mi=0;mi<4;++mi) a[mi] = frag(As, m_off+mi*16+(lane&15), ks, lane);
      #pragma unroll
      for (int ni=0;ni<4;++ni) b[ni] = frag(Bs, n_off+ni*16+(lane&15), ks, lane);
      #pragma unroll
      for (int mi=0;mi<4;++mi)
        #pragma unroll
        for (int ni=0;ni<4;++ni)
          acc[mi][ni] = __builtin_amdgcn_mfma_f32_16x16x32_bf16(a[mi], b[ni], acc[mi][ni], 0,0,0);
    }
    __syncthreads();
  }
  u16* __restrict__ orow = xp + (size_t)p*2048*2048;
  #pragma unroll
  for (int mi=0;mi<4;++mi){
    #pragma unroll
    for (int rr=0;rr<4;++rr){
      const int m = m0 + m_off + mi*16 + ((lane>>4)<<2) + rr;
      #pragma unroll
      for (int ni=0;ni<4;++ni){
        const int n = n0 + n_off + ni*16 + (lane&15);
        orow[(size_t)m*2048 + n] = f2bf(acc[mi][ni][rr]);
      }
    }
  }
}

// ---- chunked scan in u-space: u_t = a*u_{t-1} + x_t  (B-free; h = B.*u exactly) ----
// hfin layout: [z = p*2+dir][c][row(b*1024+i)][16] bf16

// K4s1: per-chunk local u-scan (zero init), fwd+bwd off one LDS x-tile
__global__ __launch_bounds__(256) void k4s1(
    const u16* __restrict__ xp,
    const float* __restrict__ AlV, const float* __restrict__ AlI,
    u16* __restrict__ hfin)
{
  const int p = blockIdx.z, c = blockIdx.y, rb = blockIdx.x;
  const int tid = threadIdx.x;
  const int row = rb*256 + tid;            // b*1024 + i
  const int bb = rb>>2;
  const int il = (rb&3)*256;               // i block base
  const int i  = il + tid;
  __shared__ __align__(16) u16 xs[TL*256];
  {
    const u16* src = xp + ((size_t)(p*2048 + bb*1024 + c*TL))*2048 + il;
    const int r0 = tid>>5, cb = (tid&31)*8;
    #pragma unroll
    for (int rr=0; rr<TL; rr+=8)
      *(uint4*)(xs + (rr+r0)*256 + cb) = *(const uint4*)(src + (size_t)(rr+r0)*2048 + cb);
  }
  const float* __restrict__ Al = p? AlI : AlV;
  float a[16], uf[16], ub[16];
  #pragma unroll
  for (int s=0;s<16;s+=4){
    const float4 al = *(const float4*)(Al + (size_t)i*NS + s);
    a[s]=-expf(al.x); a[s+1]=-expf(al.y); a[s+2]=-expf(al.z); a[s+3]=-expf(al.w);
    uf[s]=0.f; uf[s+1]=0.f; uf[s+2]=0.f; uf[s+3]=0.f;
    ub[s]=0.f; ub[s+1]=0.f; ub[s+2]=0.f; ub[s+3]=0.f;
  }
  __syncthreads();
  #pragma unroll 4
  for (int tt=0; tt<TL; ++tt){
    const float xf = bf2f(xs[tt*256 + tid]);
    const float xb = bf2f(xs[(TL-1-tt)*256 + tid]);
    #pragma unroll
    for (int s=0;s<16;++s){
      uf[s] = fmaf(uf[s], a[s], xf);
      ub[s] = fmaf(ub[s], a[s], xb);
    }
  }
  u16* hpf = hfin + (((size_t)(p*2+0)*CH + c)*2048 + row)*NS;
  u16* hpb = hfin + (((size_t)(p*2+1)*CH + c)*2048 + row)*NS;
  st8(hpf, uf); st8(hpf+8, uf+8);
  st8(hpb, ub); st8(hpb+8, ub+8);
}

// K4b: sequential prefix over chunks (in place: fin -> U_init), z = p*2+dir
__global__ __launch_bounds__(256) void k4b_prefix(
    const float* __restrict__ AlV, const float* __restrict__ AlI,
    u16* __restrict__ hfin)
{
  const int z = blockIdx.y, dir = z&1, p = z>>1;
  const int row = blockIdx.x*256 + threadIdx.x;
  const int i = row & 1023;
  const float* __restrict__ Al = p? AlI : AlV;
  float aT[16], H[16];
  #pragma unroll
  for (int s=0;s<16;s+=4){
    const float4 al = *(const float4*)(Al + (size_t)i*NS + s);
    const float sc = (float)TL;
    aT[s]  =expf(sc*al.x); aT[s+1]=expf(sc*al.y);
    aT[s+2]=expf(sc*al.z); aT[s+3]=expf(sc*al.w);
    H[s]=0.f; H[s+1]=0.f; H[s+2]=0.f; H[s+3]=0.f;
  }
  for (int k=0;k<CH;++k){
    const int c = dir ? (CH-1-k) : k;
    u16* hp = hfin + (((size_t)z*CH + c)*2048 + row)*NS;
    float fin[16];
    ld8(hp, fin); ld8(hp+8, fin+8);
    st8(hp, H);  st8(hp+8, H+8);
    #pragma unroll
    for (int s=0;s<16;++s) H[s] = fmaf(aT[s], H[s], fin[s]);
  }
}

// K4s2: final sweep seeded with exact inits; emits comb directly.
// comb[p][m][i] = bf16( 0.5*silu(g) * ( dot(uf, dmix) + dot(ub, dmix) ) ),
// dmix = (lm*B_own + (1-lm)*B_other) .* C
__global__ __launch_bounds__(256,2) void k4s2(
    const u16* __restrict__ xp, const u16* __restrict__ hfin,
    const float* __restrict__ AlV, const float* __restrict__ AlI,
    const float* __restrict__ BV,  const float* __restrict__ BI,
    const float* __restrict__ CV,  const float* __restrict__ CI,
    const float* __restrict__ lam, u16* __restrict__ comb)
{
  const int p = blockIdx.z, c = blockIdx.y, rb = blockIdx.x;
  const int tid = threadIdx.x;
  const int row = rb*256 + tid;
  const int bb = rb>>2;
  const int il = (rb&3)*256;
  const int i  = il + tid;
  __shared__ __align__(16) u16  xs[TL*256];
  __shared__ __align__(16) float ps[TL*256];
  {
    const u16* src = xp + ((size_t)(p*2048 + bb*1024 + c*TL))*2048 + il;
    const int r0 = tid>>5, cb = (tid&31)*8;
    #pragma unroll
    for (int rr=0; rr<TL; rr+=8)
      *(uint4*)(xs + (rr+r0)*256 + cb) = *(const uint4*)(src + (size_t)(rr+r0)*2048 + cb);
  }
  const float* __restrict__ Al = p? AlI : AlV;
  const float* __restrict__ B0 = p? BI : BV;    // own B
  const float* __restrict__ B1 = p? BV : BI;    // other's B (cross)
  const float* __restrict__ Cm = p? CI : CV;
  const float lm = lam[p*2+bb];
  float a[16], dmix[16], uf[16], ub[16];
  #pragma unroll
  for (int s=0;s<16;s+=4){
    const float4 al = *(const float4*)(Al + (size_t)i*NS + s);
    const float4 b0 = *(const float4*)(B0 + (size_t)i*NS + s);
    const float4 b1 = *(const float4*)(B1 + (size_t)i*NS + s);
    const float4 cv = *(const float4*)(Cm + (size_t)i*NS + s);
    a[s]=-expf(al.x); a[s+1]=-expf(al.y); a[s+2]=-expf(al.z); a[s+3]=-expf(al.w);
    dmix[s]  =(lm*b0.x+(1.f-lm)*b1.x)*cv.x;
    dmix[s+1]=(lm*b0.y+(1.f-lm)*b1.y)*cv.y;
    dmix[s+2]=(lm*b0.z+(1.f-lm)*b1.z)*cv.z;
    dmix[s+3]=(lm*b0.w+(1.f-lm)*b1.w)*cv.w;
  }
  {
    const u16* hpf = hfin + (((size_t)(p*2+0)*CH + c)*2048 + row)*NS;
    const u16* hpb = hfin + (((size_t)(p*2+1)*CH + c)*2048 + row)*NS;
    ld8(hpf, uf); ld8(hpf+8, uf+8);
    ld8(hpb, ub); ld8(hpb+8, ub+8);
  }
  __syncthreads();
  #pragma unroll 2
  for (int tt=0; tt<TL; ++tt){
    const float xf = bf2f(xs[tt*256 + tid]);
    const float xb = bf2f(xs[(TL-1-tt)*256 + tid]);
    float yf0=0.f, yf1=0.f, yb0=0.f, yb1=0.f;
    #pragma unroll
    for (int s=0;s<16;s+=2){
      uf[s]   = fmaf(uf[s],   a[s],   xf);
      uf[s+1] = fmaf(uf[s+1], a[s+1], xf);
      ub[s]   = fmaf(ub[s],   a[s],   xb);
      ub[s+1] = fmaf(ub[s+1], a[s+1], xb);
      yf0 = fmaf(uf[s],   dmix[s],   yf0);
      yf1 = fmaf(uf[s+1], dmix[s+1], yf1);
      yb0 = fmaf(ub[s],   dmix[s],   yb0);
      yb1 = fmaf(ub[s+1], dmix[s+1], yb1);
    }
    const float yf = yf0+yf1, yb = yb0+yb1;
    if (tt < TL/2){
      ps[tt*256 + tid]          = yf;
      ps[(TL-1-tt)*256 + tid]   = yb;
    } else {
      ps[tt*256 + tid]         += yf;
      ps[(TL-1-tt)*256 + tid]  += yb;
    }
  }
  __syncthreads();
  // epilogue: comb = 0.5*silu(g)*ps, vectorized
  const int r0 = tid>>5, cb = (tid&31)*8;
  #pragma unroll
  for (int rr=0; rr<TL; rr+=8){
    const int r = rr + r0;
    const size_t mrow = (size_t)(p*2048 + bb*1024 + c*TL + r);
    float g8[8], o[8];
    ld8(xp + mrow*2048 + DI + il + cb, g8);
    #pragma unroll
    for (int j=0;j<8;++j){
      const float pv = ps[r*256 + cb + j];
      o[j] = 0.5f*g8[j]*sigm(g8[j])*pv;
    }
    st8(comb + mrow*(size_t)DI + il + cb, o);
  }
}

// K5 (MFMA): outp[p][m][n] = bf16( comb[p][m][:] . ow[n][:] ),  M=2048 N=512 K=1024, BK=64
__global__ __launch_bounds__(256) void k5_mfma(
    const u16* __restrict__ comb, const u16* __restrict__ owVb, const u16* __restrict__ owIb,
    u16* __restrict__ outp)
{
  const int p = blockIdx.z;
  const u16* __restrict__ A  = comb + (size_t)p*2048*DI;
  const u16* __restrict__ Bw = p? owIb : owVb;
  const int m0 = blockIdx.x*128, n0 = blockIdx.y*64;
  __shared__ __align__(16) u16 As[128*LDK];
  __shared__ __align__(16) u16 Bs[64*LDK];
  const int tid = threadIdx.x, lane = tid&63, wid = tid>>6;
  const int m_off = (wid>>1)*64, n_off = (wid&1)*32;
  f32x4 acc[4][2];
  const f32x4 z = {0.f,0.f,0.f,0.f};
  #pragma unroll
  for (int mi=0;mi<4;++mi) for (int ni=0;ni<2;++ni) acc[mi][ni]=z;
  for (int k0=0;k0<DI;k0+=64){
    stage_bf16<128>(A  + (size_t)m0*DI, DI, As, k0, tid);
    stage_bf16<64>( Bw + (size_t)n0*DI, DI, Bs, k0, tid);
    __syncthreads();
    #pragma unroll
    for (int ks=0;ks<2;++ks){
      bf16x8 a[4], b[2];
      #pragma unroll
      for (int mi=0;mi<4;++mi) a[mi] = frag(As, m_off+mi*16+(lane&15), ks, lane);
      #pragma unroll
      for (int ni=0;ni<2;++ni) b[ni] = frag(Bs, n_off+ni*16+(lane&15), ks, lane);
      #pragma unroll
      for (int mi=0;mi<4;++mi)
        #pragma unroll
        for (int ni=0;ni<2;++ni)
          acc[mi][ni] = __builtin_amdgcn_mfma_f32_16x16x32_bf16(a[mi], b[ni], acc[mi][ni], 0,0,0);
    }
    __syncthreads();
  }
  #pragma unroll
  for (int mi=0;mi<4;++mi){
    #pragma unroll
    for (int rr=0;rr<4;++rr){
      const int mm = m0 + m_off + mi*16 + ((lane>>4)<<2) + rr;
      #pragma unroll
      for (int ni=0;ni<2;++ni){
        const int n = n0 + n_off + ni*16 + (lane&15);
        outp[((size_t)p*2048+mm)*DM + n] = f2bf(acc[mi][ni][rr]);
      }
    }
  }
}

// K6 (MFMA): fpre[p][m][q] = outp[p][m][:] . rsw[q][:],  M=2048 N=256 K=512, BK=64
__global__ __launch_bounds__(256) void k6_mfma(
    const u16* __restrict__ outp, const u16* __restrict__ rswb,
    float* __restrict__ fpre)
{
  const int p = blockIdx.z;
  const u16* __restrict__ A = outp + (size_t)p*2048*DM;
  const int m0 = blockIdx.x*64, n0 = blockIdx.y*64;
  __shared__ __align__(16) u16 As[64*LDK];
  __shared__ __align__(16) u16 Bs[64*LDK];
  const int tid = threadIdx.x, lane = tid&63, wid = tid>>6;
  const int m_off = (wid>>1)*32, n_off = (wid&1)*32;
  f32x4 acc[2][2];
  const f32x4 z = {0.f,0.f,0.f,0.f};
  #pragma unroll
  for (int mi=0;mi<2;++mi) for (int ni=0;ni<2;++ni) acc[mi][ni]=z;
  for (int k0=0;k0<DM;k0+=64){
    stage_bf16<64>(A    + (size_t)m0*DM, DM, As, k0, tid);
    stage_bf16<64>(rswb + (size_t)n0*DM, DM, Bs, k0, tid);
    __syncthreads();
    #pragma unroll
    for (int ks=0;ks<2;++ks){
      bf16x8 a[2], b[2];
      #pragma unroll
      for (int mi=0;mi<2;++mi) a[mi] = frag(As, m_off+mi*16+(lane&15), ks, lane);
      #pragma unroll
      for (int ni=0;ni<2;++ni) b[ni] = frag(Bs, n_off+ni*16+(lane&15), ks, lane);
      #pragma unroll
      for (int mi=0;mi<2;++mi)
        #pragma unroll
        for (int ni=0;ni<2;++ni)
          acc[mi][ni] = __builtin_amdgcn_mfma_f32_16x16x32_bf16(a[mi], b[ni], acc[mi][ni], 0,0,0);
    }
    __syncthreads();
  }
  #pragma unroll
  for (int mi=0;mi<2;++mi){
    #pragma unroll
    for (int rr=0;rr<4;++rr){
      const int mm = m0 + m_off + mi*16 + ((lane>>4)<<2) + rr;
      #pragma unroll
      for (int ni=0;ni<2;++ni){
        const int n = n0 + n_off + ni*16 + (lane&15);
        fpre[((size_t)p*2048+mm)*CIN + n] = acc[mi][ni][rr];
      }
    }
  }
}

// K7: out[p][b][q][hw] = x[p][b][q][hw] + bn(fpre[p][b*1024+hw][q])
__global__ __launch_bounds__(256) void k7_final(
    const float* __restrict__ fpre, const float* __restrict__ xV, const float* __restrict__ xI,
    const float* __restrict__ rsg, const float* __restrict__ rsb,
    const float* __restrict__ rsm, const float* __restrict__ rsv,
    float* __restrict__ out)
{
  const int img = blockIdx.z, p = img>>1, b = img&1;
  const int hw0 = blockIdx.x*32, q0 = blockIdx.y*32;
  const float* __restrict__ xres = (p? xI : xV) + (size_t)b*CIN*LQ;
  __shared__ float tile[32][33];
  const int tid = threadIdx.x;
  {
    const int r = tid>>3, c = (tid&7)*4;
    const float4 v = *(const float4*)(fpre + ((size_t)p*2048 + b*1024 + hw0 + r)*CIN + q0 + c);
    tile[r][c]=v.x; tile[r][c+1]=v.y; tile[r][c+2]=v.z; tile[r][c+3]=v.w;
  }
  __syncthreads();
  #pragma unroll
  for (int k=0;k<4;++k){
    const int lin = k*256 + tid;
    const int ql = lin>>5, hl = lin&31;
    const int qch = q0+ql, hw = hw0+hl;
    const float s = rsg[qch]*rsqrtf(rsv[qch]+EPSF);
    const float t = rsb[qch] - rsm[qch]*s;
    const float v = fmaf(tile[hl][ql], s, t) + xres[(size_t)qch*LQ + hw];
    out[(size_t)img*CIN*LQ + (size_t)qch*LQ + hw] = v;
  }
}

extern "C" void kernel_launch(void* const* d_in, const int* in_sizes, int n_in,
                              void* d_out, int out_size, void* d_ws, size_t ws_size,
                              hipStream_t stream)
{
  const float* cr_w = (const float*)d_in[0];
  const float* cr_g = (const float*)d_in[1];
  const float* cr_b = (const float*)d_in[2];
  const float* cr_m = (const float*)d_in[3];
  const float* cr_v = (const float*)d_in[4];
  const float* rs_w = (const float*)d_in[5];
  const float* rs_g = (const float*)d_in[6];
  const float* rs_b = (const float*)d_in[7];
  const float* rs_m = (const float*)d_in[8];
  const float* rs_v = (const float*)d_in[9];
  const float* mV_ln_g = (const float*)d_in[10];
  const float* mV_ln_b = (const float*)d_in[11];
  const float* mV_in_w = (const float*)d_in[12];
  const float* mV_A    = (const float*)d_in[13];
  const float* mV_B    = (const float*)d_in[14];
  const float* mV_C    = (const float*)d_in[15];
  const float* mV_ow   = (const float*)d_in[16];
  const float* lpV_w1  = (const float*)d_in[17];
  const float* lpV_b1  = (const float*)d_in[18];
  const float* lpV_w2  = (const float*)d_in[19];
  const float* lpV_b2  = (const float*)d_in[20];
  const float* mI_ln_g = (const float*)d_in[21];
  const float* mI_ln_b = (const float*)d_in[22];
  const float* mI_in_w = (const float*)d_in[23];
  const float* mI_A    = (const float*)d_in[24];
  const float* mI_B    = (const float*)d_in[25];
  const float* mI_C    = (const float*)d_in[26];
  const float* mI_ow   = (const float*)d_in[27];
  const float* lpI_w1  = (const float*)d_in[28];
  const float* lpI_b1  = (const float*)d_in[29];
  const float* lpI_w2  = (const float*)d_in[30];
  const float* lpI_b2  = (const float*)d_in[31];
  const float* x_V = (const float*)d_in[32];
  const float* x_I = (const float*)d_in[33];
  float* out = (float*)d_out;

  char* ws = (char*)d_ws;
  // layout (48.5 MB peak):
  float* xr    = (float*)(ws + 0);            // [2][2048][512] f32      8,388,608
  u16*   xn    = (u16*)  (ws + 8388608);      // [2][2048][512] bf16     4,194,304
  float* lam   = (float*)(ws + 12582912);     // [4] f32 (+pad)                512
  u16*   iwVb  = (u16*)  (ws + 12583424);     // [2048][512] bf16        2,097,152
  u16*   iwIb  = (u16*)  (ws + 14680576);     // [2048][512] bf16        2,097,152
  u16*   owVb  = (u16*)  (ws + 16777728);     // [512][1024] bf16        1,048,576
  u16*   owIb  = (u16*)  (ws + 17826304);     // [512][1024] bf16        1,048,576
  u16*   rswb  = (u16*)  (ws + 18874880);     // [256][512] bf16           262,144
  u16*   xp    = (u16*)  (ws + 19137024);     // [2][2048][2048] bf16   16,777,216
  u16*   comb  = (u16*)  (ws + 35914240);     // [2][2048][1024] bf16    8,388,608
  float* fpre  = (float*)(ws + 44302848);     // [2][2048][256] f32      4,194,304
  // aliases (lifetime-disjoint):
  u16*   hfin  = (u16*)  (ws + 0);            // [4][32][2048][16] bf16  8,388,608  (xr dead after k2)
  u16*   outp  = (u16*)  (ws + 8388608);      // [2][2048][512] bf16     4,194,304  (xn dead after k3)
  float* part  = (float*)(ws + 19137024);     // [4][16][512] f32          131,072  (pre-k3 xp region)

  k0_cvt      <<<dim3(256,5),   dim3(256), 0, stream>>>(mV_in_w, mI_in_w, mV_ow, mI_ow, rs_w,
                                                        iwVb, iwIb, owVb, owIb, rswb);
  k1_convraise<<<dim3(16,8,4),  dim3(256), 0, stream>>>(x_V,x_I,cr_w,cr_g,cr_b,cr_m,cr_v,xr);
  k2_ln       <<<dim3(4096),    dim3(64),  0, stream>>>(xr, mV_ln_g,mV_ln_b, mI_ln_g,mI_ln_b, xn);
  k2_pool     <<<dim3(16,4),    dim3(256), 0, stream>>>(xr, part);
  k2_lambda   <<<dim3(4),       dim3(256), 0, stream>>>(part, lpV_w1,lpV_b1,lpV_w2,lpV_b2,
                                                              lpI_w1,lpI_b1,lpI_w2,lpI_b2, lam);
  k3_mfma     <<<dim3(16,16,2), dim3(256), 0, stream>>>(xn, iwVb, iwIb, xp);
  k4s1        <<<dim3(8,CH,2),  dim3(256), 0, stream>>>(xp, mV_A, mI_A, hfin);
  k4b_prefix  <<<dim3(8,4),     dim3(256), 0, stream>>>(mV_A, mI_A, hfin);
  k4s2        <<<dim3(8,CH,2),  dim3(256), 0, stream>>>(xp, hfin, mV_A, mI_A, mV_B, mI_B,
                                                        mV_C, mI_C, lam, comb);
  k5_mfma     <<<dim3(16,8,2),  dim3(256), 0, stream>>>(comb, owVb, owIb, outp);
  k6_mfma     <<<dim3(32,4,2),  dim3(256), 0, stream>>>(outp, rswb, fpre);
  k7_final    <<<dim3(32,8,4),  dim3(256), 0, stream>>>(fpre, x_V, x_I, rs_g, rs_b, rs_m, rs_v, out);
}

// Round 6
// 129.449 us; speedup vs baseline: 5.2679x; 1.0366x over previous
//
#include <hip/hip_runtime.h>
#include <math.h>

typedef unsigned short u16;
typedef unsigned int   u32;
typedef __bf16 bf16x8 __attribute__((ext_vector_type(8)));
typedef float  f32x4  __attribute__((ext_vector_type(4)));

#define PP   2
#define LQ   1024     // H*W
#define DM   512      // d_model
#define DI   1024     // d_inner
#define NS   16       // d_state
#define CIN  256
#define EPSF 1e-5f
#define CH   32       // scan chunks
#define TL   32       // chunk length (CH*TL == LQ)

__device__ __forceinline__ float bf2f(u16 u){ return __uint_as_float(((u32)u)<<16); }
__device__ __forceinline__ u16 f2bf(float f){
  u32 x = __float_as_uint(f);
  x += 0x7fffu + ((x>>16)&1u);           // RNE
  return (u16)(x>>16);
}
__device__ __forceinline__ float sigm(float x){ return 1.f/(1.f+expf(-x)); }

__device__ __forceinline__ void ld8(const u16* p, float* f){
  const uint4 v = *(const uint4*)p;
  f[0]=bf2f((u16)v.x); f[1]=bf2f((u16)(v.x>>16));
  f[2]=bf2f((u16)v.y); f[3]=bf2f((u16)(v.y>>16));
  f[4]=bf2f((u16)v.z); f[5]=bf2f((u16)(v.z>>16));
  f[6]=bf2f((u16)v.w); f[7]=bf2f((u16)(v.w>>16));
}
__device__ __forceinline__ void st8(u16* p, const float* f){
  uint4 v;
  v.x = (u32)f2bf(f[0]) | ((u32)f2bf(f[1])<<16);
  v.y = (u32)f2bf(f[2]) | ((u32)f2bf(f[3])<<16);
  v.z = (u32)f2bf(f[4]) | ((u32)f2bf(f[5])<<16);
  v.w = (u32)f2bf(f[6]) | ((u32)f2bf(f[7])<<16);
  *(uint4*)p = v;
}

// ---- async global->LDS DMA: 16 B per lane, dest = uniform base + lane*16 ----
typedef const __attribute__((address_space(1))) u32* gas_t;
typedef __attribute__((address_space(3))) u32* las_t;
__device__ __forceinline__ void gld16(const void* g, void* l){
  __builtin_amdgcn_global_load_lds((gas_t)g, (las_t)l, 16, 0, 0);
}

// ---- unified MFMA GEMM main loop: TMxTN tile, BK=64, 4 waves (2x2), linear LDS ----
// A: row m0 base (row-major, stride K elems). B: row n0 base. As/Bs: TM*64 / TN*64 u16.
template<int TM, int TN>
__device__ __forceinline__ void gemm_main(const u16* __restrict__ A, const u16* __restrict__ B,
                                          int K, u16* As, u16* Bs,
                                          f32x4 (&acc)[TM/32][TN/32], int tid)
{
  const int lane = tid&63, w = tid>>6;
  const int m_off = (w>>1)*(TM/2), n_off = (w&1)*(TN/2);
  for (int k0=0; k0<K; k0+=64){
    #pragma unroll
    for (int j=0;j<TM/32;++j){
      const int rb = (w*(TM/32)+j)*8;
      gld16(A + (size_t)(rb+(lane>>3))*K + k0 + (lane&7)*8, As + rb*64);
    }
    #pragma unroll
    for (int j=0;j<TN/32;++j){
      const int rb = (w*(TN/32)+j)*8;
      gld16(B + (size_t)(rb+(lane>>3))*K + k0 + (lane&7)*8, Bs + rb*64);
    }
    __syncthreads();
    #pragma unroll
    for (int ks=0;ks<2;++ks){
      bf16x8 af[TM/32], bb[TN/32];
      #pragma unroll
      for (int mi=0;mi<TM/32;++mi)
        af[mi] = *(const bf16x8*)(As + (m_off+mi*16+(lane&15))*64 + ks*32 + ((lane>>4)<<3));
      #pragma unroll
      for (int ni=0;ni<TN/32;++ni)
        bb[ni] = *(const bf16x8*)(Bs + (n_off+ni*16+(lane&15))*64 + ks*32 + ((lane>>4)<<3));
      #pragma unroll
      for (int mi=0;mi<TM/32;++mi)
        #pragma unroll
        for (int ni=0;ni<TN/32;++ni)
          acc[mi][ni] = __builtin_amdgcn_mfma_f32_16x16x32_bf16(af[mi], bb[ni], acc[mi][ni], 0,0,0);
    }
    __syncthreads();
  }
}

// K0: plain f32 -> bf16 conversion (iwV, iwI, crw, rsw)
__global__ __launch_bounds__(256) void k0_cvt(
    const float* __restrict__ s0, const float* __restrict__ s1,
    const float* __restrict__ s2, const float* __restrict__ s3,
    u16* __restrict__ d0, u16* __restrict__ d1, u16* __restrict__ d2,
    u16* __restrict__ d3)
{
  const int which = blockIdx.y;
  const float* s; u16* d; int n;
  switch(which){
    case 0: s=s0; d=d0; n=1048576; break;
    case 1: s=s1; d=d1; n=1048576; break;
    case 2: s=s2; d=d2; n=131072;  break;
    default: s=s3; d=d3; n=131072; break;
  }
  for (int i = (blockIdx.x*256+threadIdx.x)*4; i < n; i += gridDim.x*256*4){
    const float4 v = *(const float4*)(s+i);
    ushort4 o; o.x=f2bf(v.x); o.y=f2bf(v.y); o.z=f2bf(v.z); o.w=f2bf(v.w);
    *(ushort4*)(d+i) = o;
  }
}

// K0t: transpose-convert f32 [R][C] -> bf16 [C][R].
// z=0,1: owV/owI (512x1024 -> 1024x512); z=2..5: x imgs (256x1024 -> 1024x256)
__global__ __launch_bounds__(256) void k0_tr(
    const float* __restrict__ owV, const float* __restrict__ owI,
    const float* __restrict__ xV,  const float* __restrict__ xI,
    u16* __restrict__ owTV, u16* __restrict__ owTI, u16* __restrict__ xT)
{
  const int z = blockIdx.z;
  int R, C; const float* src; u16* dst;
  if (z < 2){ R=512; C=1024; src = z? owI : owV; dst = z? owTI : owTV; }
  else {
    R=256; C=1024;
    const int img = z-2;               // 0: V b0, 1: V b1, 2: I b0, 3: I b1
    src = (img<2 ? xV : xI) + (size_t)(img&1)*CIN*LQ;
    dst = xT + (size_t)img*LQ*CIN;
  }
  const int r0 = blockIdx.y*32, c0 = blockIdx.x*32;
  if (r0 >= R) return;
  __shared__ float tile[32][33];
  const int tid = threadIdx.x;
  {
    const int r = tid>>3, c = (tid&7)*4;
    const float4 v = *(const float4*)(src + (size_t)(r0+r)*C + c0 + c);
    tile[r][c]=v.x; tile[r][c+1]=v.y; tile[r][c+2]=v.z; tile[r][c+3]=v.w;
  }
  __syncthreads();
  {
    const int cl = tid>>3, rl = (tid&7)*4;
    ushort4 o;
    o.x = f2bf(tile[rl+0][cl]); o.y = f2bf(tile[rl+1][cl]);
    o.z = f2bf(tile[rl+2][cl]); o.w = f2bf(tile[rl+3][cl]);
    *(ushort4*)(dst + (size_t)(c0+cl)*R + r0 + rl) = o;
  }
}

// K0b: W2[p][q][kk] = sum_n rsw[q][n]*ow_p[n][kk]  (M=256,N=1024,K=512, 128x128 tiles)
__global__ __launch_bounds__(256) void k0b_w2(
    const u16* __restrict__ rswb, const u16* __restrict__ owTV, const u16* __restrict__ owTI,
    u16* __restrict__ W2b)
{
  const int p = blockIdx.z;
  const u16* __restrict__ B = (p? owTI : owTV);
  const int m0 = blockIdx.x*128, n0 = blockIdx.y*128;
  __shared__ __align__(16) u16 As[128*64];
  __shared__ __align__(16) u16 Bs[128*64];
  const int tid = threadIdx.x, lane = tid&63, wid = tid>>6;
  const int m_off = (wid>>1)*64, n_off = (wid&1)*64;
  f32x4 acc[4][4];
  const f32x4 z = {0.f,0.f,0.f,0.f};
  #pragma unroll
  for (int mi=0;mi<4;++mi) for (int ni=0;ni<4;++ni) acc[mi][ni]=z;
  gemm_main<128,128>(rswb + (size_t)m0*DM, B + (size_t)n0*DM, DM, As, Bs, acc, tid);
  u16* __restrict__ orow = W2b + (size_t)p*256*1024;
  #pragma unroll
  for (int mi=0;mi<4;++mi)
    #pragma unroll
    for (int rr=0;rr<4;++rr){
      const int m = m0 + m_off + mi*16 + ((lane>>4)<<2) + rr;
      #pragma unroll
      for (int ni=0;ni<4;++ni){
        const int n = n0 + n_off + ni*16 + (lane&15);
        orow[(size_t)m*1024 + n] = f2bf(acc[mi][ni][rr]);
      }
    }
}

// K1 (MFMA): xr[m][n] = relu(bn( xT[m][:] . crwb[n][:] )),  M=4096 N=512 K=256, 64x64 tiles
__global__ __launch_bounds__(256) void k1_mfma(
    const u16* __restrict__ xT, const u16* __restrict__ crwb,
    const float* __restrict__ crg, const float* __restrict__ crb,
    const float* __restrict__ crm, const float* __restrict__ crv,
    float* __restrict__ xr)
{
  const int m0 = blockIdx.x*64, n0 = blockIdx.y*64;
  __shared__ __align__(16) u16 As[64*64];
  __shared__ __align__(16) u16 Bs[64*64];
  const int tid = threadIdx.x, lane = tid&63, wid = tid>>6;
  const int m_off = (wid>>1)*32, n_off = (wid&1)*32;
  f32x4 acc[2][2];
  const f32x4 z = {0.f,0.f,0.f,0.f};
  #pragma unroll
  for (int mi=0;mi<2;++mi) for (int ni=0;ni<2;++ni) acc[mi][ni]=z;
  gemm_main<64,64>(xT + (size_t)m0*CIN, crwb + (size_t)n0*CIN, CIN, As, Bs, acc, tid);
  #pragma unroll
  for (int mi=0;mi<2;++mi)
    #pragma unroll
    for (int ni=0;ni<2;++ni){
      const int n = n0 + n_off + ni*16 + (lane&15);
      const float s = crg[n]*rsqrtf(crv[n]+EPSF);
      const float t = crb[n] - crm[n]*s;
      #pragma unroll
      for (int rr=0;rr<4;++rr){
        const int m = m0 + m_off + mi*16 + ((lane>>4)<<2) + rr;
        xr[(size_t)m*DM + n] = fmaxf(fmaf(acc[mi][ni][rr], s, t), 0.f);
      }
    }
}

// K2ln: per-row LN over DM, write bf16 xn
__global__ __launch_bounds__(64) void k2_ln(
    const float* __restrict__ xr,
    const float* __restrict__ lgV, const float* __restrict__ lbV,
    const float* __restrict__ lgI, const float* __restrict__ lbI,
    u16* __restrict__ xn)
{
  const int row = blockIdx.x;        // p*2048 + m
  const int p = row>>11;
  const int lane = threadIdx.x;
  const float* __restrict__ base = xr + (size_t)row*DM + lane*8;
  const float* __restrict__ lg = (p? lgI : lgV) + lane*8;
  const float* __restrict__ lb = (p? lbI : lbV) + lane*8;
  float v[8];
  *(float4*)&v[0] = *(const float4*)(base);
  *(float4*)&v[4] = *(const float4*)(base+4);
  float s=0.f, q=0.f;
  #pragma unroll
  for (int j=0;j<8;++j){ s += v[j]; q += v[j]*v[j]; }
  #pragma unroll
  for (int off=32; off; off>>=1){ s += __shfl_down(s,off); q += __shfl_down(q,off); }
  s = __shfl(s,0); q = __shfl(q,0);
  const float mean = s*(1.f/DM);
  const float rstd = rsqrtf(fmaxf(q*(1.f/DM) - mean*mean, 0.f)+EPSF);
  float g[8], be[8], y[8];
  *(float4*)&g[0]  = *(const float4*)(lg);
  *(float4*)&g[4]  = *(const float4*)(lg+4);
  *(float4*)&be[0] = *(const float4*)(lb);
  *(float4*)&be[4] = *(const float4*)(lb+4);
  #pragma unroll
  for (int j=0;j<8;++j) y[j] = (v[j]-mean)*rstd*g[j] + be[j];
  st8(xn + (size_t)row*DM + lane*8, y);
}

// K2p: part[img][sl][ch] = sum over 64 t of xr[img][sl*64+t][ch]
__global__ __launch_bounds__(256) void k2_pool(const float* __restrict__ xr,
                                               float* __restrict__ part)
{
  const int img = blockIdx.y, sl = blockIdx.x;
  const int tid = threadIdx.x;
  const float* __restrict__ base = xr + ((size_t)img*LQ + sl*64)*DM;
  float s0=0.f, s1=0.f;
  for (int t=0;t<64;++t){
    s0 += base[(size_t)t*DM + tid];
    s1 += base[(size_t)t*DM + 256 + tid];
  }
  part[((size_t)img*16 + sl)*DM + tid]       = s0;
  part[((size_t)img*16 + sl)*DM + 256 + tid] = s1;
}

// K2: lam[img] = sigmoid(relu(pool@w1^T+b1)@w2^T+b2)
__global__ __launch_bounds__(256) void k2_lambda(
    const float* __restrict__ part,
    const float* __restrict__ w1V, const float* __restrict__ b1V,
    const float* __restrict__ w2V, const float* __restrict__ b2V,
    const float* __restrict__ w1I, const float* __restrict__ b1I,
    const float* __restrict__ w2I, const float* __restrict__ b2I,
    float* __restrict__ lam)
{
  const int img = blockIdx.x, p = img>>1;
  const float* __restrict__ w1 = p? w1I : w1V;
  const float* __restrict__ b1 = p? b1I : b1V;
  const float* __restrict__ w2 = p? w2I : w2V;
  const float* __restrict__ b2 = p? b2I : b2V;
  __shared__ float pool[DM];
  __shared__ float hb[128];
  const int tid = threadIdx.x;
  for (int ch=tid; ch<DM; ch+=256){
    float s=0.f;
    #pragma unroll
    for (int sl=0; sl<16; ++sl) s += part[((size_t)img*16 + sl)*DM + ch];
    pool[ch] = s * (1.f/LQ);
  }
  __syncthreads();
  if (tid<128){
    float h = b1[tid];
    const float* __restrict__ wr = w1 + (size_t)tid*DM;
    for (int o=0;o<DM;o+=4){
      const float4 w = *(const float4*)(wr+o);
      h += pool[o]*w.x + pool[o+1]*w.y + pool[o+2]*w.z + pool[o+3]*w.w;
    }
    hb[tid] = fmaxf(h,0.f);
  }
  __syncthreads();
  if (tid==0){
    float v = b2[0];
    for (int j=0;j<128;++j) v += hb[j]*w2[j];
    lam[img] = sigm(v);
  }
}

// K3 (MFMA): xp[p][m][n] = bf16( xn[p][m][:] . iw[n][:] ),  M=2048 N=2048 K=512, 128x128
__global__ __launch_bounds__(256) void k3_mfma(
    const u16* __restrict__ xn, const u16* __restrict__ iwVb, const u16* __restrict__ iwIb,
    u16* __restrict__ xp)
{
  const int p = blockIdx.z;
  const u16* __restrict__ A  = xn + (size_t)p*2048*DM;
  const u16* __restrict__ Bw = p? iwIb : iwVb;
  const int m0 = blockIdx.x*128, n0 = blockIdx.y*128;
  __shared__ __align__(16) u16 As[128*64];
  __shared__ __align__(16) u16 Bs[128*64];
  const int tid = threadIdx.x, lane = tid&63, wid = tid>>6;
  const int m_off = (wid>>1)*64, n_off = (wid&1)*64;
  f32x4 acc[4][4];
  const f32x4 z = {0.f,0.f,0.f,0.f};
  #pragma unroll
  for (int mi=0;mi<4;++mi) for (int ni=0;ni<4;++ni) acc[mi][ni]=z;
  gemm_main<128,128>(A + (size_t)m0*DM, Bw + (size_t)n0*DM, DM, As, Bs, acc, tid);
  u16* __restrict__ orow = xp + (size_t)p*2048*2048;
  #pragma unroll
  for (int mi=0;mi<4;++mi)
    #pragma unroll
    for (int rr=0;rr<4;++rr){
      const int m = m0 + m_off + mi*16 + ((lane>>4)<<2) + rr;
      #pragma unroll
      for (int ni=0;ni<4;++ni){
        const int n = n0 + n_off + ni*16 + (lane&15);
        orow[(size_t)m*2048 + n] = f2bf(acc[mi][ni][rr]);
      }
    }
}

// ---- chunked scan in u-space: u_t = a*u_{t-1} + x_t  (B-free; h = B.*u exactly) ----
__global__ __launch_bounds__(256) void k4s1(
    const u16* __restrict__ xp,
    const float* __restrict__ AlV, const float* __restrict__ AlI,
    u16* __restrict__ hfin)
{
  const int p = blockIdx.z, c = blockIdx.y, rb = blockIdx.x;
  const int tid = threadIdx.x;
  const int row = rb*256 + tid;            // b*1024 + i
  const int bb = rb>>2;
  const int il = (rb&3)*256;               // i block base
  const int i  = il + tid;
  __shared__ __align__(16) u16 xs[TL*256];
  {
    const u16* src = xp + ((size_t)(p*2048 + bb*1024 + c*TL))*2048 + il;
    const int r0 = tid>>5, cb = (tid&31)*8;
    #pragma unroll
    for (int rr=0; rr<TL; rr+=8)
      *(uint4*)(xs + (rr+r0)*256 + cb) = *(const uint4*)(src + (size_t)(rr+r0)*2048 + cb);
  }
  const float* __restrict__ Al = p? AlI : AlV;
  float a[16], uf[16], ub[16];
  #pragma unroll
  for (int s=0;s<16;s+=4){
    const float4 al = *(const float4*)(Al + (size_t)i*NS + s);
    a[s]=-expf(al.x); a[s+1]=-expf(al.y); a[s+2]=-expf(al.z); a[s+3]=-expf(al.w);
    uf[s]=0.f; uf[s+1]=0.f; uf[s+2]=0.f; uf[s+3]=0.f;
    ub[s]=0.f; ub[s+1]=0.f; ub[s+2]=0.f; ub[s+3]=0.f;
  }
  __syncthreads();
  #pragma unroll 4
  for (int tt=0; tt<TL; ++tt){
    const float xf = bf2f(xs[tt*256 + tid]);
    const float xb = bf2f(xs[(TL-1-tt)*256 + tid]);
    #pragma unroll
    for (int s=0;s<16;++s){
      uf[s] = fmaf(uf[s], a[s], xf);
      ub[s] = fmaf(ub[s], a[s], xb);
    }
  }
  u16* hpf = hfin + (((size_t)(p*2+0)*CH + c)*2048 + row)*NS;
  u16* hpb = hfin + (((size_t)(p*2+1)*CH + c)*2048 + row)*NS;
  st8(hpf, uf); st8(hpf+8, uf+8);
  st8(hpb, ub); st8(hpb+8, ub+8);
}

__global__ __launch_bounds__(256) void k4b_prefix(
    const float* __restrict__ AlV, const float* __restrict__ AlI,
    u16* __restrict__ hfin)
{
  const int z = blockIdx.y, dir = z&1, p = z>>1;
  const int row = blockIdx.x*256 + threadIdx.x;
  const int i = row & 1023;
  const float* __restrict__ Al = p? AlI : AlV;
  float aT[16], H[16];
  #pragma unroll
  for (int s=0;s<16;s+=4){
    const float4 al = *(const float4*)(Al + (size_t)i*NS + s);
    const float sc = (float)TL;
    aT[s]  =expf(sc*al.x); aT[s+1]=expf(sc*al.y);
    aT[s+2]=expf(sc*al.z); aT[s+3]=expf(sc*al.w);
    H[s]=0.f; H[s+1]=0.f; H[s+2]=0.f; H[s+3]=0.f;
  }
  for (int k=0;k<CH;++k){
    const int c = dir ? (CH-1-k) : k;
    u16* hp = hfin + (((size_t)z*CH + c)*2048 + row)*NS;
    float fin[16];
    ld8(hp, fin); ld8(hp+8, fin+8);
    st8(hp, H);  st8(hp+8, H+8);
    #pragma unroll
    for (int s=0;s<16;++s) H[s] = fmaf(aT[s], H[s], fin[s]);
  }
}

// K4s2: final sweep seeded with exact inits; emits comb directly.
__global__ __launch_bounds__(256,2) void k4s2(
    const u16* __restrict__ xp, const u16* __restrict__ hfin,
    const float* __restrict__ AlV, const float* __restrict__ AlI,
    const float* __restrict__ BV,  const float* __restrict__ BI,
    const float* __restrict__ CV,  const float* __restrict__ CI,
    const float* __restrict__ lam, u16* __restrict__ comb)
{
  const int p = blockIdx.z, c = blockIdx.y, rb = blockIdx.x;
  const int tid = threadIdx.x;
  const int row = rb*256 + tid;
  const int bb = rb>>2;
  const int il = (rb&3)*256;
  const int i  = il + tid;
  __shared__ __align__(16) u16  xs[TL*256];
  __shared__ __align__(16) float ps[TL*256];
  {
    const u16* src = xp + ((size_t)(p*2048 + bb*1024 + c*TL))*2048 + il;
    const int r0 = tid>>5, cb = (tid&31)*8;
    #pragma unroll
    for (int rr=0; rr<TL; rr+=8)
      *(uint4*)(xs + (rr+r0)*256 + cb) = *(const uint4*)(src + (size_t)(rr+r0)*2048 + cb);
  }
  const float* __restrict__ Al = p? AlI : AlV;
  const float* __restrict__ B0 = p? BI : BV;    // own B
  const float* __restrict__ B1 = p? BV : BI;    // other's B (cross)
  const float* __restrict__ Cm = p? CI : CV;
  const float lm = lam[p*2+bb];
  float a[16], dmix[16], uf[16], ub[16];
  #pragma unroll
  for (int s=0;s<16;s+=4){
    const float4 al = *(const float4*)(Al + (size_t)i*NS + s);
    const float4 b0 = *(const float4*)(B0 + (size_t)i*NS + s);
    const float4 b1 = *(const float4*)(B1 + (size_t)i*NS + s);
    const float4 cv = *(const float4*)(Cm + (size_t)i*NS + s);
    a[s]=-expf(al.x); a[s+1]=-expf(al.y); a[s+2]=-expf(al.z); a[s+3]=-expf(al.w);
    dmix[s]  =(lm*b0.x+(1.f-lm)*b1.x)*cv.x;
    dmix[s+1]=(lm*b0.y+(1.f-lm)*b1.y)*cv.y;
    dmix[s+2]=(lm*b0.z+(1.f-lm)*b1.z)*cv.z;
    dmix[s+3]=(lm*b0.w+(1.f-lm)*b1.w)*cv.w;
  }
  {
    const u16* hpf = hfin + (((size_t)(p*2+0)*CH + c)*2048 + row)*NS;
    const u16* hpb = hfin + (((size_t)(p*2+1)*CH + c)*2048 + row)*NS;
    ld8(hpf, uf); ld8(hpf+8, uf+8);
    ld8(hpb, ub); ld8(hpb+8, ub+8);
  }
  __syncthreads();
  #pragma unroll 2
  for (int tt=0; tt<TL; ++tt){
    const float xf = bf2f(xs[tt*256 + tid]);
    const float xb = bf2f(xs[(TL-1-tt)*256 + tid]);
    float yf0=0.f, yf1=0.f, yb0=0.f, yb1=0.f;
    #pragma unroll
    for (int s=0;s<16;s+=2){
      uf[s]   = fmaf(uf[s],   a[s],   xf);
      uf[s+1] = fmaf(uf[s+1], a[s+1], xf);
      ub[s]   = fmaf(ub[s],   a[s],   xb);
      ub[s+1] = fmaf(ub[s+1], a[s+1], xb);
      yf0 = fmaf(uf[s],   dmix[s],   yf0);
      yf1 = fmaf(uf[s+1], dmix[s+1], yf1);
      yb0 = fmaf(ub[s],   dmix[s],   yb0);
      yb1 = fmaf(ub[s+1], dmix[s+1], yb1);
    }
    const float yf = yf0+yf1, yb = yb0+yb1;
    if (tt < TL/2){
      ps[tt*256 + tid]          = yf;
      ps[(TL-1-tt)*256 + tid]   = yb;
    } else {
      ps[tt*256 + tid]         += yf;
      ps[(TL-1-tt)*256 + tid]  += yb;
    }
  }
  __syncthreads();
  const int r0 = tid>>5, cb = (tid&31)*8;
  #pragma unroll
  for (int rr=0; rr<TL; rr+=8){
    const int r = rr + r0;
    const size_t mrow = (size_t)(p*2048 + bb*1024 + c*TL + r);
    float g8[8], o[8];
    ld8(xp + mrow*2048 + DI + il + cb, g8);
    #pragma unroll
    for (int j=0;j<8;++j){
      const float pv = ps[r*256 + cb + j];
      o[j] = 0.5f*g8[j]*sigm(g8[j])*pv;
    }
    st8(comb + mrow*(size_t)DI + il + cb, o);
  }
}

// K5 (MFMA, fused): out[img][q][hw] = x[img][q][hw] + bn( comb[p][m][:] . W2[p][q][:] )
// M=2048 per p, N=256, K=1024, 64x64 tiles
__global__ __launch_bounds__(256) void k5_fused(
    const u16* __restrict__ comb, const u16* __restrict__ W2b,
    const float* __restrict__ xV, const float* __restrict__ xI,
    const float* __restrict__ rsg, const float* __restrict__ rsb,
    const float* __restrict__ rsm, const float* __restrict__ rsv,
    float* __restrict__ out)
{
  const int p = blockIdx.z;
  const int m0 = blockIdx.x*64, n0 = blockIdx.y*64;
  const u16* __restrict__ A = comb + (size_t)p*2048*DI;
  const u16* __restrict__ B = W2b + (size_t)p*256*1024;
  __shared__ __align__(16) u16 As[64*64];
  __shared__ __align__(16) u16 Bs[64*64];
  const int tid = threadIdx.x, lane = tid&63, wid = tid>>6;
  const int m_off = (wid>>1)*32, n_off = (wid&1)*32;
  f32x4 acc[2][2];
  const f32x4 z = {0.f,0.f,0.f,0.f};
  #pragma unroll
  for (int mi=0;mi<2;++mi) for (int ni=0;ni<2;++ni) acc[mi][ni]=z;
  gemm_main<64,64>(A + (size_t)m0*DI, B + (size_t)n0*DI, DI, As, Bs, acc, tid);
  const int bb = m0>>10;                 // batch within p (m0 tiles don't straddle)
  const int img = p*2 + bb;
  const float* __restrict__ xres = (p? xI : xV) + (size_t)bb*CIN*LQ;
  float* __restrict__ obase = out + (size_t)img*CIN*LQ;
  #pragma unroll
  for (int mi=0;mi<2;++mi)
    #pragma unroll
    for (int ni=0;ni<2;++ni){
      const int q = n0 + n_off + ni*16 + (lane&15);
      const float s = rsg[q]*rsqrtf(rsv[q]+EPSF);
      const float t = rsb[q] - rsm[q]*s;
      const int m = m0 + m_off + mi*16 + ((lane>>4)<<2);
      const int hw = m & 1023;
      const float4 xv = *(const float4*)(xres + (size_t)q*LQ + hw);
      float4 o;
      o.x = fmaf(acc[mi][ni][0], s, t) + xv.x;
      o.y = fmaf(acc[mi][ni][1], s, t) + xv.y;
      o.z = fmaf(acc[mi][ni][2], s, t) + xv.z;
      o.w = fmaf(acc[mi][ni][3], s, t) + xv.w;
      *(float4*)(obase + (size_t)q*LQ + hw) = o;
    }
}

extern "C" void kernel_launch(void* const* d_in, const int* in_sizes, int n_in,
                              void* d_out, int out_size, void* d_ws, size_t ws_size,
                              hipStream_t stream)
{
  const float* cr_w = (const float*)d_in[0];
  const float* cr_g = (const float*)d_in[1];
  const float* cr_b = (const float*)d_in[2];
  const float* cr_m = (const float*)d_in[3];
  const float* cr_v = (const float*)d_in[4];
  const float* rs_w = (const float*)d_in[5];
  const float* rs_g = (const float*)d_in[6];
  const float* rs_b = (const float*)d_in[7];
  const float* rs_m = (const float*)d_in[8];
  const float* rs_v = (const float*)d_in[9];
  const float* mV_ln_g = (const float*)d_in[10];
  const float* mV_ln_b = (const float*)d_in[11];
  const float* mV_in_w = (const float*)d_in[12];
  const float* mV_A    = (const float*)d_in[13];
  const float* mV_B    = (const float*)d_in[14];
  const float* mV_C    = (const float*)d_in[15];
  const float* mV_ow   = (const float*)d_in[16];
  const float* lpV_w1  = (const float*)d_in[17];
  const float* lpV_b1  = (const float*)d_in[18];
  const float* lpV_w2  = (const float*)d_in[19];
  const float* lpV_b2  = (const float*)d_in[20];
  const float* mI_ln_g = (const float*)d_in[21];
  const float* mI_ln_b = (const float*)d_in[22];
  const float* mI_in_w = (const float*)d_in[23];
  const float* mI_A    = (const float*)d_in[24];
  const float* mI_B    = (const float*)d_in[25];
  const float* mI_C    = (const float*)d_in[26];
  const float* mI_ow   = (const float*)d_in[27];
  const float* lpI_w1  = (const float*)d_in[28];
  const float* lpI_b1  = (const float*)d_in[29];
  const float* lpI_w2  = (const float*)d_in[30];
  const float* lpI_b2  = (const float*)d_in[31];
  const float* x_V = (const float*)d_in[32];
  const float* x_I = (const float*)d_in[33];
  float* out = (float*)d_out;

  char* ws = (char*)d_ws;
  // layout (~47.8 MB peak):
  float* xr    = (float*)(ws + 0);            // [4096][512] f32          8,388,608
  u16*   xn    = (u16*)  (ws + 8388608);      // [2][2048][512] bf16      4,194,304
  float* lam   = (float*)(ws + 12582912);     // [4] f32 (+pad)                 512
  u16*   iwVb  = (u16*)  (ws + 12583424);     // [2048][512] bf16         2,097,152
  u16*   iwIb  = (u16*)  (ws + 14680576);     // [2048][512] bf16         2,097,152
  u16*   owTVb = (u16*)  (ws + 16777728);     // [1024][512] bf16         1,048,576
  u16*   owTIb = (u16*)  (ws + 17826304);     // [1024][512] bf16         1,048,576
  u16*   rswb  = (u16*)  (ws + 18874880);     // [256][512] bf16            262,144
  u16*   crwb  = (u16*)  (ws + 19137024);     // [512][256] bf16            262,144
  u16*   xT    = (u16*)  (ws + 19399168);     // [4][1024][256] bf16      2,097,152
  u16*   W2b   = (u16*)  (ws + 21496320);     // [2][256][1024] bf16      1,048,576
  float* part  = (float*)(ws + 22544896);     // [4][16][512] f32           131,072
  u16*   xp    = (u16*)  (ws + 22675968);     // [2][2048][2048] bf16    16,777,216
  u16*   comb  = (u16*)  (ws + 39453184);     // [2][2048][1024] bf16     8,388,608
  // alias (lifetime-disjoint):
  u16*   hfin  = (u16*)  (ws + 0);            // [4][32][2048][16] bf16   8,388,608 (xr dead after k2_pool)

  k0_cvt      <<<dim3(64,4),    dim3(256), 0, stream>>>(mV_in_w, mI_in_w, cr_w, rs_w,
                                                        iwVb, iwIb, crwb, rswb);
  k0_tr       <<<dim3(32,16,6), dim3(256), 0, stream>>>(mV_ow, mI_ow, x_V, x_I,
                                                        owTVb, owTIb, xT);
  k0b_w2      <<<dim3(2,8,2),   dim3(256), 0, stream>>>(rswb, owTVb, owTIb, W2b);
  k1_mfma     <<<dim3(64,8),    dim3(256), 0, stream>>>(xT, crwb, cr_g, cr_b, cr_m, cr_v, xr);
  k2_ln       <<<dim3(4096),    dim3(64),  0, stream>>>(xr, mV_ln_g,mV_ln_b, mI_ln_g,mI_ln_b, xn);
  k2_pool     <<<dim3(16,4),    dim3(256), 0, stream>>>(xr, part);
  k2_lambda   <<<dim3(4),       dim3(256), 0, stream>>>(part, lpV_w1,lpV_b1,lpV_w2,lpV_b2,
                                                              lpI_w1,lpI_b1,lpI_w2,lpI_b2, lam);
  k3_mfma     <<<dim3(16,16,2), dim3(256), 0, stream>>>(xn, iwVb, iwIb, xp);
  k4s1        <<<dim3(8,CH,2),  dim3(256), 0, stream>>>(xp, mV_A, mI_A, hfin);
  k4b_prefix  <<<dim3(8,4),     dim3(256), 0, stream>>>(mV_A, mI_A, hfin);
  k4s2        <<<dim3(8,CH,2),  dim3(256), 0, stream>>>(xp, hfin, mV_A, mI_A, mV_B, mI_B,
                                                        mV_C, mI_C, lam, comb);
  k5_fused    <<<dim3(32,4,2),  dim3(256), 0, stream>>>(comb, W2b, x_V, x_I,
                                                        rs_g, rs_b, rs_m, rs_v, out);
}

// Round 7
// 122.314 us; speedup vs baseline: 5.5752x; 1.0583x over previous
//
#include <hip/hip_runtime.h>
#include <math.h>

typedef unsigned short u16;
typedef unsigned int   u32;
typedef __bf16 bf16x8 __attribute__((ext_vector_type(8)));
typedef float  f32x4  __attribute__((ext_vector_type(4)));

#define PP   2
#define LQ   1024     // H*W
#define DM   512      // d_model
#define DI   1024     // d_inner
#define NS   16       // d_state
#define CIN  256
#define EPSF 1e-5f
#define CH   32       // scan chunks
#define TL   32       // chunk length (CH*TL == LQ)

__device__ __forceinline__ float bf2f(u16 u){ return __uint_as_float(((u32)u)<<16); }
__device__ __forceinline__ u16 f2bf(float f){
  u32 x = __float_as_uint(f);
  x += 0x7fffu + ((x>>16)&1u);           // RNE
  return (u16)(x>>16);
}
__device__ __forceinline__ float sigm(float x){ return 1.f/(1.f+expf(-x)); }

__device__ __forceinline__ void ld8(const u16* p, float* f){
  const uint4 v = *(const uint4*)p;
  f[0]=bf2f((u16)v.x); f[1]=bf2f((u16)(v.x>>16));
  f[2]=bf2f((u16)v.y); f[3]=bf2f((u16)(v.y>>16));
  f[4]=bf2f((u16)v.z); f[5]=bf2f((u16)(v.z>>16));
  f[6]=bf2f((u16)v.w); f[7]=bf2f((u16)(v.w>>16));
}
__device__ __forceinline__ void st8(u16* p, const float* f){
  uint4 v;
  v.x = (u32)f2bf(f[0]) | ((u32)f2bf(f[1])<<16);
  v.y = (u32)f2bf(f[2]) | ((u32)f2bf(f[3])<<16);
  v.z = (u32)f2bf(f[4]) | ((u32)f2bf(f[5])<<16);
  v.w = (u32)f2bf(f[6]) | ((u32)f2bf(f[7])<<16);
  *(uint4*)p = v;
}

// ---- async global->LDS DMA: 16 B per lane, dest = uniform base + lane*16 ----
typedef const __attribute__((address_space(1))) u32* gas_t;
typedef __attribute__((address_space(3))) u32* las_t;
__device__ __forceinline__ void gld16(const void* g, void* l){
  __builtin_amdgcn_global_load_lds((gas_t)g, (las_t)l, 16, 0, 0);
}

// ---- unified MFMA GEMM main loop: TMxTN tile, BK=64, 4 waves (2x2) ----
// LDS layout: linear [row][64] with XOR-swizzled chunk slots (rule #21: linear
// gload_lds dest + inverse-swz global SOURCE + swz READ, same involution).
// Row r stores k-chunk p (8 bf16) at slot p ^ (r&7)  ->  frag reads hit 8
// distinct 16B slots per 16-lane group (pairwise broadcast) = conflict-free.
template<int TM, int TN>
__device__ __forceinline__ void gemm_main(const u16* __restrict__ A, const u16* __restrict__ B,
                                          int K, u16* As, u16* Bs,
                                          f32x4 (&acc)[TM/32][TN/32], int tid)
{
  const int lane = tid&63, w = tid>>6;
  const int m_off = (w>>1)*(TM/2), n_off = (w&1)*(TN/2);
  const int lr = lane>>3, lp = lane&7;           // stage: lane-row, lane-slot
  const int pos = lp ^ lr;                       // source k-chunk for this slot
  for (int k0=0; k0<K; k0+=64){
    #pragma unroll
    for (int j=0;j<TM/32;++j){
      const int rb = (w*(TM/32)+j)*8;
      gld16(A + (size_t)(rb+lr)*K + k0 + (pos<<3), As + rb*64);
    }
    #pragma unroll
    for (int j=0;j<TN/32;++j){
      const int rb = (w*(TN/32)+j)*8;
      gld16(B + (size_t)(rb+lr)*K + k0 + (pos<<3), Bs + rb*64);
    }
    __syncthreads();
    #pragma unroll
    for (int ks=0;ks<2;++ks){
      const int c = ks*4 + (lane>>4);            // k-chunk this frag wants
      bf16x8 af[TM/32], bb[TN/32];
      #pragma unroll
      for (int mi=0;mi<TM/32;++mi){
        const int R = m_off + mi*16 + (lane&15);
        af[mi] = *(const bf16x8*)(As + R*64 + ((c ^ (R&7))<<3));
      }
      #pragma unroll
      for (int ni=0;ni<TN/32;++ni){
        const int R = n_off + ni*16 + (lane&15);
        bb[ni] = *(const bf16x8*)(Bs + R*64 + ((c ^ (R&7))<<3));
      }
      #pragma unroll
      for (int mi=0;mi<TM/32;++mi)
        #pragma unroll
        for (int ni=0;ni<TN/32;++ni)
          acc[mi][ni] = __builtin_amdgcn_mfma_f32_16x16x32_bf16(af[mi], bb[ni], acc[mi][ni], 0,0,0);
    }
    __syncthreads();
  }
}

// K0: plain f32 -> bf16 conversion (iwV, iwI, crw, rsw)
__global__ __launch_bounds__(256) void k0_cvt(
    const float* __restrict__ s0, const float* __restrict__ s1,
    const float* __restrict__ s2, const float* __restrict__ s3,
    u16* __restrict__ d0, u16* __restrict__ d1, u16* __restrict__ d2,
    u16* __restrict__ d3)
{
  const int which = blockIdx.y;
  const float* s; u16* d; int n;
  switch(which){
    case 0: s=s0; d=d0; n=1048576; break;
    case 1: s=s1; d=d1; n=1048576; break;
    case 2: s=s2; d=d2; n=131072;  break;
    default: s=s3; d=d3; n=131072; break;
  }
  for (int i = (blockIdx.x*256+threadIdx.x)*4; i < n; i += gridDim.x*256*4){
    const float4 v = *(const float4*)(s+i);
    ushort4 o; o.x=f2bf(v.x); o.y=f2bf(v.y); o.z=f2bf(v.z); o.w=f2bf(v.w);
    *(ushort4*)(d+i) = o;
  }
}

// K0t: transpose-convert f32 [R][C] -> bf16 [C][R].
__global__ __launch_bounds__(256) void k0_tr(
    const float* __restrict__ owV, const float* __restrict__ owI,
    const float* __restrict__ xV,  const float* __restrict__ xI,
    u16* __restrict__ owTV, u16* __restrict__ owTI, u16* __restrict__ xT)
{
  const int z = blockIdx.z;
  int R, C; const float* src; u16* dst;
  if (z < 2){ R=512; C=1024; src = z? owI : owV; dst = z? owTI : owTV; }
  else {
    R=256; C=1024;
    const int img = z-2;               // 0: V b0, 1: V b1, 2: I b0, 3: I b1
    src = (img<2 ? xV : xI) + (size_t)(img&1)*CIN*LQ;
    dst = xT + (size_t)img*LQ*CIN;
  }
  const int r0 = blockIdx.y*32, c0 = blockIdx.x*32;
  if (r0 >= R) return;
  __shared__ float tile[32][33];
  const int tid = threadIdx.x;
  {
    const int r = tid>>3, c = (tid&7)*4;
    const float4 v = *(const float4*)(src + (size_t)(r0+r)*C + c0 + c);
    tile[r][c]=v.x; tile[r][c+1]=v.y; tile[r][c+2]=v.z; tile[r][c+3]=v.w;
  }
  __syncthreads();
  {
    const int cl = tid>>3, rl = (tid&7)*4;
    ushort4 o;
    o.x = f2bf(tile[rl+0][cl]); o.y = f2bf(tile[rl+1][cl]);
    o.z = f2bf(tile[rl+2][cl]); o.w = f2bf(tile[rl+3][cl]);
    *(ushort4*)(dst + (size_t)(c0+cl)*R + r0 + rl) = o;
  }
}

// K0b: W2[p][q][kk] = sum_n rsw[q][n]*ow_p[n][kk]  (M=256,N=1024,K=512)
__global__ __launch_bounds__(256) void k0b_w2(
    const u16* __restrict__ rswb, const u16* __restrict__ owTV, const u16* __restrict__ owTI,
    u16* __restrict__ W2b)
{
  const int p = blockIdx.z;
  const u16* __restrict__ B = (p? owTI : owTV);
  const int m0 = blockIdx.x*128, n0 = blockIdx.y*128;
  __shared__ __align__(16) u16 As[128*64];
  __shared__ __align__(16) u16 Bs[128*64];
  const int tid = threadIdx.x, lane = tid&63, wid = tid>>6;
  const int m_off = (wid>>1)*64, n_off = (wid&1)*64;
  f32x4 acc[4][4];
  const f32x4 z = {0.f,0.f,0.f,0.f};
  #pragma unroll
  for (int mi=0;mi<4;++mi) for (int ni=0;ni<4;++ni) acc[mi][ni]=z;
  gemm_main<128,128>(rswb + (size_t)m0*DM, B + (size_t)n0*DM, DM, As, Bs, acc, tid);
  u16* __restrict__ orow = W2b + (size_t)p*256*1024;
  #pragma unroll
  for (int mi=0;mi<4;++mi)
    #pragma unroll
    for (int rr=0;rr<4;++rr){
      const int m = m0 + m_off + mi*16 + ((lane>>4)<<2) + rr;
      #pragma unroll
      for (int ni=0;ni<4;++ni){
        const int n = n0 + n_off + ni*16 + (lane&15);
        orow[(size_t)m*1024 + n] = f2bf(acc[mi][ni][rr]);
      }
    }
}

// K1 (MFMA): xr[m][n] = relu(bn( xT[m][:] . crwb[n][:] )),  M=4096 N=512 K=256
__global__ __launch_bounds__(256) void k1_mfma(
    const u16* __restrict__ xT, const u16* __restrict__ crwb,
    const float* __restrict__ crg, const float* __restrict__ crb,
    const float* __restrict__ crm, const float* __restrict__ crv,
    float* __restrict__ xr)
{
  const int m0 = blockIdx.x*64, n0 = blockIdx.y*64;
  __shared__ __align__(16) u16 As[64*64];
  __shared__ __align__(16) u16 Bs[64*64];
  const int tid = threadIdx.x, lane = tid&63, wid = tid>>6;
  const int m_off = (wid>>1)*32, n_off = (wid&1)*32;
  f32x4 acc[2][2];
  const f32x4 z = {0.f,0.f,0.f,0.f};
  #pragma unroll
  for (int mi=0;mi<2;++mi) for (int ni=0;ni<2;++ni) acc[mi][ni]=z;
  gemm_main<64,64>(xT + (size_t)m0*CIN, crwb + (size_t)n0*CIN, CIN, As, Bs, acc, tid);
  #pragma unroll
  for (int mi=0;mi<2;++mi)
    #pragma unroll
    for (int ni=0;ni<2;++ni){
      const int n = n0 + n_off + ni*16 + (lane&15);
      const float s = crg[n]*rsqrtf(crv[n]+EPSF);
      const float t = crb[n] - crm[n]*s;
      #pragma unroll
      for (int rr=0;rr<4;++rr){
        const int m = m0 + m_off + mi*16 + ((lane>>4)<<2) + rr;
        xr[(size_t)m*DM + n] = fmaxf(fmaf(acc[mi][ni][rr], s, t), 0.f);
      }
    }
}

// K2ln: per-row LN over DM, write bf16 xn
__global__ __launch_bounds__(64) void k2_ln(
    const float* __restrict__ xr,
    const float* __restrict__ lgV, const float* __restrict__ lbV,
    const float* __restrict__ lgI, const float* __restrict__ lbI,
    u16* __restrict__ xn)
{
  const int row = blockIdx.x;        // p*2048 + m
  const int p = row>>11;
  const int lane = threadIdx.x;
  const float* __restrict__ base = xr + (size_t)row*DM + lane*8;
  const float* __restrict__ lg = (p? lgI : lgV) + lane*8;
  const float* __restrict__ lb = (p? lbI : lbV) + lane*8;
  float v[8];
  *(float4*)&v[0] = *(const float4*)(base);
  *(float4*)&v[4] = *(const float4*)(base+4);
  float s=0.f, q=0.f;
  #pragma unroll
  for (int j=0;j<8;++j){ s += v[j]; q += v[j]*v[j]; }
  #pragma unroll
  for (int off=32; off; off>>=1){ s += __shfl_down(s,off); q += __shfl_down(q,off); }
  s = __shfl(s,0); q = __shfl(q,0);
  const float mean = s*(1.f/DM);
  const float rstd = rsqrtf(fmaxf(q*(1.f/DM) - mean*mean, 0.f)+EPSF);
  float g[8], be[8], y[8];
  *(float4*)&g[0]  = *(const float4*)(lg);
  *(float4*)&g[4]  = *(const float4*)(lg+4);
  *(float4*)&be[0] = *(const float4*)(lb);
  *(float4*)&be[4] = *(const float4*)(lb+4);
  #pragma unroll
  for (int j=0;j<8;++j) y[j] = (v[j]-mean)*rstd*g[j] + be[j];
  st8(xn + (size_t)row*DM + lane*8, y);
}

// K2p: part[img][sl][ch] = sum over 64 t of xr[img][sl*64+t][ch]
__global__ __launch_bounds__(256) void k2_pool(const float* __restrict__ xr,
                                               float* __restrict__ part)
{
  const int img = blockIdx.y, sl = blockIdx.x;
  const int tid = threadIdx.x;
  const float* __restrict__ base = xr + ((size_t)img*LQ + sl*64)*DM;
  float s0=0.f, s1=0.f;
  for (int t=0;t<64;++t){
    s0 += base[(size_t)t*DM + tid];
    s1 += base[(size_t)t*DM + 256 + tid];
  }
  part[((size_t)img*16 + sl)*DM + tid]       = s0;
  part[((size_t)img*16 + sl)*DM + 256 + tid] = s1;
}

// K2: lam[img] = sigmoid(relu(pool@w1^T+b1)@w2^T+b2)
__global__ __launch_bounds__(256) void k2_lambda(
    const float* __restrict__ part,
    const float* __restrict__ w1V, const float* __restrict__ b1V,
    const float* __restrict__ w2V, const float* __restrict__ b2V,
    const float* __restrict__ w1I, const float* __restrict__ b1I,
    const float* __restrict__ w2I, const float* __restrict__ b2I,
    float* __restrict__ lam)
{
  const int img = blockIdx.x, p = img>>1;
  const float* __restrict__ w1 = p? w1I : w1V;
  const float* __restrict__ b1 = p? b1I : b1V;
  const float* __restrict__ w2 = p? w2I : w2V;
  const float* __restrict__ b2 = p? b2I : b2V;
  __shared__ float pool[DM];
  __shared__ float hb[128];
  const int tid = threadIdx.x;
  for (int ch=tid; ch<DM; ch+=256){
    float s=0.f;
    #pragma unroll
    for (int sl=0; sl<16; ++sl) s += part[((size_t)img*16 + sl)*DM + ch];
    pool[ch] = s * (1.f/LQ);
  }
  __syncthreads();
  if (tid<128){
    float h = b1[tid];
    const float* __restrict__ wr = w1 + (size_t)tid*DM;
    for (int o=0;o<DM;o+=4){
      const float4 w = *(const float4*)(wr+o);
      h += pool[o]*w.x + pool[o+1]*w.y + pool[o+2]*w.z + pool[o+3]*w.w;
    }
    hb[tid] = fmaxf(h,0.f);
  }
  __syncthreads();
  if (tid==0){
    float v = b2[0];
    for (int j=0;j<128;++j) v += hb[j]*w2[j];
    lam[img] = sigm(v);
  }
}

// K3 (MFMA): xp[p][m][n] = bf16( xn[p][m][:] . iw[n][:] ),  M=2048 N=2048 K=512
__global__ __launch_bounds__(256) void k3_mfma(
    const u16* __restrict__ xn, const u16* __restrict__ iwVb, const u16* __restrict__ iwIb,
    u16* __restrict__ xp)
{
  const int p = blockIdx.z;
  const u16* __restrict__ A  = xn + (size_t)p*2048*DM;
  const u16* __restrict__ Bw = p? iwIb : iwVb;
  const int m0 = blockIdx.x*128, n0 = blockIdx.y*128;
  __shared__ __align__(16) u16 As[128*64];
  __shared__ __align__(16) u16 Bs[128*64];
  const int tid = threadIdx.x, lane = tid&63, wid = tid>>6;
  const int m_off = (wid>>1)*64, n_off = (wid&1)*64;
  f32x4 acc[4][4];
  const f32x4 z = {0.f,0.f,0.f,0.f};
  #pragma unroll
  for (int mi=0;mi<4;++mi) for (int ni=0;ni<4;++ni) acc[mi][ni]=z;
  gemm_main<128,128>(A + (size_t)m0*DM, Bw + (size_t)n0*DM, DM, As, Bs, acc, tid);
  u16* __restrict__ orow = xp + (size_t)p*2048*2048;
  #pragma unroll
  for (int mi=0;mi<4;++mi)
    #pragma unroll
    for (int rr=0;rr<4;++rr){
      const int m = m0 + m_off + mi*16 + ((lane>>4)<<2) + rr;
      #pragma unroll
      for (int ni=0;ni<4;++ni){
        const int n = n0 + n_off + ni*16 + (lane&15);
        orow[(size_t)m*2048 + n] = f2bf(acc[mi][ni][rr]);
      }
    }
}

// ---- chunked scan in u-space: u_t = a*u_{t-1} + x_t  (B-free; h = B.*u exactly) ----
__global__ __launch_bounds__(256) void k4s1(
    const u16* __restrict__ xp,
    const float* __restrict__ AlV, const float* __restrict__ AlI,
    u16* __restrict__ hfin)
{
  const int p = blockIdx.z, c = blockIdx.y, rb = blockIdx.x;
  const int tid = threadIdx.x;
  const int row = rb*256 + tid;            // b*1024 + i
  const int bb = rb>>2;
  const int il = (rb&3)*256;               // i block base
  const int i  = il + tid;
  __shared__ __align__(16) u16 xs[TL*256];
  {
    const u16* src = xp + ((size_t)(p*2048 + bb*1024 + c*TL))*2048 + il;
    const int r0 = tid>>5, cb = (tid&31)*8;
    #pragma unroll
    for (int rr=0; rr<TL; rr+=8)
      *(uint4*)(xs + (rr+r0)*256 + cb) = *(const uint4*)(src + (size_t)(rr+r0)*2048 + cb);
  }
  const float* __restrict__ Al = p? AlI : AlV;
  float a[16], uf[16], ub[16];
  #pragma unroll
  for (int s=0;s<16;s+=4){
    const float4 al = *(const float4*)(Al + (size_t)i*NS + s);
    a[s]=-expf(al.x); a[s+1]=-expf(al.y); a[s+2]=-expf(al.z); a[s+3]=-expf(al.w);
    uf[s]=0.f; uf[s+1]=0.f; uf[s+2]=0.f; uf[s+3]=0.f;
    ub[s]=0.f; ub[s+1]=0.f; ub[s+2]=0.f; ub[s+3]=0.f;
  }
  __syncthreads();
  #pragma unroll 4
  for (int tt=0; tt<TL; ++tt){
    const float xf = bf2f(xs[tt*256 + tid]);
    const float xb = bf2f(xs[(TL-1-tt)*256 + tid]);
    #pragma unroll
    for (int s=0;s<16;++s){
      uf[s] = fmaf(uf[s], a[s], xf);
      ub[s] = fmaf(ub[s], a[s], xb);
    }
  }
  u16* hpf = hfin + (((size_t)(p*2+0)*CH + c)*2048 + row)*NS;
  u16* hpb = hfin + (((size_t)(p*2+1)*CH + c)*2048 + row)*NS;
  st8(hpf, uf); st8(hpf+8, uf+8);
  st8(hpb, ub); st8(hpb+8, ub+8);
}

__global__ __launch_bounds__(256) void k4b_prefix(
    const float* __restrict__ AlV, const float* __restrict__ AlI,
    u16* __restrict__ hfin)
{
  const int z = blockIdx.y, dir = z&1, p = z>>1;
  const int row = blockIdx.x*256 + threadIdx.x;
  const int i = row & 1023;
  const float* __restrict__ Al = p? AlI : AlV;
  float aT[16], H[16];
  #pragma unroll
  for (int s=0;s<16;s+=4){
    const float4 al = *(const float4*)(Al + (size_t)i*NS + s);
    const float sc = (float)TL;
    aT[s]  =expf(sc*al.x); aT[s+1]=expf(sc*al.y);
    aT[s+2]=expf(sc*al.z); aT[s+3]=expf(sc*al.w);
    H[s]=0.f; H[s+1]=0.f; H[s+2]=0.f; H[s+3]=0.f;
  }
  for (int k=0;k<CH;++k){
    const int c = dir ? (CH-1-k) : k;
    u16* hp = hfin + (((size_t)z*CH + c)*2048 + row)*NS;
    float fin[16];
    ld8(hp, fin); ld8(hp+8, fin+8);
    st8(hp, H);  st8(hp+8, H+8);
    #pragma unroll
    for (int s=0;s<16;++s) H[s] = fmaf(aT[s], H[s], fin[s]);
  }
}

// K4s2: final sweep seeded with exact inits; emits comb directly.
__global__ __launch_bounds__(256,2) void k4s2(
    const u16* __restrict__ xp, const u16* __restrict__ hfin,
    const float* __restrict__ AlV, const float* __restrict__ AlI,
    const float* __restrict__ BV,  const float* __restrict__ BI,
    const float* __restrict__ CV,  const float* __restrict__ CI,
    const float* __restrict__ lam, u16* __restrict__ comb)
{
  const int p = blockIdx.z, c = blockIdx.y, rb = blockIdx.x;
  const int tid = threadIdx.x;
  const int row = rb*256 + tid;
  const int bb = rb>>2;
  const int il = (rb&3)*256;
  const int i  = il + tid;
  __shared__ __align__(16) u16  xs[TL*256];
  __shared__ __align__(16) float ps[TL*256];
  {
    const u16* src = xp + ((size_t)(p*2048 + bb*1024 + c*TL))*2048 + il;
    const int r0 = tid>>5, cb = (tid&31)*8;
    #pragma unroll
    for (int rr=0; rr<TL; rr+=8)
      *(uint4*)(xs + (rr+r0)*256 + cb) = *(const uint4*)(src + (size_t)(rr+r0)*2048 + cb);
  }
  const float* __restrict__ Al = p? AlI : AlV;
  const float* __restrict__ B0 = p? BI : BV;    // own B
  const float* __restrict__ B1 = p? BV : BI;    // other's B (cross)
  const float* __restrict__ Cm = p? CI : CV;
  const float lm = lam[p*2+bb];
  float a[16], dmix[16], uf[16], ub[16];
  #pragma unroll
  for (int s=0;s<16;s+=4){
    const float4 al = *(const float4*)(Al + (size_t)i*NS + s);
    const float4 b0 = *(const float4*)(B0 + (size_t)i*NS + s);
    const float4 b1 = *(const float4*)(B1 + (size_t)i*NS + s);
    const float4 cv = *(const float4*)(Cm + (size_t)i*NS + s);
    a[s]=-expf(al.x); a[s+1]=-expf(al.y); a[s+2]=-expf(al.z); a[s+3]=-expf(al.w);
    dmix[s]  =(lm*b0.x+(1.f-lm)*b1.x)*cv.x;
    dmix[s+1]=(lm*b0.y+(1.f-lm)*b1.y)*cv.y;
    dmix[s+2]=(lm*b0.z+(1.f-lm)*b1.z)*cv.z;
    dmix[s+3]=(lm*b0.w+(1.f-lm)*b1.w)*cv.w;
  }
  {
    const u16* hpf = hfin + (((size_t)(p*2+0)*CH + c)*2048 + row)*NS;
    const u16* hpb = hfin + (((size_t)(p*2+1)*CH + c)*2048 + row)*NS;
    ld8(hpf, uf); ld8(hpf+8, uf+8);
    ld8(hpb, ub); ld8(hpb+8, ub+8);
  }
  __syncthreads();
  #pragma unroll 2
  for (int tt=0; tt<TL; ++tt){
    const float xf = bf2f(xs[tt*256 + tid]);
    const float xb = bf2f(xs[(TL-1-tt)*256 + tid]);
    float yf0=0.f, yf1=0.f, yb0=0.f, yb1=0.f;
    #pragma unroll
    for (int s=0;s<16;s+=2){
      uf[s]   = fmaf(uf[s],   a[s],   xf);
      uf[s+1] = fmaf(uf[s+1], a[s+1], xf);
      ub[s]   = fmaf(ub[s],   a[s],   xb);
      ub[s+1] = fmaf(ub[s+1], a[s+1], xb);
      yf0 = fmaf(uf[s],   dmix[s],   yf0);
      yf1 = fmaf(uf[s+1], dmix[s+1], yf1);
      yb0 = fmaf(ub[s],   dmix[s],   yb0);
      yb1 = fmaf(ub[s+1], dmix[s+1], yb1);
    }
    const float yf = yf0+yf1, yb = yb0+yb1;
    if (tt < TL/2){
      ps[tt*256 + tid]          = yf;
      ps[(TL-1-tt)*256 + tid]   = yb;
    } else {
      ps[tt*256 + tid]         += yf;
      ps[(TL-1-tt)*256 + tid]  += yb;
    }
  }
  __syncthreads();
  const int r0 = tid>>5, cb = (tid&31)*8;
  #pragma unroll
  for (int rr=0; rr<TL; rr+=8){
    const int r = rr + r0;
    const size_t mrow = (size_t)(p*2048 + bb*1024 + c*TL + r);
    float g8[8], o[8];
    ld8(xp + mrow*2048 + DI + il + cb, g8);
    #pragma unroll
    for (int j=0;j<8;++j){
      const float pv = ps[r*256 + cb + j];
      o[j] = 0.5f*g8[j]*sigm(g8[j])*pv;
    }
    st8(comb + mrow*(size_t)DI + il + cb, o);
  }
}

// K5 (MFMA, fused): out[img][q][hw] = x[img][q][hw] + bn( comb[p][m][:] . W2[p][q][:] )
__global__ __launch_bounds__(256) void k5_fused(
    const u16* __restrict__ comb, const u16* __restrict__ W2b,
    const float* __restrict__ xV, const float* __restrict__ xI,
    const float* __restrict__ rsg, const float* __restrict__ rsb,
    const float* __restrict__ rsm, const float* __restrict__ rsv,
    float* __restrict__ out)
{
  const int p = blockIdx.z;
  const int m0 = blockIdx.x*64, n0 = blockIdx.y*64;
  const u16* __restrict__ A = comb + (size_t)p*2048*DI;
  const u16* __restrict__ B = W2b + (size_t)p*256*1024;
  __shared__ __align__(16) u16 As[64*64];
  __shared__ __align__(16) u16 Bs[64*64];
  const int tid = threadIdx.x, lane = tid&63, wid = tid>>6;
  const int m_off = (wid>>1)*32, n_off = (wid&1)*32;
  f32x4 acc[2][2];
  const f32x4 z = {0.f,0.f,0.f,0.f};
  #pragma unroll
  for (int mi=0;mi<2;++mi) for (int ni=0;ni<2;++ni) acc[mi][ni]=z;
  gemm_main<64,64>(A + (size_t)m0*DI, B + (size_t)n0*DI, DI, As, Bs, acc, tid);
  const int bb = m0>>10;                 // batch within p (m0 tiles don't straddle)
  const int img = p*2 + bb;
  const float* __restrict__ xres = (p? xI : xV) + (size_t)bb*CIN*LQ;
  float* __restrict__ obase = out + (size_t)img*CIN*LQ;
  #pragma unroll
  for (int mi=0;mi<2;++mi)
    #pragma unroll
    for (int ni=0;ni<2;++ni){
      const int q = n0 + n_off + ni*16 + (lane&15);
      const float s = rsg[q]*rsqrtf(rsv[q]+EPSF);
      const float t = rsb[q] - rsm[q]*s;
      const int m = m0 + m_off + mi*16 + ((lane>>4)<<2);
      const int hw = m & 1023;
      const float4 xv = *(const float4*)(xres + (size_t)q*LQ + hw);
      float4 o;
      o.x = fmaf(acc[mi][ni][0], s, t) + xv.x;
      o.y = fmaf(acc[mi][ni][1], s, t) + xv.y;
      o.z = fmaf(acc[mi][ni][2], s, t) + xv.z;
      o.w = fmaf(acc[mi][ni][3], s, t) + xv.w;
      *(float4*)(obase + (size_t)q*LQ + hw) = o;
    }
}

extern "C" void kernel_launch(void* const* d_in, const int* in_sizes, int n_in,
                              void* d_out, int out_size, void* d_ws, size_t ws_size,
                              hipStream_t stream)
{
  const float* cr_w = (const float*)d_in[0];
  const float* cr_g = (const float*)d_in[1];
  const float* cr_b = (const float*)d_in[2];
  const float* cr_m = (const float*)d_in[3];
  const float* cr_v = (const float*)d_in[4];
  const float* rs_w = (const float*)d_in[5];
  const float* rs_g = (const float*)d_in[6];
  const float* rs_b = (const float*)d_in[7];
  const float* rs_m = (const float*)d_in[8];
  const float* rs_v = (const float*)d_in[9];
  const float* mV_ln_g = (const float*)d_in[10];
  const float* mV_ln_b = (const float*)d_in[11];
  const float* mV_in_w = (const float*)d_in[12];
  const float* mV_A    = (const float*)d_in[13];
  const float* mV_B    = (const float*)d_in[14];
  const float* mV_C    = (const float*)d_in[15];
  const float* mV_ow   = (const float*)d_in[16];
  const float* lpV_w1  = (const float*)d_in[17];
  const float* lpV_b1  = (const float*)d_in[18];
  const float* lpV_w2  = (const float*)d_in[19];
  const float* lpV_b2  = (const float*)d_in[20];
  const float* mI_ln_g = (const float*)d_in[21];
  const float* mI_ln_b = (const float*)d_in[22];
  const float* mI_in_w = (const float*)d_in[23];
  const float* mI_A    = (const float*)d_in[24];
  const float* mI_B    = (const float*)d_in[25];
  const float* mI_C    = (const float*)d_in[26];
  const float* mI_ow   = (const float*)d_in[27];
  const float* lpI_w1  = (const float*)d_in[28];
  const float* lpI_b1  = (const float*)d_in[29];
  const float* lpI_w2  = (const float*)d_in[30];
  const float* lpI_b2  = (const float*)d_in[31];
  const float* x_V = (const float*)d_in[32];
  const float* x_I = (const float*)d_in[33];
  float* out = (float*)d_out;

  char* ws = (char*)d_ws;
  // layout (~47.8 MB peak):
  float* xr    = (float*)(ws + 0);            // [4096][512] f32          8,388,608
  u16*   xn    = (u16*)  (ws + 8388608);      // [2][2048][512] bf16      4,194,304
  float* lam   = (float*)(ws + 12582912);     // [4] f32 (+pad)                 512
  u16*   iwVb  = (u16*)  (ws + 12583424);     // [2048][512] bf16         2,097,152
  u16*   iwIb  = (u16*)  (ws + 14680576);     // [2048][512] bf16         2,097,152
  u16*   owTVb = (u16*)  (ws + 16777728);     // [1024][512] bf16         1,048,576
  u16*   owTIb = (u16*)  (ws + 17826304);     // [1024][512] bf16         1,048,576
  u16*   rswb  = (u16*)  (ws + 18874880);     // [256][512] bf16            262,144
  u16*   crwb  = (u16*)  (ws + 19137024);     // [512][256] bf16            262,144
  u16*   xT    = (u16*)  (ws + 19399168);     // [4][1024][256] bf16      2,097,152
  u16*   W2b   = (u16*)  (ws + 21496320);     // [2][256][1024] bf16      1,048,576
  float* part  = (float*)(ws + 22544896);     // [4][16][512] f32           131,072
  u16*   xp    = (u16*)  (ws + 22675968);     // [2][2048][2048] bf16    16,777,216
  u16*   comb  = (u16*)  (ws + 39453184);     // [2][2048][1024] bf16     8,388,608
  // alias (lifetime-disjoint):
  u16*   hfin  = (u16*)  (ws + 0);            // [4][32][2048][16] bf16   8,388,608 (xr dead after k2_pool)

  k0_cvt      <<<dim3(64,4),    dim3(256), 0, stream>>>(mV_in_w, mI_in_w, cr_w, rs_w,
                                                        iwVb, iwIb, crwb, rswb);
  k0_tr       <<<dim3(32,16,6), dim3(256), 0, stream>>>(mV_ow, mI_ow, x_V, x_I,
                                                        owTVb, owTIb, xT);
  k0b_w2      <<<dim3(2,8,2),   dim3(256), 0, stream>>>(rswb, owTVb, owTIb, W2b);
  k1_mfma     <<<dim3(64,8),    dim3(256), 0, stream>>>(xT, crwb, cr_g, cr_b, cr_m, cr_v, xr);
  k2_ln       <<<dim3(4096),    dim3(64),  0, stream>>>(xr, mV_ln_g,mV_ln_b, mI_ln_g,mI_ln_b, xn);
  k2_pool     <<<dim3(16,4),    dim3(256), 0, stream>>>(xr, part);
  k2_lambda   <<<dim3(4),       dim3(256), 0, stream>>>(part, lpV_w1,lpV_b1,lpV_w2,lpV_b2,
                                                              lpI_w1,lpI_b1,lpI_w2,lpI_b2, lam);
  k3_mfma     <<<dim3(16,16,2), dim3(256), 0, stream>>>(xn, iwVb, iwIb, xp);
  k4s1        <<<dim3(8,CH,2),  dim3(256), 0, stream>>>(xp, mV_A, mI_A, hfin);
  k4b_prefix  <<<dim3(8,4),     dim3(256), 0, stream>>>(mV_A, mI_A, hfin);
  k4s2        <<<dim3(8,CH,2),  dim3(256), 0, stream>>>(xp, hfin, mV_A, mI_A, mV_B, mI_B,
                                                        mV_C, mI_C, lam, comb);
  k5_fused    <<<dim3(32,4,2),  dim3(256), 0, stream>>>(comb, W2b, x_V, x_I,
                                                        rs_g, rs_b, rs_m, rs_v, out);
}

// Round 8
// 117.620 us; speedup vs baseline: 5.7977x; 1.0399x over previous
//
#include <hip/hip_runtime.h>
#include <math.h>

typedef unsigned short u16;
typedef unsigned int   u32;
typedef __bf16 bf16x8 __attribute__((ext_vector_type(8)));
typedef float  f32x4  __attribute__((ext_vector_type(4)));

#define PP   2
#define LQ   1024     // H*W
#define DM   512      // d_model
#define DI   1024     // d_inner
#define NS   16       // d_state
#define CIN  256
#define EPSF 1e-5f
#define CH   32       // scan chunks
#define TL   32       // chunk length (CH*TL == LQ)

__device__ __forceinline__ float bf2f(u16 u){ return __uint_as_float(((u32)u)<<16); }
__device__ __forceinline__ u16 f2bf(float f){
  u32 x = __float_as_uint(f);
  x += 0x7fffu + ((x>>16)&1u);           // RNE
  return (u16)(x>>16);
}
__device__ __forceinline__ float sigm(float x){ return 1.f/(1.f+expf(-x)); }

__device__ __forceinline__ void ld8(const u16* p, float* f){
  const uint4 v = *(const uint4*)p;
  f[0]=bf2f((u16)v.x); f[1]=bf2f((u16)(v.x>>16));
  f[2]=bf2f((u16)v.y); f[3]=bf2f((u16)(v.y>>16));
  f[4]=bf2f((u16)v.z); f[5]=bf2f((u16)(v.z>>16));
  f[6]=bf2f((u16)v.w); f[7]=bf2f((u16)(v.w>>16));
}
__device__ __forceinline__ void st8(u16* p, const float* f){
  uint4 v;
  v.x = (u32)f2bf(f[0]) | ((u32)f2bf(f[1])<<16);
  v.y = (u32)f2bf(f[2]) | ((u32)f2bf(f[3])<<16);
  v.z = (u32)f2bf(f[4]) | ((u32)f2bf(f[5])<<16);
  v.w = (u32)f2bf(f[6]) | ((u32)f2bf(f[7])<<16);
  *(uint4*)p = v;
}

// ---- async global->LDS DMA: 16 B per lane, dest = uniform base + lane*16 ----
typedef const __attribute__((address_space(1))) u32* gas_t;
typedef __attribute__((address_space(3))) u32* las_t;
__device__ __forceinline__ void gld16(const void* g, void* l){
  __builtin_amdgcn_global_load_lds((gas_t)g, (las_t)l, 16, 0, 0);
}

// ---- unified MFMA GEMM main loop: TMxTN tile, BK=64, 4 waves (2x2) ----
// LDS: linear [row][64] with XOR-swizzled chunk slots (linear gload_lds dest +
// inverse-swz global SOURCE + swz READ, same involution) -> conflict-free.
template<int TM, int TN>
__device__ __forceinline__ void gemm_main(const u16* __restrict__ A, const u16* __restrict__ B,
                                          int K, u16* As, u16* Bs,
                                          f32x4 (&acc)[TM/32][TN/32], int tid)
{
  const int lane = tid&63, w = tid>>6;
  const int m_off = (w>>1)*(TM/2), n_off = (w&1)*(TN/2);
  const int lr = lane>>3, lp = lane&7;           // stage: lane-row, lane-slot
  const int pos = lp ^ lr;                       // source k-chunk for this slot
  for (int k0=0; k0<K; k0+=64){
    #pragma unroll
    for (int j=0;j<TM/32;++j){
      const int rb = (w*(TM/32)+j)*8;
      gld16(A + (size_t)(rb+lr)*K + k0 + (pos<<3), As + rb*64);
    }
    #pragma unroll
    for (int j=0;j<TN/32;++j){
      const int rb = (w*(TN/32)+j)*8;
      gld16(B + (size_t)(rb+lr)*K + k0 + (pos<<3), Bs + rb*64);
    }
    __syncthreads();
    #pragma unroll
    for (int ks=0;ks<2;++ks){
      const int c = ks*4 + (lane>>4);            // k-chunk this frag wants
      bf16x8 af[TM/32], bb[TN/32];
      #pragma unroll
      for (int mi=0;mi<TM/32;++mi){
        const int R = m_off + mi*16 + (lane&15);
        af[mi] = *(const bf16x8*)(As + R*64 + ((c ^ (R&7))<<3));
      }
      #pragma unroll
      for (int ni=0;ni<TN/32;++ni){
        const int R = n_off + ni*16 + (lane&15);
        bb[ni] = *(const bf16x8*)(Bs + R*64 + ((c ^ (R&7))<<3));
      }
      #pragma unroll
      for (int mi=0;mi<TM/32;++mi)
        #pragma unroll
        for (int ni=0;ni<TN/32;++ni)
          acc[mi][ni] = __builtin_amdgcn_mfma_f32_16x16x32_bf16(af[mi], bb[ni], acc[mi][ni], 0,0,0);
    }
    __syncthreads();
  }
}

// K0prep: z=0..3 plain cvt (iwV,iwI,crw,rsw); z=4,5 transpose-cvt ow; z=6..9 transpose-cvt x imgs
__global__ __launch_bounds__(256) void k0_prep(
    const float* __restrict__ iwV, const float* __restrict__ iwI,
    const float* __restrict__ crw, const float* __restrict__ rsw,
    const float* __restrict__ owV, const float* __restrict__ owI,
    const float* __restrict__ xV,  const float* __restrict__ xI,
    u16* __restrict__ iwVb, u16* __restrict__ iwIb,
    u16* __restrict__ crwb, u16* __restrict__ rswb,
    u16* __restrict__ owTV, u16* __restrict__ owTI, u16* __restrict__ xT)
{
  const int z = blockIdx.z, tid = threadIdx.x;
  if (z < 4){
    const float* s; u16* d; int n;
    switch(z){
      case 0: s=iwV; d=iwVb; n=1048576; break;
      case 1: s=iwI; d=iwIb; n=1048576; break;
      case 2: s=crw; d=crwb; n=131072;  break;
      default: s=rsw; d=rswb; n=131072; break;
    }
    const int bid = blockIdx.y*32 + blockIdx.x;
    for (int i = (bid*256+tid)*4; i < n; i += 512*256*4){
      const float4 v = *(const float4*)(s+i);
      ushort4 o; o.x=f2bf(v.x); o.y=f2bf(v.y); o.z=f2bf(v.z); o.w=f2bf(v.w);
      *(ushort4*)(d+i) = o;
    }
    return;
  }
  int R; const float* src; u16* dst;
  if (z < 6){ R=512; src = (z==5)? owI : owV; dst = (z==5)? owTI : owTV; }
  else {
    R=256;
    const int img = z-6;               // 0: V b0, 1: V b1, 2: I b0, 3: I b1
    src = (img<2 ? xV : xI) + (size_t)(img&1)*CIN*LQ;
    dst = xT + (size_t)img*LQ*CIN;
  }
  const int r0 = blockIdx.y*32, c0 = blockIdx.x*32;
  if (r0 >= R) return;
  __shared__ float tile[32][33];
  {
    const int r = tid>>3, c = (tid&7)*4;
    const float4 v = *(const float4*)(src + (size_t)(r0+r)*1024 + c0 + c);
    tile[r][c]=v.x; tile[r][c+1]=v.y; tile[r][c+2]=v.z; tile[r][c+3]=v.w;
  }
  __syncthreads();
  {
    const int cl = tid>>3, rl = (tid&7)*4;
    ushort4 o;
    o.x = f2bf(tile[rl+0][cl]); o.y = f2bf(tile[rl+1][cl]);
    o.z = f2bf(tile[rl+2][cl]); o.w = f2bf(tile[rl+3][cl]);
    *(ushort4*)(dst + (size_t)(c0+cl)*R + r0 + rl) = o;
  }
}

// K0b: W2[p][q][kk] = sum_n rsw[q][n]*ow_p[n][kk]  (M=256,N=1024,K=512)
__global__ __launch_bounds__(256) void k0b_w2(
    const u16* __restrict__ rswb, const u16* __restrict__ owTV, const u16* __restrict__ owTI,
    u16* __restrict__ W2b)
{
  const int p = blockIdx.z;
  const u16* __restrict__ B = (p? owTI : owTV);
  const int m0 = blockIdx.x*128, n0 = blockIdx.y*128;
  __shared__ __align__(16) u16 As[128*64];
  __shared__ __align__(16) u16 Bs[128*64];
  const int tid = threadIdx.x, lane = tid&63, wid = tid>>6;
  const int m_off = (wid>>1)*64, n_off = (wid&1)*64;
  f32x4 acc[4][4];
  const f32x4 z = {0.f,0.f,0.f,0.f};
  #pragma unroll
  for (int mi=0;mi<4;++mi) for (int ni=0;ni<4;++ni) acc[mi][ni]=z;
  gemm_main<128,128>(rswb + (size_t)m0*DM, B + (size_t)n0*DM, DM, As, Bs, acc, tid);
  u16* __restrict__ orow = W2b + (size_t)p*256*1024;
  #pragma unroll
  for (int mi=0;mi<4;++mi)
    #pragma unroll
    for (int rr=0;rr<4;++rr){
      const int m = m0 + m_off + mi*16 + ((lane>>4)<<2) + rr;
      #pragma unroll
      for (int ni=0;ni<4;++ni){
        const int n = n0 + n_off + ni*16 + (lane&15);
        orow[(size_t)m*1024 + n] = f2bf(acc[mi][ni][rr]);
      }
    }
}

// K1 (MFMA): xr[m][n] = relu(bn( xT[m][:] . crwb[n][:] )),  M=4096 N=512 K=256
__global__ __launch_bounds__(256) void k1_mfma(
    const u16* __restrict__ xT, const u16* __restrict__ crwb,
    const float* __restrict__ crg, const float* __restrict__ crb,
    const float* __restrict__ crm, const float* __restrict__ crv,
    float* __restrict__ xr)
{
  const int m0 = blockIdx.x*64, n0 = blockIdx.y*64;
  __shared__ __align__(16) u16 As[64*64];
  __shared__ __align__(16) u16 Bs[64*64];
  const int tid = threadIdx.x, lane = tid&63, wid = tid>>6;
  const int m_off = (wid>>1)*32, n_off = (wid&1)*32;
  f32x4 acc[2][2];
  const f32x4 z = {0.f,0.f,0.f,0.f};
  #pragma unroll
  for (int mi=0;mi<2;++mi) for (int ni=0;ni<2;++ni) acc[mi][ni]=z;
  gemm_main<64,64>(xT + (size_t)m0*CIN, crwb + (size_t)n0*CIN, CIN, As, Bs, acc, tid);
  #pragma unroll
  for (int mi=0;mi<2;++mi)
    #pragma unroll
    for (int ni=0;ni<2;++ni){
      const int n = n0 + n_off + ni*16 + (lane&15);
      const float s = crg[n]*rsqrtf(crv[n]+EPSF);
      const float t = crb[n] - crm[n]*s;
      #pragma unroll
      for (int rr=0;rr<4;++rr){
        const int m = m0 + m_off + mi*16 + ((lane>>4)<<2) + rr;
        xr[(size_t)m*DM + n] = fmaxf(fmaf(acc[mi][ni][rr], s, t), 0.f);
      }
    }
}

// K2f: fused LN (-> bf16 xn) + pool partials. Block=(sl,img), 4 waves x 16 rows.
__global__ __launch_bounds__(256) void k2f(
    const float* __restrict__ xr,
    const float* __restrict__ lgV, const float* __restrict__ lbV,
    const float* __restrict__ lgI, const float* __restrict__ lbI,
    u16* __restrict__ xn, float* __restrict__ part)
{
  const int sl = blockIdx.x, img = blockIdx.y, p = img>>1;
  const int tid = threadIdx.x, w = tid>>6, l = tid&63;
  const float* __restrict__ lg = (p? lgI : lgV) + l*8;
  const float* __restrict__ lb = (p? lbI : lbV) + l*8;
  float g8[8], b8[8];
  *(float4*)&g8[0] = *(const float4*)lg;  *(float4*)&g8[4] = *(const float4*)(lg+4);
  *(float4*)&b8[0] = *(const float4*)lb;  *(float4*)&b8[4] = *(const float4*)(lb+4);
  float acc[8] = {};
  const int rbase = img*1024 + sl*64 + w*16;
  for (int r=0; r<16; ++r){
    const int row = rbase + r;
    const float* __restrict__ base = xr + (size_t)row*DM + l*8;
    float v[8];
    *(float4*)&v[0] = *(const float4*)(base);
    *(float4*)&v[4] = *(const float4*)(base+4);
    float s=0.f, q=0.f;
    #pragma unroll
    for (int j=0;j<8;++j){ s += v[j]; q += v[j]*v[j]; acc[j] += v[j]; }
    #pragma unroll
    for (int off=32; off; off>>=1){ s += __shfl_down(s,off); q += __shfl_down(q,off); }
    s = __shfl(s,0); q = __shfl(q,0);
    const float mean = s*(1.f/DM);
    const float rstd = rsqrtf(fmaxf(q*(1.f/DM) - mean*mean, 0.f)+EPSF);
    float y[8];
    #pragma unroll
    for (int j=0;j<8;++j) y[j] = (v[j]-mean)*rstd*g8[j] + b8[j];
    st8(xn + (size_t)row*DM + l*8, y);
  }
  __shared__ float pw[4][512];
  #pragma unroll
  for (int j=0;j<8;++j) pw[w][l*8+j] = acc[j];
  __syncthreads();
  for (int ch=tid; ch<DM; ch+=256)
    part[((size_t)img*16 + sl)*DM + ch] = pw[0][ch]+pw[1][ch]+pw[2][ch]+pw[3][ch];
}

// K2: lam[img] = sigmoid(relu(pool@w1^T+b1)@w2^T+b2)
__global__ __launch_bounds__(256) void k2_lambda(
    const float* __restrict__ part,
    const float* __restrict__ w1V, const float* __restrict__ b1V,
    const float* __restrict__ w2V, const float* __restrict__ b2V,
    const float* __restrict__ w1I, const float* __restrict__ b1I,
    const float* __restrict__ w2I, const float* __restrict__ b2I,
    float* __restrict__ lam)
{
  const int img = blockIdx.x, p = img>>1;
  const float* __restrict__ w1 = p? w1I : w1V;
  const float* __restrict__ b1 = p? b1I : b1V;
  const float* __restrict__ w2 = p? w2I : w2V;
  const float* __restrict__ b2 = p? b2I : b2V;
  __shared__ float pool[DM];
  __shared__ float hb[128];
  const int tid = threadIdx.x;
  for (int ch=tid; ch<DM; ch+=256){
    float s=0.f;
    #pragma unroll
    for (int sl=0; sl<16; ++sl) s += part[((size_t)img*16 + sl)*DM + ch];
    pool[ch] = s * (1.f/LQ);
  }
  __syncthreads();
  if (tid<128){
    float h = b1[tid];
    const float* __restrict__ wr = w1 + (size_t)tid*DM;
    for (int o=0;o<DM;o+=4){
      const float4 w = *(const float4*)(wr+o);
      h += pool[o]*w.x + pool[o+1]*w.y + pool[o+2]*w.z + pool[o+3]*w.w;
    }
    hb[tid] = fmaxf(h,0.f);
  }
  __syncthreads();
  if (tid==0){
    float v = b2[0];
    for (int j=0;j<128;++j) v += hb[j]*w2[j];
    lam[img] = sigm(v);
  }
}

// K3 (MFMA): xp[p][m][n] = bf16( xn[p][m][:] . iw[n][:] ),  M=2048 N=2048 K=512
__global__ __launch_bounds__(256) void k3_mfma(
    const u16* __restrict__ xn, const u16* __restrict__ iwVb, const u16* __restrict__ iwIb,
    u16* __restrict__ xp)
{
  const int p = blockIdx.z;
  const u16* __restrict__ A  = xn + (size_t)p*2048*DM;
  const u16* __restrict__ Bw = p? iwIb : iwVb;
  const int m0 = blockIdx.x*128, n0 = blockIdx.y*128;
  __shared__ __align__(16) u16 As[128*64];
  __shared__ __align__(16) u16 Bs[128*64];
  const int tid = threadIdx.x, lane = tid&63, wid = tid>>6;
  const int m_off = (wid>>1)*64, n_off = (wid&1)*64;
  f32x4 acc[4][4];
  const f32x4 z = {0.f,0.f,0.f,0.f};
  #pragma unroll
  for (int mi=0;mi<4;++mi) for (int ni=0;ni<4;++ni) acc[mi][ni]=z;
  gemm_main<128,128>(A + (size_t)m0*DM, Bw + (size_t)n0*DM, DM, As, Bs, acc, tid);
  u16* __restrict__ orow = xp + (size_t)p*2048*2048;
  #pragma unroll
  for (int mi=0;mi<4;++mi)
    #pragma unroll
    for (int rr=0;rr<4;++rr){
      const int m = m0 + m_off + mi*16 + ((lane>>4)<<2) + rr;
      #pragma unroll
      for (int ni=0;ni<4;++ni){
        const int n = n0 + n_off + ni*16 + (lane&15);
        orow[(size_t)m*2048 + n] = f2bf(acc[mi][ni][rr]);
      }
    }
}

// ---- chunked scan in u-space: u_t = a*u_{t-1} + x_t  (B-free; h = B.*u exactly) ----
// K4s1: per-chunk local u-scan (zero init), store RAW chunk-final states.
__global__ __launch_bounds__(256) void k4s1(
    const u16* __restrict__ xp,
    const float* __restrict__ AlV, const float* __restrict__ AlI,
    u16* __restrict__ hfin)
{
  const int p = blockIdx.z, c = blockIdx.y, rb = blockIdx.x;
  const int tid = threadIdx.x;
  const int row = rb*256 + tid;            // b*1024 + i
  const int bb = rb>>2;
  const int il = (rb&3)*256;               // i block base
  const int i  = il + tid;
  __shared__ __align__(16) u16 xs[TL*256];
  {
    const u16* src = xp + ((size_t)(p*2048 + bb*1024 + c*TL))*2048 + il;
    const int r0 = tid>>5, cb = (tid&31)*8;
    #pragma unroll
    for (int rr=0; rr<TL; rr+=8)
      *(uint4*)(xs + (rr+r0)*256 + cb) = *(const uint4*)(src + (size_t)(rr+r0)*2048 + cb);
  }
  const float* __restrict__ Al = p? AlI : AlV;
  float a[16], uf[16], ub[16];
  #pragma unroll
  for (int s=0;s<16;s+=4){
    const float4 al = *(const float4*)(Al + (size_t)i*NS + s);
    a[s]=-expf(al.x); a[s+1]=-expf(al.y); a[s+2]=-expf(al.z); a[s+3]=-expf(al.w);
    uf[s]=0.f; uf[s+1]=0.f; uf[s+2]=0.f; uf[s+3]=0.f;
    ub[s]=0.f; ub[s+1]=0.f; ub[s+2]=0.f; ub[s+3]=0.f;
  }
  __syncthreads();
  #pragma unroll 4
  for (int tt=0; tt<TL; ++tt){
    const float xf = bf2f(xs[tt*256 + tid]);
    const float xb = bf2f(xs[(TL-1-tt)*256 + tid]);
    #pragma unroll
    for (int s=0;s<16;++s){
      uf[s] = fmaf(uf[s], a[s], xf);
      ub[s] = fmaf(ub[s], a[s], xb);
    }
  }
  u16* hpf = hfin + (((size_t)(p*2+0)*CH + c)*2048 + row)*NS;
  u16* hpb = hfin + (((size_t)(p*2+1)*CH + c)*2048 + row)*NS;
  st8(hpf, uf); st8(hpf+8, uf+8);
  st8(hpb, ub); st8(hpb+8, ub+8);
}

// K4s2: final sweep; computes its own chunk-init prefix from raw finals, emits comb.
__global__ __launch_bounds__(256,2) void k4s2(
    const u16* __restrict__ xp, const u16* __restrict__ hfin,
    const float* __restrict__ AlV, const float* __restrict__ AlI,
    const float* __restrict__ BV,  const float* __restrict__ BI,
    const float* __restrict__ CV,  const float* __restrict__ CI,
    const float* __restrict__ lam, u16* __restrict__ comb)
{
  const int p = blockIdx.z, c = blockIdx.y, rb = blockIdx.x;
  const int tid = threadIdx.x;
  const int row = rb*256 + tid;
  const int bb = rb>>2;
  const int il = (rb&3)*256;
  const int i  = il + tid;
  __shared__ __align__(16) u16  xs[TL*256];
  __shared__ __align__(16) float ps[TL*256];
  {
    const u16* src = xp + ((size_t)(p*2048 + bb*1024 + c*TL))*2048 + il;
    const int r0 = tid>>5, cb = (tid&31)*8;
    #pragma unroll
    for (int rr=0; rr<TL; rr+=8)
      *(uint4*)(xs + (rr+r0)*256 + cb) = *(const uint4*)(src + (size_t)(rr+r0)*2048 + cb);
  }
  const float* __restrict__ Al = p? AlI : AlV;
  const float* __restrict__ B0 = p? BI : BV;    // own B
  const float* __restrict__ B1 = p? BV : BI;    // other's B (cross)
  const float* __restrict__ Cm = p? CI : CV;
  const float lm = lam[p*2+bb];
  float a[16], aT[16], dmix[16], uf[16], ub[16];
  #pragma unroll
  for (int s=0;s<16;s+=4){
    const float4 al = *(const float4*)(Al + (size_t)i*NS + s);
    const float4 b0 = *(const float4*)(B0 + (size_t)i*NS + s);
    const float4 b1 = *(const float4*)(B1 + (size_t)i*NS + s);
    const float4 cv = *(const float4*)(Cm + (size_t)i*NS + s);
    a[s]=-expf(al.x); a[s+1]=-expf(al.y); a[s+2]=-expf(al.z); a[s+3]=-expf(al.w);
    aT[s]  =expf((float)TL*al.x); aT[s+1]=expf((float)TL*al.y);     // a^TL (TL even)
    aT[s+2]=expf((float)TL*al.z); aT[s+3]=expf((float)TL*al.w);
    dmix[s]  =(lm*b0.x+(1.f-lm)*b1.x)*cv.x;
    dmix[s+1]=(lm*b0.y+(1.f-lm)*b1.y)*cv.y;
    dmix[s+2]=(lm*b0.z+(1.f-lm)*b1.z)*cv.z;
    dmix[s+3]=(lm*b0.w+(1.f-lm)*b1.w)*cv.w;
    uf[s]=0.f; uf[s+1]=0.f; uf[s+2]=0.f; uf[s+3]=0.f;
    ub[s]=0.f; ub[s+1]=0.f; ub[s+2]=0.f; ub[s+3]=0.f;
  }
  // in-register chunk prefix from raw finals (replaces k4b), software-pipelined
  const size_t cstride = (size_t)2048*NS;
  {
    const u16* hb = hfin + ((size_t)(p*2+0)*CH*2048 + row)*NS;
    if (c > 0){
      float fin[16];
      ld8(hb, fin); ld8(hb+8, fin+8);
      for (int j=1; j<c; ++j){
        float nx[16];
        ld8(hb + (size_t)j*cstride, nx); ld8(hb + (size_t)j*cstride + 8, nx+8);
        #pragma unroll
        for (int s=0;s<16;++s) uf[s] = fmaf(aT[s], uf[s], fin[s]);
        #pragma unroll
        for (int s=0;s<16;++s) fin[s] = nx[s];
      }
      #pragma unroll
      for (int s=0;s<16;++s) uf[s] = fmaf(aT[s], uf[s], fin[s]);
    }
  }
  {
    const u16* hb = hfin + ((size_t)(p*2+1)*CH*2048 + row)*NS;
    if (c < CH-1){
      float fin[16];
      ld8(hb + (size_t)(CH-1)*cstride, fin); ld8(hb + (size_t)(CH-1)*cstride + 8, fin+8);
      for (int j=CH-2; j>c; --j){
        float nx[16];
        ld8(hb + (size_t)j*cstride, nx); ld8(hb + (size_t)j*cstride + 8, nx+8);
        #pragma unroll
        for (int s=0;s<16;++s) ub[s] = fmaf(aT[s], ub[s], fin[s]);
        #pragma unroll
        for (int s=0;s<16;++s) fin[s] = nx[s];
      }
      #pragma unroll
      for (int s=0;s<16;++s) ub[s] = fmaf(aT[s], ub[s], fin[s]);
    }
  }
  __syncthreads();
  #pragma unroll 2
  for (int tt=0; tt<TL; ++tt){
    const float xf = bf2f(xs[tt*256 + tid]);
    const float xb = bf2f(xs[(TL-1-tt)*256 + tid]);
    float yf0=0.f, yf1=0.f, yb0=0.f, yb1=0.f;
    #pragma unroll
    for (int s=0;s<16;s+=2){
      uf[s]   = fmaf(uf[s],   a[s],   xf);
      uf[s+1] = fmaf(uf[s+1], a[s+1], xf);
      ub[s]   = fmaf(ub[s],   a[s],   xb);
      ub[s+1] = fmaf(ub[s+1], a[s+1], xb);
      yf0 = fmaf(uf[s],   dmix[s],   yf0);
      yf1 = fmaf(uf[s+1], dmix[s+1], yf1);
      yb0 = fmaf(ub[s],   dmix[s],   yb0);
      yb1 = fmaf(ub[s+1], dmix[s+1], yb1);
    }
    const float yf = yf0+yf1, yb = yb0+yb1;
    if (tt < TL/2){
      ps[tt*256 + tid]          = yf;
      ps[(TL-1-tt)*256 + tid]   = yb;
    } else {
      ps[tt*256 + tid]         += yf;
      ps[(TL-1-tt)*256 + tid]  += yb;
    }
  }
  __syncthreads();
  const int r0 = tid>>5, cb = (tid&31)*8;
  #pragma unroll
  for (int rr=0; rr<TL; rr+=8){
    const int r = rr + r0;
    const size_t mrow = (size_t)(p*2048 + bb*1024 + c*TL + r);
    float g8[8], o[8];
    ld8(xp + mrow*2048 + DI + il + cb, g8);
    #pragma unroll
    for (int j=0;j<8;++j){
      const float pv = ps[r*256 + cb + j];
      o[j] = 0.5f*g8[j]*sigm(g8[j])*pv;
    }
    st8(comb + mrow*(size_t)DI + il + cb, o);
  }
}

// K5 (MFMA, fused): out[img][q][hw] = x[img][q][hw] + bn( comb[p][m][:] . W2[p][q][:] )
__global__ __launch_bounds__(256) void k5_fused(
    const u16* __restrict__ comb, const u16* __restrict__ W2b,
    const float* __restrict__ xV, const float* __restrict__ xI,
    const float* __restrict__ rsg, const float* __restrict__ rsb,
    const float* __restrict__ rsm, const float* __restrict__ rsv,
    float* __restrict__ out)
{
  const int p = blockIdx.z;
  const int m0 = blockIdx.x*64, n0 = blockIdx.y*64;
  const u16* __restrict__ A = comb + (size_t)p*2048*DI;
  const u16* __restrict__ B = W2b + (size_t)p*256*1024;
  __shared__ __align__(16) u16 As[64*64];
  __shared__ __align__(16) u16 Bs[64*64];
  const int tid = threadIdx.x, lane = tid&63, wid = tid>>6;
  const int m_off = (wid>>1)*32, n_off = (wid&1)*32;
  f32x4 acc[2][2];
  const f32x4 z = {0.f,0.f,0.f,0.f};
  #pragma unroll
  for (int mi=0;mi<2;++mi) for (int ni=0;ni<2;++ni) acc[mi][ni]=z;
  gemm_main<64,64>(A + (size_t)m0*DI, B + (size_t)n0*DI, DI, As, Bs, acc, tid);
  const int bb = m0>>10;                 // batch within p (m0 tiles don't straddle)
  const int img = p*2 + bb;
  const float* __restrict__ xres = (p? xI : xV) + (size_t)bb*CIN*LQ;
  float* __restrict__ obase = out + (size_t)img*CIN*LQ;
  #pragma unroll
  for (int mi=0;mi<2;++mi)
    #pragma unroll
    for (int ni=0;ni<2;++ni){
      const int q = n0 + n_off + ni*16 + (lane&15);
      const float s = rsg[q]*rsqrtf(rsv[q]+EPSF);
      const float t = rsb[q] - rsm[q]*s;
      const int m = m0 + m_off + mi*16 + ((lane>>4)<<2);
      const int hw = m & 1023;
      const float4 xv = *(const float4*)(xres + (size_t)q*LQ + hw);
      float4 o;
      o.x = fmaf(acc[mi][ni][0], s, t) + xv.x;
      o.y = fmaf(acc[mi][ni][1], s, t) + xv.y;
      o.z = fmaf(acc[mi][ni][2], s, t) + xv.z;
      o.w = fmaf(acc[mi][ni][3], s, t) + xv.w;
      *(float4*)(obase + (size_t)q*LQ + hw) = o;
    }
}

extern "C" void kernel_launch(void* const* d_in, const int* in_sizes, int n_in,
                              void* d_out, int out_size, void* d_ws, size_t ws_size,
                              hipStream_t stream)
{
  const float* cr_w = (const float*)d_in[0];
  const float* cr_g = (const float*)d_in[1];
  const float* cr_b = (const float*)d_in[2];
  const float* cr_m = (const float*)d_in[3];
  const float* cr_v = (const float*)d_in[4];
  const float* rs_w = (const float*)d_in[5];
  const float* rs_g = (const float*)d_in[6];
  const float* rs_b = (const float*)d_in[7];
  const float* rs_m = (const float*)d_in[8];
  const float* rs_v = (const float*)d_in[9];
  const float* mV_ln_g = (const float*)d_in[10];
  const float* mV_ln_b = (const float*)d_in[11];
  const float* mV_in_w = (const float*)d_in[12];
  const float* mV_A    = (const float*)d_in[13];
  const float* mV_B    = (const float*)d_in[14];
  const float* mV_C    = (const float*)d_in[15];
  const float* mV_ow   = (const float*)d_in[16];
  const float* lpV_w1  = (const float*)d_in[17];
  const float* lpV_b1  = (const float*)d_in[18];
  const float* lpV_w2  = (const float*)d_in[19];
  const float* lpV_b2  = (const float*)d_in[20];
  const float* mI_ln_g = (const float*)d_in[21];
  const float* mI_ln_b = (const float*)d_in[22];
  const float* mI_in_w = (const float*)d_in[23];
  const float* mI_A    = (const float*)d_in[24];
  const float* mI_B    = (const float*)d_in[25];
  const float* mI_C    = (const float*)d_in[26];
  const float* mI_ow   = (const float*)d_in[27];
  const float* lpI_w1  = (const float*)d_in[28];
  const float* lpI_b1  = (const float*)d_in[29];
  const float* lpI_w2  = (const float*)d_in[30];
  const float* lpI_b2  = (const float*)d_in[31];
  const float* x_V = (const float*)d_in[32];
  const float* x_I = (const float*)d_in[33];
  float* out = (float*)d_out;

  char* ws = (char*)d_ws;
  // layout (~47.8 MB peak):
  float* xr    = (float*)(ws + 0);            // [4096][512] f32          8,388,608
  u16*   xn    = (u16*)  (ws + 8388608);      // [2][2048][512] bf16      4,194,304
  float* lam   = (float*)(ws + 12582912);     // [4] f32 (+pad)                 512
  u16*   iwVb  = (u16*)  (ws + 12583424);     // [2048][512] bf16         2,097,152
  u16*   iwIb  = (u16*)  (ws + 14680576);     // [2048][512] bf16         2,097,152
  u16*   owTVb = (u16*)  (ws + 16777728);     // [1024][512] bf16         1,048,576
  u16*   owTIb = (u16*)  (ws + 17826304);     // [1024][512] bf16         1,048,576
  u16*   rswb  = (u16*)  (ws + 18874880);     // [256][512] bf16            262,144
  u16*   crwb  = (u16*)  (ws + 19137024);     // [512][256] bf16            262,144
  u16*   xT    = (u16*)  (ws + 19399168);     // [4][1024][256] bf16      2,097,152
  u16*   W2b   = (u16*)  (ws + 21496320);     // [2][256][1024] bf16      1,048,576
  float* part  = (float*)(ws + 22544896);     // [4][16][512] f32           131,072
  u16*   xp    = (u16*)  (ws + 22675968);     // [2][2048][2048] bf16    16,777,216
  u16*   comb  = (u16*)  (ws + 39453184);     // [2][2048][1024] bf16     8,388,608
  // alias (lifetime-disjoint):
  u16*   hfin  = (u16*)  (ws + 0);            // [4][32][2048][16] bf16   8,388,608 (xr dead after k2f)

  k0_prep     <<<dim3(32,16,10), dim3(256), 0, stream>>>(mV_in_w, mI_in_w, cr_w, rs_w,
                                                         mV_ow, mI_ow, x_V, x_I,
                                                         iwVb, iwIb, crwb, rswb,
                                                         owTVb, owTIb, xT);
  k0b_w2      <<<dim3(2,8,2),   dim3(256), 0, stream>>>(rswb, owTVb, owTIb, W2b);
  k1_mfma     <<<dim3(64,8),    dim3(256), 0, stream>>>(xT, crwb, cr_g, cr_b, cr_m, cr_v, xr);
  k2f         <<<dim3(16,4),    dim3(256), 0, stream>>>(xr, mV_ln_g,mV_ln_b, mI_ln_g,mI_ln_b,
                                                        xn, part);
  k2_lambda   <<<dim3(4),       dim3(256), 0, stream>>>(part, lpV_w1,lpV_b1,lpV_w2,lpV_b2,
                                                              lpI_w1,lpI_b1,lpI_w2,lpI_b2, lam);
  k3_mfma     <<<dim3(16,16,2), dim3(256), 0, stream>>>(xn, iwVb, iwIb, xp);
  k4s1        <<<dim3(8,CH,2),  dim3(256), 0, stream>>>(xp, mV_A, mI_A, hfin);
  k4s2        <<<dim3(8,CH,2),  dim3(256), 0, stream>>>(xp, hfin, mV_A, mI_A, mV_B, mI_B,
                                                        mV_C, mI_C, lam, comb);
  k5_fused    <<<dim3(32,4,2),  dim3(256), 0, stream>>>(comb, W2b, x_V, x_I,
                                                        rs_g, rs_b, rs_m, rs_v, out);
}